// Round 8
// baseline (912.055 us; speedup 1.0000x reference)
//
#include <hip/hip_runtime.h>
#include <hip/hip_bf16.h>

typedef unsigned short u16;
typedef unsigned int u32;
typedef __bf16 bf16x8 __attribute__((ext_vector_type(8)));
typedef float f32x4 __attribute__((ext_vector_type(4)));

#define MFMA16(a,b,c) __builtin_amdgcn_mfma_f32_16x16x32_bf16((a),(b),(c),0,0,0)

__device__ __forceinline__ u16 f2bf(float f){
  u32 u = __builtin_bit_cast(u32, f);
  u32 r = (u + 0x7fffu + ((u >> 16) & 1u)) >> 16;
  return (u16)r;
}
__device__ __forceinline__ float bf2f(u16 h){
  u32 u = ((u32)h) << 16;
  return __builtin_bit_cast(float, u);
}
__device__ __forceinline__ void splitbf(float x, u16& hi, u16& lo){
  hi = f2bf(x);
  lo = f2bf(x - bf2f(hi));
}
__device__ __forceinline__ void gload_lds16(const u16* g, u16* l){
  __builtin_amdgcn_global_load_lds((__attribute__((address_space(1))) void*)(g),
                                   (__attribute__((address_space(3))) void*)(l), 16, 0, 0);
}
__device__ __forceinline__ const u16* selu(const u16* barr, const u16* parr, int i){
  return (i < 128) ? (barr + (size_t)i*16384) : (parr + (size_t)(i-128)*16384);
}
__device__ __forceinline__ const float* self32(const float* barr, const float* parr, int i){
  return (i < 128) ? (barr + (size_t)i*16384) : (parr + (size_t)(i-128)*16384);
}
// attention partial slots: 16512 f32 each (128x128 acc + 128 lsum)
__device__ __forceinline__ float* slotp(float* p1, float* p2, int s){
  return (s < 381) ? (p1 + (size_t)s*16512) : (p2 + (size_t)(s-381)*16512);
}
__device__ __forceinline__ const float* slotpc(const float* p1, const float* p2, int s){
  return (s < 381) ? (p1 + (size_t)s*16512) : (p2 + (size_t)(s-381)*16512);
}

// ---------------- workspace layout (bytes) ----------------
constexpr size_t OF_HSBF   = 0;           // hs bf16 (dead after gemm1); then BDTH/BDTL; then omix_bf
constexpr size_t OF_WQKVBF = 8388608;     // Wqkv bf16 (dead after gemm1)
constexpr size_t OF_WOBF   = 20971520;    // Wo bf16 [2048][2048]
constexpr size_t OF_QKV    = 29360128;    // qkv f32 (dead after prep2a/vt)
constexpr size_t OF_QBF    = 54525952;    // raw q bf16 [16][2048][128]
constexpr size_t OF_KBF    = 62914560;    // raw k bf16 [4][2048][128]
constexpr size_t OF_VT     = 65011712;    // vT bf16 [4][128][2048]
constexpr size_t OF_QLB    = 67108864;    // softmax q bf16 [16][2048][128]
constexpr size_t OF_KLF    = 75497472;    // softmax k f32 (dead after prep2b)
constexpr size_t OF_KLB    = 79691776;    // softmax k bf16
constexpr size_t OF_GLF    = 81788928;    // gate f32 (dead after prep2a)
constexpr size_t OF_TINV   = 85983232;    // Tinv f32 (dead after prep2a)
constexpr size_t OF_WF     = 88080384;    // w f32 (dead after prep2b)
constexpr size_t OF_WB     = 92274688;    // w bf16
constexpr size_t OF_U0     = 94371840;    // u0 f32 [128][64][128]
constexpr size_t OF_SJ     = 111149056;   // S^T states bf16 [512][128][128]
constexpr size_t OF_OMIX   = 127926272;   // f32 [2048][2048] (written by olin)
constexpr size_t OF_OMIXB  = 144703488;   // (old omix_bf region; now apart2 only)
// scan operator buffers:
constexpr size_t OF_ADF  = 102760448;             // D f32 8MB (side A)
constexpr size_t OF_ABTF = OF_OMIX;               // BT f32 8MB
constexpr size_t OF_ADH  = OF_OMIX + 8388608;     // D hi 4MB
constexpr size_t OF_ADL  = OF_OMIX + 12582912;    // D lo 4MB
constexpr size_t OF_ADTH = OF_OMIXB;              // D^T hi 4MB
constexpr size_t OF_ADTL = OF_OMIXB + 4194304;    // D^T lo 4MB
constexpr size_t OF_ABTH = OF_KLF;                // BT hi 4MB
constexpr size_t OF_ABTL = OF_GLF;                // BT lo 4MB
// side B:
constexpr size_t OF_BDF  = OF_QKV;                // 8MB
constexpr size_t OF_BBTF = OF_QKV + 8388608;      // 8MB
constexpr size_t OF_BDH  = OF_QKV + 16777216;     // 4MB
constexpr size_t OF_BDL  = OF_QKV + 20971520;     // 4MB
constexpr size_t OF_BDTH = OF_HSBF;               // 4MB
constexpr size_t OF_BDTL = OF_HSBF + 4194304;     // 4MB
constexpr size_t OF_BBTH = OF_WQKVBF;             // 4MB
constexpr size_t OF_BBTL = OF_WQKVBF + 4194304;   // 4MB
// head-start states
constexpr size_t OF_TTF  = OF_TINV;               // 1MB
constexpr size_t OF_TTH  = OF_WQKVBF + 8388608;   // 512KB
constexpr size_t OF_TTL  = OF_WQKVBF + 8912896;   // 512KB
// op pool (overlaid on dead side-A DF region):
constexpr size_t OF_PDF  = OF_ADF;
constexpr size_t OF_PBTF = OF_ADF + 1048576;
constexpr size_t OF_PDH  = OF_ADF + 2097152;
constexpr size_t OF_PDL  = OF_ADF + 2621440;
constexpr size_t OF_PDTH = OF_ADF + 3145728;
constexpr size_t OF_PDTL = OF_ADF + 3670016;
constexpr size_t OF_PBTH = OF_ADF + 4194304;
constexpr size_t OF_PBTL = OF_ADF + 4718592;
// attention K-split partial slots: 381 in dead qkv region + 195 at old omix_bf region
constexpr size_t OF_APART1 = OF_QKV;
constexpr size_t OF_APART2 = OF_OMIXB;
// final bf16 omix lives at ws+0 (BDTH/BDTL dead after k_expand)
constexpr size_t OF_OBF = 0;

struct ChainJobs { int cnt[4]; int a[4][3]; int b[4][3]; int d[4][3]; };

// ---------------- fused f2b of all 5 inputs ----------------
__global__ void k_f2ball(const float* __restrict__ hs, const float* __restrict__ Wq,
                         const float* __restrict__ Wk, const float* __restrict__ Wv,
                         const float* __restrict__ Wo, u16* __restrict__ hs_bf,
                         u16* __restrict__ wqkv_bf, u16* __restrict__ wo_bf){
  int bid = blockIdx.x;
  const float* src; u16* dst; int off;
  if(bid < 4096){ src = hs; dst = hs_bf; off = bid; }
  else if(bid < 8192){ src = Wq; dst = wqkv_bf; off = bid - 4096; }
  else if(bid < 9216){ src = Wk; dst = wqkv_bf + 2048*2048; off = bid - 8192; }
  else if(bid < 10240){ src = Wv; dst = wqkv_bf + 2560*2048; off = bid - 9216; }
  else { src = Wo; dst = wo_bf; off = bid - 10240; }
  int i = (off*256 + threadIdx.x) * 4;
  f32x4 v = *(const f32x4*)(src + i);
  u32 w0 = (u32)f2bf(v[0]) | ((u32)f2bf(v[1]) << 16);
  u32 w1 = (u32)f2bf(v[2]) | ((u32)f2bf(v[3]) << 16);
  *(u32*)(dst + i) = w0;
  *(u32*)(dst + i + 2) = w1;
}

// ---------------- bf16 NT GEMM with XCD-chunked swizzle ----------------
__global__ __launch_bounds__(256) void k_gemm(const u16* __restrict__ A, const u16* __restrict__ B,
                                              float* __restrict__ C, int K, int N){
  __shared__ u16 aL[128*32];
  __shared__ u16 bL[128*32];
  int lin = blockIdx.y * gridDim.x + blockIdx.x;
  int nwg = gridDim.x * gridDim.y;
  int s = (lin & 7) * (nwg >> 3) + (lin >> 3);
  int bn = s % gridDim.x, bm = s / gridDim.x;
  int tid = threadIdx.x, lane = tid & 63, w = tid >> 6;
  int wm = w >> 1, wn = w & 1;
  f32x4 acc[4][4] = {};
  int nK = K >> 5;
  const u16* Abase = A + (size_t)bm * 128 * K;
  const u16* Bbase = B + (size_t)bn * 128 * K;
  for(int kt = 0; kt < nK; ++kt){
    __syncthreads();
    #pragma unroll
    for(int t = 0; t < 2; ++t){
      int row = t*64 + w*16 + (lane >> 2);
      int kc = (lane & 3) * 8;
      gload_lds16(Abase + (size_t)row*K + kt*32 + kc, &aL[(t*64 + w*16)*32]);
      gload_lds16(Bbase + (size_t)row*K + kt*32 + kc, &bL[(t*64 + w*16)*32]);
    }
    __syncthreads();
    bf16x8 af[4], bf[4];
    #pragma unroll
    for(int i = 0; i < 4; ++i){
      af[i] = *(const bf16x8*)&aL[(wm*64 + i*16 + (lane & 15))*32 + ((lane >> 4) << 3)];
      bf[i] = *(const bf16x8*)&bL[(wn*64 + i*16 + (lane & 15))*32 + ((lane >> 4) << 3)];
    }
    #pragma unroll
    for(int i = 0; i < 4; ++i)
      #pragma unroll
      for(int j = 0; j < 4; ++j)
        acc[i][j] = MFMA16(af[i], bf[j], acc[i][j]);
  }
  #pragma unroll
  for(int i = 0; i < 4; ++i)
    #pragma unroll
    for(int j = 0; j < 4; ++j)
      #pragma unroll
      for(int r = 0; r < 4; ++r){
        int row = bm*128 + wm*64 + i*16 + ((lane >> 4) << 2) + r;
        int col = bn*128 + wn*64 + j*16 + (lane & 15);
        C[(size_t)row * N + col] = acc[i][j][r];
      }
}

// ---------------- fused linprep + V-transpose ----------------
__global__ __launch_bounds__(256) void k_linvt(const float* __restrict__ qkv, u16* qbf, u16* qlb,
                                               u16* kbf, float* klf, u16* klb, float* glf,
                                               u16* __restrict__ vT){
  __shared__ float t[64][65];
  int bid = blockIdx.x;
  if(bid < 10240){
    int gtask = bid * 4 + (threadIdx.x >> 6);
    int lane = threadIdx.x & 63;
    int n = gtask / 20, tt = gtask % 20;
    const float* row = (tt < 16) ? (qkv + (size_t)n*3072 + tt*128)
                                 : (qkv + (size_t)n*3072 + 2048 + (tt-16)*128);
    float v0 = row[lane], v1 = row[lane + 64];
    float m = fmaxf(v0, v1);
    #pragma unroll
    for(int o = 1; o < 64; o <<= 1) m = fmaxf(m, __shfl_xor(m, o, 64));
    float e0 = __expf(v0 - m), e1 = __expf(v1 - m);
    float s = e0 + e1;
    #pragma unroll
    for(int o = 1; o < 64; o <<= 1) s += __shfl_xor(s, o, 64);
    float r0 = e0 / s, r1 = e1 / s;
    if(tt < 16){
      size_t base = ((size_t)tt*2048 + n) * 128;
      qbf[base + lane] = f2bf(v0); qbf[base + 64 + lane] = f2bf(v1);
      qlb[base + lane] = f2bf(r0); qlb[base + 64 + lane] = f2bf(r1);
    } else {
      int g = tt - 16;
      size_t base = ((size_t)g*2048 + n) * 128;
      kbf[base + lane] = f2bf(v0); kbf[base + 64 + lane] = f2bf(v1);
      klf[base + lane] = r0;       klf[base + 64 + lane] = r1;
      klb[base + lane] = f2bf(r0); klb[base + 64 + lane] = f2bf(r1);
      float g0 = (fminf(v0, 0.f) - log1pf(__expf(-fabsf(v0)))) * (1.f/16.f);
      float g1 = (fminf(v1, 0.f) - log1pf(__expf(-fabsf(v1)))) * (1.f/16.f);
      glf[base + lane] = g0; glf[base + 64 + lane] = g1;
    }
  } else {
    int v = bid - 10240;
    int nt = v & 31, dt = (v >> 5) & 1, g = v >> 6;
    int tid = threadIdx.x;
    {
      int r = tid >> 2, c0 = (tid & 3) * 16;
      const float* src = qkv + (size_t)(nt*64 + r)*3072 + 2560 + g*128 + dt*64 + c0;
      #pragma unroll
      for(int q = 0; q < 16; q += 4){
        f32x4 vv = *(const f32x4*)(src + q);
        t[r][c0+q] = vv[0]; t[r][c0+q+1] = vv[1]; t[r][c0+q+2] = vv[2]; t[r][c0+q+3] = vv[3];
      }
    }
    __syncthreads();
    {
      int d = tid >> 2, c0 = (tid & 3) * 16;
      u16* dst = vT + ((size_t)g*128 + dt*64 + d)*2048 + (size_t)nt*64 + c0;
      #pragma unroll
      for(int half = 0; half < 2; ++half){
        int b = c0 + half*8;
        u32 w0 = (u32)f2bf(t[b+0][d]) | ((u32)f2bf(t[b+1][d]) << 16);
        u32 w1 = (u32)f2bf(t[b+2][d]) | ((u32)f2bf(t[b+3][d]) << 16);
        u32 w2 = (u32)f2bf(t[b+4][d]) | ((u32)f2bf(t[b+5][d]) << 16);
        u32 w3 = (u32)f2bf(t[b+6][d]) | ((u32)f2bf(t[b+7][d]) << 16);
        *(uint4*)(dst + half*8) = make_uint4(w0, w1, w2, w3);
      }
    }
  }
}

// ---------------- prep1 ----------------
__global__ __launch_bounds__(256) void k_prep1(const float* __restrict__ klf, const float* __restrict__ glf,
                                               float* __restrict__ tinv){
  __shared__ float KlT[128][68];
  __shared__ float Kb[64][132];
  __shared__ float Am[64][68];
  __shared__ float XT[64][68];
  int idx = blockIdx.x, g = idx >> 5, c = idx & 31, tid = threadIdx.x;
  size_t base = ((size_t)g*2048 + c*64) * 128;
  {
    int r = tid >> 2, d0 = (tid & 3) * 32;
    #pragma unroll
    for(int dd = 0; dd < 32; dd += 4){
      f32x4 kv = *(const f32x4*)(klf + base + r*128 + d0 + dd);
      f32x4 gv = *(const f32x4*)(glf + base + r*128 + d0 + dd);
      KlT[d0+dd][r] = kv[0]; KlT[d0+dd+1][r] = kv[1]; KlT[d0+dd+2][r] = kv[2]; KlT[d0+dd+3][r] = kv[3];
      f32x4 kb = kv * gv;
      *(f32x4*)&Kb[r][d0+dd] = kb;
    }
  }
  __syncthreads();
  {
    int i = tid >> 2, j0 = (tid & 3) * 16;
    f32x4 s[4] = {};
    for(int d = 0; d < 128; ++d){
      float kb = Kb[i][d];
      #pragma unroll
      for(int q = 0; q < 4; ++q){
        f32x4 kl = *(const f32x4*)&KlT[d][j0 + q*4];
        s[q] += kb * kl;
      }
    }
    #pragma unroll
    for(int q = 0; q < 4; ++q) *(f32x4*)&Am[i][j0 + q*4] = s[q];
  }
  __syncthreads();
  if(tid < 64){
    int cc = tid;
    float x0 = (cc == 0) ? 1.f : 0.f;
    XT[cc][0] = x0;
    tinv[(size_t)idx*4096 + cc] = x0;
    for(int i = 1; i < 64; ++i){
      float s = (i == cc) ? 1.f : 0.f;
      int i4 = i & ~3;
      for(int jj = 0; jj < i4; jj += 4){
        f32x4 av = *(const f32x4*)&Am[i][jj];
        f32x4 xv = *(const f32x4*)&XT[cc][jj];
        s -= av[0]*xv[0] + av[1]*xv[1] + av[2]*xv[2] + av[3]*xv[3];
      }
      for(int jj = i4; jj < i; ++jj) s -= Am[i][jj] * XT[cc][jj];
      XT[cc][i] = s;
      tinv[(size_t)idx*4096 + i*64 + cc] = s;
    }
  }
}

// ---------------- prep2a ----------------
__global__ __launch_bounds__(256) void k_prep2a(const float* __restrict__ klf, const float* __restrict__ glf,
                                                const float* __restrict__ qkv, const float* __restrict__ tinv,
                                                float* __restrict__ wf, u16* __restrict__ wb, float* __restrict__ u0f){
  __shared__ float Ti[64][68];
  __shared__ float B1[64][132];
  __shared__ float B2[64][132];
  int idx = blockIdx.x, g = idx >> 5, c = idx & 31, tid = threadIdx.x;
  size_t base = ((size_t)g*2048 + c*64) * 128;
  {
    int r = tid >> 2, d0 = (tid & 3) * 32;
    #pragma unroll
    for(int dd = 0; dd < 32; dd += 4){
      f32x4 kv = *(const f32x4*)(klf + base + r*128 + d0 + dd);
      f32x4 gv = *(const f32x4*)(glf + base + r*128 + d0 + dd);
      f32x4 vv = *(const f32x4*)(qkv + (size_t)(c*64 + r)*3072 + 2560 + g*128 + d0 + dd);
      *(f32x4*)&B1[r][d0+dd] = kv * gv;
      *(f32x4*)&B2[r][d0+dd] = vv * gv;
    }
    int c0 = (tid & 3) * 16;
    #pragma unroll
    for(int q = 0; q < 16; q += 4)
      *(f32x4*)&Ti[r][c0+q] = *(const f32x4*)(tinv + (size_t)idx*4096 + r*64 + c0 + q);
  }
  __syncthreads();
  int i = tid >> 2, cc0 = (tid & 3) * 32;
  f32x4 wa[8] = {}; f32x4 ua[8] = {};
  for(int jj = 0; jj < 64; ++jj){
    float a = Ti[i][jj];
    #pragma unroll
    for(int q = 0; q < 8; ++q){
      f32x4 b1 = *(const f32x4*)&B1[jj][cc0 + q*4];
      f32x4 b2 = *(const f32x4*)&B2[jj][cc0 + q*4];
      wa[q] += a * b1; ua[q] += a * b2;
    }
  }
  #pragma unroll
  for(int q = 0; q < 8; ++q){
    *(f32x4*)(wf + (size_t)idx*8192 + i*128 + cc0 + q*4) = wa[q];
    *(f32x4*)(u0f + (size_t)idx*8192 + i*128 + cc0 + q*4) = ua[q];
    u32 w0 = (u32)f2bf(wa[q][0]) | ((u32)f2bf(wa[q][1]) << 16);
    u32 w1 = (u32)f2bf(wa[q][2]) | ((u32)f2bf(wa[q][3]) << 16);
    u32* dst = (u32*)(wb + (size_t)idx*8192 + i*128 + cc0 + q*4);
    dst[0] = w0; dst[1] = w1;
  }
}

// ---------------- prep2b ----------------
__global__ __launch_bounds__(256) void k_prep2b(const float* __restrict__ klf, const float* __restrict__ wf,
                                                const float* __restrict__ u0f,
                                                float* __restrict__ dF, u16* __restrict__ dH, u16* __restrict__ dL,
                                                u16* __restrict__ dTH, u16* __restrict__ dTL,
                                                float* __restrict__ btF, u16* __restrict__ btH, u16* __restrict__ btL){
  __shared__ float Kl[64][132];
  __shared__ float Wm[64][132];
  __shared__ float Um[64][132];
  int idx = blockIdx.x, g = idx >> 5, c = idx & 31, tid = threadIdx.x;
  size_t base = ((size_t)g*2048 + c*64) * 128;
  {
    int r = tid >> 2, d0 = (tid & 3) * 32;
    #pragma unroll
    for(int dd = 0; dd < 32; dd += 4){
      *(f32x4*)&Kl[r][d0+dd] = *(const f32x4*)(klf + base + r*128 + d0 + dd);
      *(f32x4*)&Wm[r][d0+dd] = *(const f32x4*)(wf + (size_t)idx*8192 + r*128 + d0 + dd);
      *(f32x4*)&Um[r][d0+dd] = *(const f32x4*)(u0f + (size_t)idx*8192 + r*128 + d0 + dd);
    }
  }
  __syncthreads();
  int a = tid >> 1, b0 = (tid & 1) * 64;
  f32x4 pa[16] = {}; f32x4 ca[16] = {};
  for(int r = 0; r < 64; ++r){
    float ka = Kl[r][a];
    float ua = Um[r][a];
    #pragma unroll
    for(int q = 0; q < 16; ++q){
      f32x4 wv = *(const f32x4*)&Wm[r][b0 + q*4];
      f32x4 kv = *(const f32x4*)&Kl[r][b0 + q*4];
      pa[q] += ka * wv;
      ca[q] += ua * kv;
    }
  }
  size_t ob = (size_t)idx * 16384;
  #pragma unroll
  for(int q = 0; q < 16; ++q){
    #pragma unroll
    for(int e = 0; e < 4; ++e){
      int b = b0 + q*4 + e;
      float dv = -pa[q][e];
      u16 dh, dl; splitbf(dv, dh, dl);
      dF[ob + a*128 + b] = dv;
      dH[ob + a*128 + b] = dh;
      dL[ob + a*128 + b] = dl;
      dTH[ob + (size_t)b*128 + a] = dh;
      dTL[ob + (size_t)b*128 + a] = dl;
      float cv = ca[q][e];
      u16 ch, cl; splitbf(cv, ch, cl);
      btF[ob + a*128 + b] = cv;
      btH[ob + a*128 + b] = ch;
      btL[ob + a*128 + b] = cl;
    }
  }
}

// ---------------- Kogge-Stone compose round (split-precision) ----------------
__global__ __launch_bounds__(256) void k_ks(
    const float* __restrict__ sDF, const u16* __restrict__ sDH, const u16* __restrict__ sDL,
    const u16* __restrict__ sDTH, const u16* __restrict__ sDTL,
    const float* __restrict__ sBF, const u16* __restrict__ sBH, const u16* __restrict__ sBL,
    float* __restrict__ dDF, u16* __restrict__ dDH, u16* __restrict__ dDL,
    u16* __restrict__ dDTH, u16* __restrict__ dDTL,
    float* __restrict__ dBF, u16* __restrict__ dBH, u16* __restrict__ dBL, int off){
  __shared__ float T[128][132];
  int c = blockIdx.x, g = blockIdx.y, z = blockIdx.z;
  int idx = g*32 + c, tid = threadIdx.x;
  size_t base = (size_t)idx * 16384;
  if(c < off){
    if(z == 0){
      for(int i = tid; i < 4096; i += 256) ((uint4*)(dDF + base))[i] = ((const uint4*)(sDF + base))[i];
      for(int i = tid; i < 2048; i += 256){
        ((uint4*)(dDH + base))[i] = ((const uint4*)(sDH + base))[i];
        ((uint4*)(dDL + base))[i] = ((const uint4*)(sDL + base))[i];
        ((uint4*)(dDTH + base))[i] = ((const uint4*)(sDTH + base))[i];
        ((uint4*)(dDTL + base))[i] = ((const uint4*)(sDTL + base))[i];
      }
    } else {
      for(int i = tid; i < 4096; i += 256) ((uint4*)(dBF + base))[i] = ((const uint4*)(sBF + base))[i];
      for(int i = tid; i < 2048; i += 256){
        ((uint4*)(dBH + base))[i] = ((const uint4*)(sBH + base))[i];
        ((uint4*)(dBL + base))[i] = ((const uint4*)(sBL + base))[i];
      }
    }
    return;
  }
  size_t blo = (size_t)(idx - off) * 16384;
  int lane = tid & 63, w = tid >> 6;
  const u16 *Ah, *Al, *Bh, *Bl;
  if(z == 0){ Ah = sDH + base; Al = sDL + base; Bh = sDTH + blo; Bl = sDTL + blo; }
  else      { Ah = sBH + blo;  Al = sBL + blo;  Bh = sDH + base; Bl = sDL + base; }
  f32x4 acc[2][8] = {};
  #pragma unroll
  for(int ks = 0; ks < 4; ++ks){
    bf16x8 ah[2], al[2], bh[8], bl[8];
    #pragma unroll
    for(int mt = 0; mt < 2; ++mt){
      int ro = (w*32 + mt*16 + (lane & 15))*128 + ks*32 + ((lane >> 4) << 3);
      ah[mt] = *(const bf16x8*)(Ah + ro);
      al[mt] = *(const bf16x8*)(Al + ro);
    }
    #pragma unroll
    for(int nt = 0; nt < 8; ++nt){
      int ro = (nt*16 + (lane & 15))*128 + ks*32 + ((lane >> 4) << 3);
      bh[nt] = *(const bf16x8*)(Bh + ro);
      bl[nt] = *(const bf16x8*)(Bl + ro);
    }
    #pragma unroll
    for(int mt = 0; mt < 2; ++mt)
      #pragma unroll
      for(int nt = 0; nt < 8; ++nt)
        acc[mt][nt] = MFMA16(ah[mt], bh[nt],
                      MFMA16(ah[mt], bl[nt],
                      MFMA16(al[mt], bh[nt], acc[mt][nt])));
  }
  if(z == 0){
    #pragma unroll
    for(int mt = 0; mt < 2; ++mt)
      #pragma unroll
      for(int nt = 0; nt < 8; ++nt)
        #pragma unroll
        for(int r = 0; r < 4; ++r){
          int row = w*32 + mt*16 + ((lane >> 4) << 2) + r;
          int col = nt*16 + (lane & 15);
          float v = acc[mt][nt][r] + sDF[base + row*128 + col] + sDF[blo + row*128 + col];
          dDF[base + row*128 + col] = v;
          u16 hi, lo; splitbf(v, hi, lo);
          dDH[base + row*128 + col] = hi;
          dDL[base + row*128 + col] = lo;
          T[row][col] = v;
        }
    __syncthreads();
    int tcol = tid >> 1, half = tid & 1;
    for(int m = 0; m < 64; ++m){
      float v = T[half*64 + m][tcol];
      u16 hi, lo; splitbf(v, hi, lo);
      dDTH[base + (size_t)tcol*128 + half*64 + m] = hi;
      dDTL[base + (size_t)tcol*128 + half*64 + m] = lo;
    }
  } else {
    #pragma unroll
    for(int mt = 0; mt < 2; ++mt)
      #pragma unroll
      for(int nt = 0; nt < 8; ++nt)
        #pragma unroll
        for(int r = 0; r < 4; ++r){
          int row = w*32 + mt*16 + ((lane >> 4) << 2) + r;
          int col = nt*16 + (lane & 15);
          float v = acc[mt][nt][r] + sBF[base + row*128 + col] + sBF[blo + row*128 + col];
          dBF[base + row*128 + col] = v;
          u16 hi, lo; splitbf(v, hi, lo);
          dBH[base + row*128 + col] = hi;
          dBL[base + row*128 + col] = lo;
        }
  }
}

// ---------------- hi/lo MFMA helper for 128x128 compose ----------------
__device__ __forceinline__ void comp_mfma(const u16* Ah, const u16* Al, const u16* Bh, const u16* Bl,
                                          f32x4 (&acc)[2][8], int lane, int w){
  #pragma unroll
  for(int ks = 0; ks < 4; ++ks){
    bf16x8 ah[2], al[2], bh[8], bl[8];
    #pragma unroll
    for(int mt = 0; mt < 2; ++mt){
      int ro = (w*32 + mt*16 + (lane & 15))*128 + ks*32 + ((lane >> 4) << 3);
      ah[mt] = *(const bf16x8*)(Ah + ro);
      al[mt] = *(const bf16x8*)(Al + ro);
    }
    #pragma unroll
    for(int nt = 0; nt < 8; ++nt){
      int ro = (nt*16 + (lane & 15))*128 + ks*32 + ((lane >> 4) << 3);
      bh[nt] = *(const bf16x8*)(Bh + ro);
      bl[nt] = *(const bf16x8*)(Bl + ro);
    }
    #pragma unroll
    for(int mt = 0; mt < 2; ++mt)
      #pragma unroll
      for(int nt = 0; nt < 8; ++nt)
        acc[mt][nt] = MFMA16(ah[mt], bh[nt],
                      MFMA16(ah[mt], bl[nt],
                      MFMA16(al[mt], bh[nt], acc[mt][nt])));
  }
}

// ---------------- chained composes: per-block sequential job list (D part then BT part) ----------------
__global__ __launch_bounds__(256) void k_compchain(
    const float* __restrict__ bDF, const u16* __restrict__ bDH, const u16* __restrict__ bDL,
    const u16* __restrict__ bDTH, const u16* __restrict__ bDTL,
    const float* __restrict__ bBTF, const u16* __restrict__ bBTH, const u16* __restrict__ bBTL,
    float* __restrict__ pDF, u16* __restrict__ pDH, u16* __restrict__ pDL,
    u16* __restrict__ pDTH, u16* __restrict__ pDTL,
    float* __restrict__ pBTF, u16* __restrict__ pBTH, u16* __restrict__ pBTL,
    ChainJobs cj){
  __shared__ float T[128][132];
  int blk = blockIdx.x, tid = threadIdx.x, lane = tid & 63, w = tid >> 6;
  for(int jt = 0; jt < cj.cnt[blk]; ++jt){
    int a = cj.a[blk][jt], b = cj.b[blk][jt], d = cj.d[blk][jt] - 128;
    size_t ob = (size_t)d * 16384;
    { // D' = D_a + D_b + D_a*D_b
      f32x4 acc[2][8] = {};
      comp_mfma(selu(bDH,pDH,a), selu(bDL,pDL,a), selu(bDTH,pDTH,b), selu(bDTL,pDTL,b), acc, lane, w);
      const float* F1 = self32(bDF, pDF, a);
      const float* F2 = self32(bDF, pDF, b);
      #pragma unroll
      for(int mt = 0; mt < 2; ++mt)
        #pragma unroll
        for(int nt = 0; nt < 8; ++nt)
          #pragma unroll
          for(int r = 0; r < 4; ++r){
            int row = w*32 + mt*16 + ((lane >> 4) << 2) + r;
            int col = nt*16 + (lane & 15);
            float v = acc[mt][nt][r] + F1[row*128 + col] + F2[row*128 + col];
            pDF[ob + row*128 + col] = v;
            u16 hi, lo; splitbf(v, hi, lo);
            pDH[ob + row*128 + col] = hi;
            pDL[ob + row*128 + col] = lo;
            T[row][col] = v;
          }
      __syncthreads();
      int tcol = tid >> 1, half = tid & 1;
      for(int m = 0; m < 64; ++m){
        float v = T[half*64 + m][tcol];
        u16 hi, lo; splitbf(v, hi, lo);
        pDTH[ob + (size_t)tcol*128 + half*64 + m] = hi;
        pDTL[ob + (size_t)tcol*128 + half*64 + m] = lo;
      }
      __syncthreads();
    }
    { // BT' = BT_a + BT_b + nt(BT_b, D_a)
      f32x4 acc[2][8] = {};
      comp_mfma(selu(bBTH,pBTH,b), selu(bBTL,pBTL,b), selu(bDH,pDH,a), selu(bDL,pDL,a), acc, lane, w);
      const float* F1 = self32(bBTF, pBTF, a);
      const float* F2 = self32(bBTF, pBTF, b);
      #pragma unroll
      for(int mt = 0; mt < 2; ++mt)
        #pragma unroll
        for(int nt = 0; nt < 8; ++nt)
          #pragma unroll
          for(int r = 0; r < 4; ++r){
            int row = w*32 + mt*16 + ((lane >> 4) << 2) + r;
            int col = nt*16 + (lane & 15);
            float v = acc[mt][nt][r] + F1[row*128 + col] + F2[row*128 + col];
            pBTF[ob + row*128 + col] = v;
            u16 hi, lo; splitbf(v, hi, lo);
            pBTH[ob + row*128 + col] = hi;
            pBTL[ob + row*128 + col] = lo;
          }
      __syncthreads();
    }
  }
}

// ---------------- head starts (parallel) ----------------
__global__ __launch_bounds__(256) void k_heads(
    const u16* __restrict__ bDH, const u16* __restrict__ bDL,
    const float* __restrict__ bBTF, const u16* __restrict__ bBTH, const u16* __restrict__ bBTL,
    const u16* __restrict__ pDH, const u16* __restrict__ pDL,
    const float* __restrict__ pBTF, const u16* __restrict__ pBTH, const u16* __restrict__ pBTL,
    float* __restrict__ ttF, u16* __restrict__ ttH, u16* __restrict__ ttL, u16* __restrict__ sj){
  int h = blockIdx.x, g = h >> 2, i = h & 3;
  int tid = threadIdx.x, lane = tid & 63, w = tid >> 6;
  int psi = (g == 0) ? -1 : (g == 1 ? 136 : (g == 2 ? 140 : 142));
  int phi = (i == 0) ? -1 : (i == 1 ? g*32 + 31 : (i == 2 ? 128 + g : 132 + g));
  f32x4 acc[2][8] = {};
  if(psi >= 0 && phi >= 0)
    comp_mfma(selu(bBTH,pBTH,psi), selu(bBTL,pBTL,psi), selu(bDH,pDH,phi), selu(bDL,pDL,phi), acc, lane, w);
  const float* Pf = (psi >= 0) ? self32(bBTF, pBTF, psi) : nullptr;
  const float* Ff = (phi >= 0) ? self32(bBTF, pBTF, phi) : nullptr;
  #pragma unroll
  for(int mt = 0; mt < 2; ++mt)
    #pragma unroll
    for(int nt = 0; nt < 8; ++nt)
      #pragma unroll
      for(int r = 0; r < 4; ++r){
        int row = w*32 + mt*16 + ((lane >> 4) << 2) + r;
        int col = nt*16 + (lane & 15);
        float v = acc[mt][nt][r];
        if(Pf) v += Pf[row*128 + col];
        if(Ff) v += Ff[row*128 + col];
        u16 hi, lo; splitbf(v, hi, lo);
        size_t o = (size_t)h*16384 + row*128 + col;
        ttF[o] = v; ttH[o] = hi; ttL[o] = lo;
        sj[(size_t)(h*32)*16384 + row*128 + col] = hi;
      }
}

// ---------------- expand ----------------
__global__ __launch_bounds__(256) void k_expand(const u16* __restrict__ bDH, const u16* __restrict__ bDL,
                                                const float* __restrict__ bBF, const float* __restrict__ ttF,
                                                const u16* __restrict__ ttH, const u16* __restrict__ ttL,
                                                u16* __restrict__ sj){
  int j = blockIdx.x;
  int c = j & 31;
  if(c == 0) return;
  int h = j >> 5, g = h >> 2;
  size_t obase = (size_t)j * 16384;
  size_t mb = (size_t)(g*32 + c - 1) * 16384;
  size_t tb = (size_t)h * 16384;
  int tid = threadIdx.x, lane = tid & 63, w = tid >> 6;
  f32x4 acc[2][8] = {};
  comp_mfma(ttH + tb, ttL + tb, bDH + mb, bDL + mb, acc, lane, w);
  #pragma unroll
  for(int mt = 0; mt < 2; ++mt)
    #pragma unroll
    for(int nt = 0; nt < 8; ++nt)
      #pragma unroll
      for(int r = 0; r < 4; ++r){
        int row = w*32 + mt*16 + ((lane >> 4) << 2) + r;
        int col = nt*16 + (lane & 15);
        float v = acc[mt][nt][r] + ttF[tb + row*128 + col] + bBF[mb + row*128 + col];
        sj[obase + row*128 + col] = f2bf(v);
      }
}

// ---------------- o_lin ----------------
__global__ __launch_bounds__(256) void k_olin(const u16* __restrict__ qlb, const u16* __restrict__ klb,
                                              const u16* __restrict__ wb, const float* __restrict__ u0f,
                                              const u16* __restrict__ sj, float* __restrict__ omix){
  __shared__ u16 ut[128*64];
  __shared__ u16 pl[4][16*64];
  int j = blockIdx.x;
  int h = j >> 5, c = j & 31, g = h >> 2, idx = g*32 + c;
  int tid = threadIdx.x, lane = tid & 63, w = tid >> 6;
  const u16* Sj = sj + (size_t)j * 16384;
  const u16* Q  = qlb + ((size_t)h*2048 + c*64) * 128;
  const u16* Kc = klb + ((size_t)g*2048 + c*64) * 128;
  const u16* W  = wb + (size_t)idx * 8192;
  const float* U0 = u0f + (size_t)idx * 8192;
  bf16x8 aq[4], aw[4];
  #pragma unroll
  for(int ks = 0; ks < 4; ++ks){
    aq[ks] = *(const bf16x8*)(Q + (w*16 + (lane & 15))*128 + ks*32 + ((lane >> 4) << 3));
    aw[ks] = *(const bf16x8*)(W + (w*16 + (lane & 15))*128 + ks*32 + ((lane >> 4) << 3));
  }
  f32x4 t1[8] = {}, ui[8] = {};
  #pragma unroll
  for(int ks = 0; ks < 4; ++ks)
    #pragma unroll
    for(int nt = 0; nt < 8; ++nt){
      bf16x8 b = *(const bf16x8*)(Sj + (nt*16 + (lane & 15))*128 + ks*32 + ((lane >> 4) << 3));
      t1[nt] = MFMA16(aq[ks], b, t1[nt]);
      ui[nt] = MFMA16(aw[ks], b, ui[nt]);
    }
  f32x4 sc[4] = {};
  #pragma unroll
  for(int ks = 0; ks < 4; ++ks)
    #pragma unroll
    for(int nt = 0; nt < 4; ++nt){
      bf16x8 b = *(const bf16x8*)(Kc + (nt*16 + (lane & 15))*128 + ks*32 + ((lane >> 4) << 3));
      sc[nt] = MFMA16(aq[ks], b, sc[nt]);
    }
  #pragma unroll
  for(int nt = 0; nt < 4; ++nt)
    #pragma unroll
    for(int r = 0; r < 4; ++r){
      int row = ((lane >> 4) << 2) + r;
      int col = nt*16 + (lane & 15);
      int grow = w*16 + row;
      float v = (col <= grow) ? sc[nt][r] : 0.f;
      int bo = (row*128 + col*2) ^ ((row & 7) << 4);
      *(u16*)((char*)&pl[w][0] + bo) = f2bf(v);
    }
  #pragma unroll
  for(int nt = 0; nt < 8; ++nt)
    #pragma unroll
    for(int r = 0; r < 4; ++r){
      int kv = w*16 + ((lane >> 4) << 2) + r;
      int d  = nt*16 + (lane & 15);
      float v = U0[kv*128 + d] - ui[nt][r];
      int bo = (d*128 + kv*2) ^ ((d & 7) << 4);
      *(u16*)((char*)ut + bo) = f2bf(v);
    }
  __syncthreads();
  f32x4 o2[8] = {};
  #pragma unroll
  for(int ks2 = 0; ks2 < 2; ++ks2){
    int row = lane & 15;
    int boA = (row*128 + ks2*64 + ((lane >> 4) << 4)) ^ ((row & 7) << 4);
    bf16x8 a = *(const bf16x8*)((const char*)&pl[w][0] + boA);
    #pragma unroll
    for(int nt = 0; nt < 8; ++nt){
      int d = nt*16 + (lane & 15);
      int boB = (d*128 + ks2*64 + ((lane >> 4) << 4)) ^ ((d & 7) << 4);
      bf16x8 b = *(const bf16x8*)((const char*)ut + boB);
      o2[nt] = MFMA16(a, b, o2[nt]);
    }
  }
  #pragma unroll
  for(int nt = 0; nt < 8; ++nt)
    #pragma unroll
    for(int r = 0; r < 4; ++r){
      int grow = c*64 + w*16 + ((lane >> 4) << 2) + r;
      int d = nt*16 + (lane & 15);
      omix[(size_t)grow*2048 + h*128 + d] = 0.5f * (t1[nt][r] + o2[nt][r]);
    }
}

// ---------------- base causal attention: head-major block order + XCD swizzle, dbuf P-LDS, K prefetch ----------------
// bid = h*40 + j; j<4: finalize qB=j into obf; else slot = h*36 + (j-4).
__global__ __launch_bounds__(256) void k_attn(const u16* __restrict__ qbf, const u16* __restrict__ kbf,
                                              const u16* __restrict__ vT, const float* __restrict__ omix,
                                              u16* __restrict__ obf,
                                              float* __restrict__ part1, float* __restrict__ part2){
  __shared__ u16 pl[4][2560];
  int rb = blockIdx.x;
  int bid = (rb & 7) * 80 + (rb >> 3);   // XCD-chunked swizzle (640 % 8 == 0)
  int h = bid / 40, j = bid % 40;
  int qB, kt0, kt1, slot = -1;
  if(j < 4){ qB = j; kt0 = 0; kt1 = 4*(qB+1); }
  else {
    int jj = j - 4; int seg;
    if(jj < 8){ qB = 4 + (jj >> 1); seg = jj & 1; }
    else if(jj < 20){ int q = jj - 8; qB = 8 + q/3; seg = q - (qB-8)*3; }
    else { int q = jj - 20; qB = 12 + (q >> 2); seg = q & 3; }
    slot = h*36 + jj;
    kt0 = seg*16;
    int full = 4*(qB+1);
    kt1 = (kt0 + 16 < full) ? kt0 + 16 : full;
  }
  int g = h >> 2;
  int tid = threadIdx.x, lane = tid & 63, w = tid >> 6;
  const u16* K = kbf + (size_t)g*2048*128;
  const u16* V = vT + (size_t)g*128*2048;
  bf16x8 aq[2][4];
  #pragma unroll
  for(int m = 0; m < 2; ++m){
    const u16* Q = qbf + ((size_t)h*2048 + qB*128 + w*32 + m*16) * 128;
    #pragma unroll
    for(int ks = 0; ks < 4; ++ks)
      aq[m][ks] = *(const bf16x8*)(Q + (lane & 15)*128 + ks*32 + ((lane >> 4) << 3));
  }
  f32x4 acc[2][8] = {};
  float lsum[2][4] = {};
  const float scale = 0.08838834764831845f;
  int qr0[2];
  #pragma unroll
  for(int m = 0; m < 2; ++m) qr0[m] = qB*128 + w*32 + m*16 + ((lane >> 4) << 2);
  u16* plw = &pl[w][0];
  bf16x8 kb[8];
  #pragma unroll
  for(int ct = 0; ct < 2; ++ct)
    #pragma unroll
    for(int ks = 0; ks < 4; ++ks)
      kb[ct*4+ks] = *(const bf16x8*)(K + (size_t)(kt0*32 + ct*16 + (lane & 15))*128 + ks*32 + ((lane >> 4) << 3));
  int buf = 0;
  for(int kt = kt0; kt < kt1; ++kt){
    f32x4 s[2][2] = {};
    #pragma unroll
    for(int m = 0; m < 2; ++m)
      #pragma unroll
      for(int ct = 0; ct < 2; ++ct)
        #pragma unroll
        for(int ks = 0; ks < 4; ++ks)
          s[m][ct] = MFMA16(aq[m][ks], kb[ct*4+ks], s[m][ct]);
    bf16x8 kbn[8];
    if(kt + 1 < kt1){
      #pragma unroll
      for(int ct = 0; ct < 2; ++ct)
        #pragma unroll
        for(int ks = 0; ks < 4; ++ks)
          kbn[ct*4+ks] = *(const bf16x8*)(K + (size_t)((kt+1)*32 + ct*16 + (lane & 15))*128 + ks*32 + ((lane >> 4) << 3));
    }
    bf16x8 bv[8];
    #pragma unroll
    for(int nt = 0; nt < 8; ++nt)
      bv[nt] = *(const bf16x8*)(V + (size_t)(nt*16 + (lane & 15))*2048 + kt*32 + ((lane >> 4) << 3));
    #pragma unroll
    for(int m = 0; m < 2; ++m)
      #pragma unroll
      for(int ct = 0; ct < 2; ++ct)
        #pragma unroll
        for(int r = 0; r < 4; ++r){
          int col = kt*32 + ct*16 + (lane & 15);
          float p = (col <= qr0[m] + r) ? __expf(s[m][ct][r] * scale) : 0.f;
          lsum[m][r] += p;
          int row = m*16 + ((lane >> 4) << 2) + r;
          *(u16*)((char*)plw + buf*2560 + row*80 + (ct*16 + (lane & 15))*2) = f2bf(p);
        }
    __builtin_amdgcn_s_setprio(1);
    #pragma unroll
    for(int m = 0; m < 2; ++m){
      bf16x8 ap = *(const bf16x8*)((const char*)plw + buf*2560 + (m*16 + (lane & 15))*80 + ((lane >> 4) << 4));
      #pragma unroll
      for(int nt = 0; nt < 8; ++nt)
        acc[m][nt] = MFMA16(ap, bv[nt], acc[m][nt]);
    }
    __builtin_amdgcn_s_setprio(0);
    #pragma unroll
    for(int i = 0; i < 8; ++i) kb[i] = kbn[i];
    buf ^= 1;
  }
  #pragma unroll
  for(int m = 0; m < 2; ++m)
    #pragma unroll
    for(int r = 0; r < 4; ++r){
      float v = lsum[m][r];
      v += __shfl_xor(v, 1, 64); v += __shfl_xor(v, 2, 64);
      v += __shfl_xor(v, 4, 64); v += __shfl_xor(v, 8, 64);
      lsum[m][r] = v;
    }
  if(slot < 0){
    #pragma unroll
    for(int m = 0; m < 2; ++m)
      #pragma unroll
      for(int nt = 0; nt < 8; ++nt)
        #pragma unroll
        for(int r = 0; r < 4; ++r){
          int row = qB*128 + w*32 + m*16 + ((lane >> 4) << 2) + r;
          int d = nt*16 + (lane & 15);
          size_t o = (size_t)row*2048 + h*128 + d;
          float fin = omix[o] + 0.5f * acc[m][nt][r] / lsum[m][r];
          obf[o] = f2bf(fin);
        }
  } else {
    float* P = slotp(part1, part2, slot);
    #pragma unroll
    for(int m = 0; m < 2; ++m)
      #pragma unroll
      for(int nt = 0; nt < 8; ++nt)
        #pragma unroll
        for(int r = 0; r < 4; ++r){
          int row = w*32 + m*16 + ((lane >> 4) << 2) + r;
          int d = nt*16 + (lane & 15);
          P[(size_t)row*128 + d] = acc[m][nt][r];
        }
    if((lane & 15) == 0)
      #pragma unroll
      for(int m = 0; m < 2; ++m)
        #pragma unroll
        for(int r = 0; r < 4; ++r)
          P[16384 + w*32 + m*16 + ((lane >> 4) << 2) + r] = lsum[m][r];
  }
}

// ---------------- combine attention K-segments; writes final bf16 omix ----------------
__global__ __launch_bounds__(256) void k_acomb(const float* __restrict__ part1, const float* __restrict__ part2,
                                               const float* __restrict__ omix, u16* __restrict__ obf){
  int bid = blockIdx.x;             // h*12 + (qB-4)
  int h = bid / 12, qx = bid % 12, qB = 4 + qx;
  int nseg = (qB >= 12) ? 4 : (qB >= 8) ? 3 : 2;
  int off = (qB < 8) ? (qB-4)*2 : (qB < 12) ? 8 + (qB-8)*3 : 20 + (qB-12)*4;
  int s0 = h*36 + off;
  int tid = threadIdx.x;
  #pragma unroll
  for(int it = 0; it < 16; ++it){
    int i = it*1024 + tid*4;
    int row = i >> 7;
    f32x4 a = {};
    float l = 0.f;
    for(int s = 0; s < nseg; ++s){
      const float* P = slotpc(part1, part2, s0 + s);
      a += *(const f32x4*)(P + i);
      l += P[16384 + row];
    }
    size_t idx = (size_t)(qB*128 + row)*2048 + h*128 + (i & 127);
    f32x4 cur = *(const f32x4*)(omix + idx);
    f32x4 fin = cur + a * (0.5f / l);
    u32 w0 = (u32)f2bf(fin[0]) | ((u32)f2bf(fin[1]) << 16);
    u32 w1 = (u32)f2bf(fin[2]) | ((u32)f2bf(fin[3]) << 16);
    *(u32*)(obf + idx) = w0;
    *(u32*)(obf + idx + 2) = w1;
  }
}

// ---------------- launch ----------------
extern "C" void kernel_launch(void* const* d_in, const int* in_sizes, int n_in,
                              void* d_out, int out_size, void* d_ws, size_t ws_size,
                              hipStream_t stream){
  (void)in_sizes; (void)n_in; (void)out_size; (void)ws_size;
  const float* hs = (const float*)d_in[0];
  const float* Wq = (const float*)d_in[1];
  const float* Wk = (const float*)d_in[2];
  const float* Wv = (const float*)d_in[3];
  const float* Wo = (const float*)d_in[4];
  float* out = (float*)d_out;
  char* ws = (char*)d_ws;

  u16*   hs_bf   = (u16*)(ws + OF_HSBF);
  u16*   wqkv_bf = (u16*)(ws + OF_WQKVBF);
  u16*   wo_bf   = (u16*)(ws + OF_WOBF);
  float* qkv     = (float*)(ws + OF_QKV);
  u16*   qbf     = (u16*)(ws + OF_QBF);
  u16*   kbf     = (u16*)(ws + OF_KBF);
  u16*   vT      = (u16*)(ws + OF_VT);
  u16*   qlb     = (u16*)(ws + OF_QLB);
  float* klf     = (float*)(ws + OF_KLF);
  u16*   klb     = (u16*)(ws + OF_KLB);
  float* glf     = (float*)(ws + OF_GLF);
  float* tinvb   = (float*)(ws + OF_TINV);
  float* wf      = (float*)(ws + OF_WF);
  u16*   wb      = (u16*)(ws + OF_WB);
  float* u0f     = (float*)(ws + OF_U0);
  u16*   sjb     = (u16*)(ws + OF_SJ);
  float* omix    = (float*)(ws + OF_OMIX);
  u16*   obf     = (u16*)(ws + OF_OBF);
  float* aDF  = (float*)(ws + OF_ADF);
  u16*   aDH  = (u16*)(ws + OF_ADH);
  u16*   aDL  = (u16*)(ws + OF_ADL);
  u16*   aDTH = (u16*)(ws + OF_ADTH);
  u16*   aDTL = (u16*)(ws + OF_ADTL);
  float* aBTF = (float*)(ws + OF_ABTF);
  u16*   aBTH = (u16*)(ws + OF_ABTH);
  u16*   aBTL = (u16*)(ws + OF_ABTL);
  float* bDF  = (float*)(ws + OF_BDF);
  u16*   bDH  = (u16*)(ws + OF_BDH);
  u16*   bDL  = (u16*)(ws + OF_BDL);
  u16*   bDTH = (u16*)(ws + OF_BDTH);
  u16*   bDTL = (u16*)(ws + OF_BDTL);
  float* bBTF = (float*)(ws + OF_BBTF);
  u16*   bBTH = (u16*)(ws + OF_BBTH);
  u16*   bBTL = (u16*)(ws + OF_BBTL);
  float* ttF  = (float*)(ws + OF_TTF);
  u16*   ttH  = (u16*)(ws + OF_TTH);
  u16*   ttL  = (u16*)(ws + OF_TTL);
  float* pDF  = (float*)(ws + OF_PDF);
  float* pBTF = (float*)(ws + OF_PBTF);
  u16*   pDH  = (u16*)(ws + OF_PDH);
  u16*   pDL  = (u16*)(ws + OF_PDL);
  u16*   pDTH = (u16*)(ws + OF_PDTH);
  u16*   pDTL = (u16*)(ws + OF_PDTL);
  u16*   pBTH = (u16*)(ws + OF_PBTH);
  u16*   pBTL = (u16*)(ws + OF_PBTL);
  float* apart1 = (float*)(ws + OF_APART1);
  float* apart2 = (float*)(ws + OF_APART2);

  k_f2ball<<<14336, 256, 0, stream>>>(hs, Wq, Wk, Wv, Wo, hs_bf, wqkv_bf, wo_bf);
  k_gemm<<<dim3(24, 16), 256, 0, stream>>>(hs_bf, wqkv_bf, qkv, 2048, 3072);
  k_linvt<<<10496, 256, 0, stream>>>(qkv, qbf, qlb, kbf, klf, klb, glf, vT);

  k_prep1<<<128, 256, 0, stream>>>(klf, glf, tinvb);
  k_prep2a<<<128, 256, 0, stream>>>(klf, glf, qkv, tinvb, wf, wb, u0f);
  k_prep2b<<<128, 256, 0, stream>>>(klf, wf, u0f, aDF, aDH, aDL, aDTH, aDTL, aBTF, aBTH, aBTL);

  k_ks<<<dim3(32, 4, 2), 256, 0, stream>>>(aDF, aDH, aDL, aDTH, aDTL, aBTF, aBTH, aBTL,
                                           bDF, bDH, bDL, bDTH, bDTL, bBTF, bBTH, bBTL, 1);
  k_ks<<<dim3(32, 4, 2), 256, 0, stream>>>(bDF, bDH, bDL, bDTH, bDTL, bBTF, bBTH, bBTL,
                                           aDF, aDH, aDL, aDTH, aDTL, aBTF, aBTH, aBTL, 2);
  k_ks<<<dim3(32, 4, 2), 256, 0, stream>>>(aDF, aDH, aDL, aDTH, aDTL, aBTF, aBTH, aBTL,
                                           bDF, bDH, bDL, bDTH, bDTL, bBTF, bBTH, bBTL, 4);
  k_ks<<<dim3(32, 4, 2), 256, 0, stream>>>(bDF, bDH, bDL, bDTH, bDTL, bBTF, bBTH, bBTL,
                                           aDF, aDH, aDL, aDTH, aDTL, aBTF, aBTH, aBTL, 8);
  k_ks<<<dim3(32, 4, 2), 256, 0, stream>>>(aDF, aDH, aDL, aDTH, aDTL, aBTF, aBTH, aBTL,
                                           bDF, bDH, bDL, bDTH, bDTL, bBTF, bBTH, bBTL, 16);

  // powers: per-group chain Phi^2 -> Phi^3 -> Phi^4 (4 blocks)
  ChainJobs jp{};
  for(int g = 0; g < 4; ++g){
    jp.cnt[g] = 3;
    jp.a[g][0] = g*32+31; jp.b[g][0] = g*32+31; jp.d[g][0] = 128+g;
    jp.a[g][1] = 128+g;   jp.b[g][1] = g*32+31; jp.d[g][1] = 132+g;
    jp.a[g][2] = 128+g;   jp.b[g][2] = 128+g;   jp.d[g][2] = 136+g;
  }
  k_compchain<<<4, 256, 0, stream>>>(bDF, bDH, bDL, bDTH, bDTL, bBTF, bBTH, bBTL,
                                     pDF, pDH, pDL, pDTH, pDTL, pBTF, pBTH, pBTL, jp);
  // prefixes: block0: Psi2; block1: T then Psi3
  ChainJobs jq{};
  jq.cnt[0] = 1; jq.a[0][0] = 137; jq.b[0][0] = 136; jq.d[0][0] = 140;
  jq.cnt[1] = 2; jq.a[1][0] = 138; jq.b[1][0] = 137; jq.d[1][0] = 141;
                 jq.a[1][1] = 141; jq.b[1][1] = 136; jq.d[1][1] = 142;
  k_compchain<<<2, 256, 0, stream>>>(bDF, bDH, bDL, bDTH, bDTL, bBTF, bBTH, bBTL,
                                     pDF, pDH, pDL, pDTH, pDTL, pBTF, pBTH, pBTL, jq);

  k_heads<<<16, 256, 0, stream>>>(bDH, bDL, bBTF, bBTH, bBTL,
                                  pDH, pDL, pBTF, pBTH, pBTL, ttF, ttH, ttL, sjb);
  k_expand<<<512, 256, 0, stream>>>(bDH, bDL, bBTF, ttF, ttH, ttL, sjb);

  k_olin<<<512, 256, 0, stream>>>(qlb, klb, wb, u0f, sjb, omix);
  k_attn<<<640, 256, 0, stream>>>(qbf, kbf, vT, omix, obf, apart1, apart2);
  k_acomb<<<192, 256, 0, stream>>>(apart1, apart2, omix, obf);

  k_gemm<<<dim3(16, 16), 256, 0, stream>>>(obf, wo_bf, out, 2048, 2048);
}

// Round 9
// 705.787 us; speedup vs baseline: 1.2923x; 1.2923x over previous
//
#include <hip/hip_runtime.h>
#include <hip/hip_bf16.h>

typedef unsigned short u16;
typedef unsigned int u32;
typedef __bf16 bf16x8 __attribute__((ext_vector_type(8)));
typedef float f32x4 __attribute__((ext_vector_type(4)));

#define MFMA16(a,b,c) __builtin_amdgcn_mfma_f32_16x16x32_bf16((a),(b),(c),0,0,0)

__device__ __forceinline__ u16 f2bf(float f){
  u32 u = __builtin_bit_cast(u32, f);
  u32 r = (u + 0x7fffu + ((u >> 16) & 1u)) >> 16;
  return (u16)r;
}
__device__ __forceinline__ float bf2f(u16 h){
  u32 u = ((u32)h) << 16;
  return __builtin_bit_cast(float, u);
}
__device__ __forceinline__ void splitbf(float x, u16& hi, u16& lo){
  hi = f2bf(x);
  lo = f2bf(x - bf2f(hi));
}
__device__ __forceinline__ void gload_lds16(const u16* g, u16* l){
  __builtin_amdgcn_global_load_lds((__attribute__((address_space(1))) void*)(g),
                                   (__attribute__((address_space(3))) void*)(l), 16, 0, 0);
}
__device__ __forceinline__ const u16* selu(const u16* barr, const u16* parr, int i){
  return (i < 128) ? (barr + (size_t)i*16384) : (parr + (size_t)(i-128)*16384);
}
__device__ __forceinline__ const float* self32(const float* barr, const float* parr, int i){
  return (i < 128) ? (barr + (size_t)i*16384) : (parr + (size_t)(i-128)*16384);
}
// attention partial slots: 16512 f32 each (128x128 acc + 128 lsum)
__device__ __forceinline__ float* slotp(float* p1, float* p2, int s){
  return (s < 381) ? (p1 + (size_t)s*16512) : (p2 + (size_t)(s-381)*16512);
}
__device__ __forceinline__ const float* slotpc(const float* p1, const float* p2, int s){
  return (s < 381) ? (p1 + (size_t)s*16512) : (p2 + (size_t)(s-381)*16512);
}

// ---------------- workspace layout (bytes) ----------------
constexpr size_t OF_HSBF   = 0;           // hs bf16 (dead after gemm1); then BDTH/BDTL; then obf
constexpr size_t OF_WQKVBF = 8388608;     // Wqkv bf16 (dead after gemm1)
constexpr size_t OF_WOBF   = 20971520;    // Wo bf16 [2048][2048]
constexpr size_t OF_QKV    = 29360128;    // qkv f32 (dead after prep2a/vt)
constexpr size_t OF_QBF    = 54525952;    // raw q bf16 [16][2048][128]
constexpr size_t OF_KBF    = 62914560;    // raw k bf16 [4][2048][128]
constexpr size_t OF_VT     = 65011712;    // vT bf16 [4][128][2048]
constexpr size_t OF_QLB    = 67108864;    // softmax q bf16 [16][2048][128]
constexpr size_t OF_KLF    = 75497472;    // softmax k f32 (dead after prep2b)
constexpr size_t OF_KLB    = 79691776;    // softmax k bf16
constexpr size_t OF_GLF    = 81788928;    // gate f32 (dead after prep2a)
constexpr size_t OF_TINV   = 85983232;    // Tinv f32 (dead after prep2a)
constexpr size_t OF_WF     = 88080384;    // w f32 (dead after prep2b)
constexpr size_t OF_WB     = 92274688;    // w bf16
constexpr size_t OF_U0     = 94371840;    // u0 f32 [128][64][128]
constexpr size_t OF_SJ     = 111149056;   // S^T states bf16 [512][128][128]
constexpr size_t OF_OMIX   = 127926272;   // f32 [2048][2048] (written by olin)
constexpr size_t OF_OMIXB  = 144703488;   // old omix_bf region; now apart2 only
// scan operator buffers:
constexpr size_t OF_ADF  = 102760448;             // D f32 8MB (side A)
constexpr size_t OF_ABTF = OF_OMIX;               // BT f32 8MB
constexpr size_t OF_ADH  = OF_OMIX + 8388608;     // D hi 4MB
constexpr size_t OF_ADL  = OF_OMIX + 12582912;    // D lo 4MB
constexpr size_t OF_ADTH = OF_OMIXB;              // D^T hi 4MB
constexpr size_t OF_ADTL = OF_OMIXB + 4194304;    // D^T lo 4MB
constexpr size_t OF_ABTH = OF_KLF;                // BT hi 4MB
constexpr size_t OF_ABTL = OF_GLF;                // BT lo 4MB
// side B:
constexpr size_t OF_BDF  = OF_QKV;                // 8MB
constexpr size_t OF_BBTF = OF_QKV + 8388608;      // 8MB
constexpr size_t OF_BDH  = OF_QKV + 16777216;     // 4MB
constexpr size_t OF_BDL  = OF_QKV + 20971520;     // 4MB
constexpr size_t OF_BDTH = OF_HSBF;               // 4MB
constexpr size_t OF_BDTL = OF_HSBF + 4194304;     // 4MB
constexpr size_t OF_BBTH = OF_WQKVBF;             // 4MB
constexpr size_t OF_BBTL = OF_WQKVBF + 4194304;   // 4MB
// head-start states
constexpr size_t OF_TTF  = OF_TINV;               // 1MB
constexpr size_t OF_TTH  = OF_WQKVBF + 8388608;   // 512KB
constexpr size_t OF_TTL  = OF_WQKVBF + 8912896;   // 512KB
// op pool (overlaid on dead side-A DF region):
constexpr size_t OF_PDF  = OF_ADF;
constexpr size_t OF_PBTF = OF_ADF + 1048576;
constexpr size_t OF_PDH  = OF_ADF + 2097152;
constexpr size_t OF_PDL  = OF_ADF + 2621440;
constexpr size_t OF_PDTH = OF_ADF + 3145728;
constexpr size_t OF_PDTL = OF_ADF + 3670016;
constexpr size_t OF_PBTH = OF_ADF + 4194304;
constexpr size_t OF_PBTL = OF_ADF + 4718592;
// attention K-split partial slots: 381 in dead qkv region + 195 at old omix_bf region
constexpr size_t OF_APART1 = OF_QKV;
constexpr size_t OF_APART2 = OF_OMIXB;
// final bf16 omix at ws+0 (BDTH/BDTL dead after last compose)
constexpr size_t OF_OBF = 0;

struct CompJobs { int a[8]; int b[8]; int d[8]; };

// ---------------- fused f2b of all 5 inputs ----------------
__global__ void k_f2ball(const float* __restrict__ hs, const float* __restrict__ Wq,
                         const float* __restrict__ Wk, const float* __restrict__ Wv,
                         const float* __restrict__ Wo, u16* __restrict__ hs_bf,
                         u16* __restrict__ wqkv_bf, u16* __restrict__ wo_bf){
  int bid = blockIdx.x;
  const float* src; u16* dst; int off;
  if(bid < 4096){ src = hs; dst = hs_bf; off = bid; }
  else if(bid < 8192){ src = Wq; dst = wqkv_bf; off = bid - 4096; }
  else if(bid < 9216){ src = Wk; dst = wqkv_bf + 2048*2048; off = bid - 8192; }
  else if(bid < 10240){ src = Wv; dst = wqkv_bf + 2560*2048; off = bid - 9216; }
  else { src = Wo; dst = wo_bf; off = bid - 10240; }
  int i = (off*256 + threadIdx.x) * 4;
  f32x4 v = *(const f32x4*)(src + i);
  u32 w0 = (u32)f2bf(v[0]) | ((u32)f2bf(v[1]) << 16);
  u32 w1 = (u32)f2bf(v[2]) | ((u32)f2bf(v[3]) << 16);
  *(u32*)(dst + i) = w0;
  *(u32*)(dst + i + 2) = w1;
}

// ---------------- bf16 NT GEMM with XCD-chunked swizzle ----------------
__global__ __launch_bounds__(256) void k_gemm(const u16* __restrict__ A, const u16* __restrict__ B,
                                              float* __restrict__ C, int K, int N){
  __shared__ u16 aL[128*32];
  __shared__ u16 bL[128*32];
  int lin = blockIdx.y * gridDim.x + blockIdx.x;
  int nwg = gridDim.x * gridDim.y;
  int s = (lin & 7) * (nwg >> 3) + (lin >> 3);
  int bn = s % gridDim.x, bm = s / gridDim.x;
  int tid = threadIdx.x, lane = tid & 63, w = tid >> 6;
  int wm = w >> 1, wn = w & 1;
  f32x4 acc[4][4] = {};
  int nK = K >> 5;
  const u16* Abase = A + (size_t)bm * 128 * K;
  const u16* Bbase = B + (size_t)bn * 128 * K;
  for(int kt = 0; kt < nK; ++kt){
    __syncthreads();
    #pragma unroll
    for(int t = 0; t < 2; ++t){
      int row = t*64 + w*16 + (lane >> 2);
      int kc = (lane & 3) * 8;
      gload_lds16(Abase + (size_t)row*K + kt*32 + kc, &aL[(t*64 + w*16)*32]);
      gload_lds16(Bbase + (size_t)row*K + kt*32 + kc, &bL[(t*64 + w*16)*32]);
    }
    __syncthreads();
    bf16x8 af[4], bf[4];
    #pragma unroll
    for(int i = 0; i < 4; ++i){
      af[i] = *(const bf16x8*)&aL[(wm*64 + i*16 + (lane & 15))*32 + ((lane >> 4) << 3)];
      bf[i] = *(const bf16x8*)&bL[(wn*64 + i*16 + (lane & 15))*32 + ((lane >> 4) << 3)];
    }
    #pragma unroll
    for(int i = 0; i < 4; ++i)
      #pragma unroll
      for(int j = 0; j < 4; ++j)
        acc[i][j] = MFMA16(af[i], bf[j], acc[i][j]);
  }
  #pragma unroll
  for(int i = 0; i < 4; ++i)
    #pragma unroll
    for(int j = 0; j < 4; ++j)
      #pragma unroll
      for(int r = 0; r < 4; ++r){
        int row = bm*128 + wm*64 + i*16 + ((lane >> 4) << 2) + r;
        int col = bn*128 + wn*64 + j*16 + (lane & 15);
        C[(size_t)row * N + col] = acc[i][j][r];
      }
}

// ---------------- fused linprep + V-transpose ----------------
__global__ __launch_bounds__(256) void k_linvt(const float* __restrict__ qkv, u16* qbf, u16* qlb,
                                               u16* kbf, float* klf, u16* klb, float* glf,
                                               u16* __restrict__ vT){
  __shared__ float t[64][65];
  int bid = blockIdx.x;
  if(bid < 10240){
    int gtask = bid * 4 + (threadIdx.x >> 6);
    int lane = threadIdx.x & 63;
    int n = gtask / 20, tt = gtask % 20;
    const float* row = (tt < 16) ? (qkv + (size_t)n*3072 + tt*128)
                                 : (qkv + (size_t)n*3072 + 2048 + (tt-16)*128);
    float v0 = row[lane], v1 = row[lane + 64];
    float m = fmaxf(v0, v1);
    #pragma unroll
    for(int o = 1; o < 64; o <<= 1) m = fmaxf(m, __shfl_xor(m, o, 64));
    float e0 = __expf(v0 - m), e1 = __expf(v1 - m);
    float s = e0 + e1;
    #pragma unroll
    for(int o = 1; o < 64; o <<= 1) s += __shfl_xor(s, o, 64);
    float r0 = e0 / s, r1 = e1 / s;
    if(tt < 16){
      size_t base = ((size_t)tt*2048 + n) * 128;
      qbf[base + lane] = f2bf(v0); qbf[base + 64 + lane] = f2bf(v1);
      qlb[base + lane] = f2bf(r0); qlb[base + 64 + lane] = f2bf(r1);
    } else {
      int g = tt - 16;
      size_t base = ((size_t)g*2048 + n) * 128;
      kbf[base + lane] = f2bf(v0); kbf[base + 64 + lane] = f2bf(v1);
      klf[base + lane] = r0;       klf[base + 64 + lane] = r1;
      klb[base + lane] = f2bf(r0); klb[base + 64 + lane] = f2bf(r1);
      float g0 = (fminf(v0, 0.f) - log1pf(__expf(-fabsf(v0)))) * (1.f/16.f);
      float g1 = (fminf(v1, 0.f) - log1pf(__expf(-fabsf(v1)))) * (1.f/16.f);
      glf[base + lane] = g0; glf[base + 64 + lane] = g1;
    }
  } else {
    int v = bid - 10240;
    int nt = v & 31, dt = (v >> 5) & 1, g = v >> 6;
    int tid = threadIdx.x;
    {
      int r = tid >> 2, c0 = (tid & 3) * 16;
      const float* src = qkv + (size_t)(nt*64 + r)*3072 + 2560 + g*128 + dt*64 + c0;
      #pragma unroll
      for(int q = 0; q < 16; q += 4){
        f32x4 vv = *(const f32x4*)(src + q);
        t[r][c0+q] = vv[0]; t[r][c0+q+1] = vv[1]; t[r][c0+q+2] = vv[2]; t[r][c0+q+3] = vv[3];
      }
    }
    __syncthreads();
    {
      int d = tid >> 2, c0 = (tid & 3) * 16;
      u16* dst = vT + ((size_t)g*128 + dt*64 + d)*2048 + (size_t)nt*64 + c0;
      #pragma unroll
      for(int half = 0; half < 2; ++half){
        int b = c0 + half*8;
        u32 w0 = (u32)f2bf(t[b+0][d]) | ((u32)f2bf(t[b+1][d]) << 16);
        u32 w1 = (u32)f2bf(t[b+2][d]) | ((u32)f2bf(t[b+3][d]) << 16);
        u32 w2 = (u32)f2bf(t[b+4][d]) | ((u32)f2bf(t[b+5][d]) << 16);
        u32 w3 = (u32)f2bf(t[b+6][d]) | ((u32)f2bf(t[b+7][d]) << 16);
        *(uint4*)(dst + half*8) = make_uint4(w0, w1, w2, w3);
      }
    }
  }
}

// ---------------- prep1 ----------------
__global__ __launch_bounds__(256) void k_prep1(const float* __restrict__ klf, const float* __restrict__ glf,
                                               float* __restrict__ tinv){
  __shared__ float KlT[128][68];
  __shared__ float Kb[64][132];
  __shared__ float Am[64][68];
  __shared__ float XT[64][68];
  int idx = blockIdx.x, g = idx >> 5, c = idx & 31, tid = threadIdx.x;
  size_t base = ((size_t)g*2048 + c*64) * 128;
  {
    int r = tid >> 2, d0 = (tid & 3) * 32;
    #pragma unroll
    for(int dd = 0; dd < 32; dd += 4){
      f32x4 kv = *(const f32x4*)(klf + base + r*128 + d0 + dd);
      f32x4 gv = *(const f32x4*)(glf + base + r*128 + d0 + dd);
      KlT[d0+dd][r] = kv[0]; KlT[d0+dd+1][r] = kv[1]; KlT[d0+dd+2][r] = kv[2]; KlT[d0+dd+3][r] = kv[3];
      f32x4 kb = kv * gv;
      *(f32x4*)&Kb[r][d0+dd] = kb;
    }
  }
  __syncthreads();
  {
    int i = tid >> 2, j0 = (tid & 3) * 16;
    f32x4 s[4] = {};
    for(int d = 0; d < 128; ++d){
      float kb = Kb[i][d];
      #pragma unroll
      for(int q = 0; q < 4; ++q){
        f32x4 kl = *(const f32x4*)&KlT[d][j0 + q*4];
        s[q] += kb * kl;
      }
    }
    #pragma unroll
    for(int q = 0; q < 4; ++q) *(f32x4*)&Am[i][j0 + q*4] = s[q];
  }
  __syncthreads();
  if(tid < 64){
    int cc = tid;
    float x0 = (cc == 0) ? 1.f : 0.f;
    XT[cc][0] = x0;
    tinv[(size_t)idx*4096 + cc] = x0;
    for(int i = 1; i < 64; ++i){
      float s = (i == cc) ? 1.f : 0.f;
      int i4 = i & ~3;
      for(int jj = 0; jj < i4; jj += 4){
        f32x4 av = *(const f32x4*)&Am[i][jj];
        f32x4 xv = *(const f32x4*)&XT[cc][jj];
        s -= av[0]*xv[0] + av[1]*xv[1] + av[2]*xv[2] + av[3]*xv[3];
      }
      for(int jj = i4; jj < i; ++jj) s -= Am[i][jj] * XT[cc][jj];
      XT[cc][i] = s;
      tinv[(size_t)idx*4096 + i*64 + cc] = s;
    }
  }
}

// ---------------- prep2a ----------------
__global__ __launch_bounds__(256) void k_prep2a(const float* __restrict__ klf, const float* __restrict__ glf,
                                                const float* __restrict__ qkv, const float* __restrict__ tinv,
                                                float* __restrict__ wf, u16* __restrict__ wb, float* __restrict__ u0f){
  __shared__ float Ti[64][68];
  __shared__ float B1[64][132];
  __shared__ float B2[64][132];
  int idx = blockIdx.x, g = idx >> 5, c = idx & 31, tid = threadIdx.x;
  size_t base = ((size_t)g*2048 + c*64) * 128;
  {
    int r = tid >> 2, d0 = (tid & 3) * 32;
    #pragma unroll
    for(int dd = 0; dd < 32; dd += 4){
      f32x4 kv = *(const f32x4*)(klf + base + r*128 + d0 + dd);
      f32x4 gv = *(const f32x4*)(glf + base + r*128 + d0 + dd);
      f32x4 vv = *(const f32x4*)(qkv + (size_t)(c*64 + r)*3072 + 2560 + g*128 + d0 + dd);
      *(f32x4*)&B1[r][d0+dd] = kv * gv;
      *(f32x4*)&B2[r][d0+dd] = vv * gv;
    }
    int c0 = (tid & 3) * 16;
    #pragma unroll
    for(int q = 0; q < 16; q += 4)
      *(f32x4*)&Ti[r][c0+q] = *(const f32x4*)(tinv + (size_t)idx*4096 + r*64 + c0 + q);
  }
  __syncthreads();
  int i = tid >> 2, cc0 = (tid & 3) * 32;
  f32x4 wa[8] = {}; f32x4 ua[8] = {};
  for(int jj = 0; jj < 64; ++jj){
    float a = Ti[i][jj];
    #pragma unroll
    for(int q = 0; q < 8; ++q){
      f32x4 b1 = *(const f32x4*)&B1[jj][cc0 + q*4];
      f32x4 b2 = *(const f32x4*)&B2[jj][cc0 + q*4];
      wa[q] += a * b1; ua[q] += a * b2;
    }
  }
  #pragma unroll
  for(int q = 0; q < 8; ++q){
    *(f32x4*)(wf + (size_t)idx*8192 + i*128 + cc0 + q*4) = wa[q];
    *(f32x4*)(u0f + (size_t)idx*8192 + i*128 + cc0 + q*4) = ua[q];
    u32 w0 = (u32)f2bf(wa[q][0]) | ((u32)f2bf(wa[q][1]) << 16);
    u32 w1 = (u32)f2bf(wa[q][2]) | ((u32)f2bf(wa[q][3]) << 16);
    u32* dst = (u32*)(wb + (size_t)idx*8192 + i*128 + cc0 + q*4);
    dst[0] = w0; dst[1] = w1;
  }
}

// ---------------- prep2b ----------------
__global__ __launch_bounds__(256) void k_prep2b(const float* __restrict__ klf, const float* __restrict__ wf,
                                                const float* __restrict__ u0f,
                                                float* __restrict__ dF, u16* __restrict__ dH, u16* __restrict__ dL,
                                                u16* __restrict__ dTH, u16* __restrict__ dTL,
                                                float* __restrict__ btF, u16* __restrict__ btH, u16* __restrict__ btL){
  __shared__ float Kl[64][132];
  __shared__ float Wm[64][132];
  __shared__ float Um[64][132];
  int idx = blockIdx.x, g = idx >> 5, c = idx & 31, tid = threadIdx.x;
  size_t base = ((size_t)g*2048 + c*64) * 128;
  {
    int r = tid >> 2, d0 = (tid & 3) * 32;
    #pragma unroll
    for(int dd = 0; dd < 32; dd += 4){
      *(f32x4*)&Kl[r][d0+dd] = *(const f32x4*)(klf + base + r*128 + d0 + dd);
      *(f32x4*)&Wm[r][d0+dd] = *(const f32x4*)(wf + (size_t)idx*8192 + r*128 + d0 + dd);
      *(f32x4*)&Um[r][d0+dd] = *(const f32x4*)(u0f + (size_t)idx*8192 + r*128 + d0 + dd);
    }
  }
  __syncthreads();
  int a = tid >> 1, b0 = (tid & 1) * 64;
  f32x4 pa[16] = {}; f32x4 ca[16] = {};
  for(int r = 0; r < 64; ++r){
    float ka = Kl[r][a];
    float ua = Um[r][a];
    #pragma unroll
    for(int q = 0; q < 16; ++q){
      f32x4 wv = *(const f32x4*)&Wm[r][b0 + q*4];
      f32x4 kv = *(const f32x4*)&Kl[r][b0 + q*4];
      pa[q] += ka * wv;
      ca[q] += ua * kv;
    }
  }
  size_t ob = (size_t)idx * 16384;
  #pragma unroll
  for(int q = 0; q < 16; ++q){
    #pragma unroll
    for(int e = 0; e < 4; ++e){
      int b = b0 + q*4 + e;
      float dv = -pa[q][e];
      u16 dh, dl; splitbf(dv, dh, dl);
      dF[ob + a*128 + b] = dv;
      dH[ob + a*128 + b] = dh;
      dL[ob + a*128 + b] = dl;
      dTH[ob + (size_t)b*128 + a] = dh;
      dTL[ob + (size_t)b*128 + a] = dl;
      float cv = ca[q][e];
      u16 ch, cl; splitbf(cv, ch, cl);
      btF[ob + a*128 + b] = cv;
      btH[ob + a*128 + b] = ch;
      btL[ob + a*128 + b] = cl;
    }
  }
}

// ---------------- Kogge-Stone compose round (split-precision) ----------------
__global__ __launch_bounds__(256) void k_ks(
    const float* __restrict__ sDF, const u16* __restrict__ sDH, const u16* __restrict__ sDL,
    const u16* __restrict__ sDTH, const u16* __restrict__ sDTL,
    const float* __restrict__ sBF, const u16* __restrict__ sBH, const u16* __restrict__ sBL,
    float* __restrict__ dDF, u16* __restrict__ dDH, u16* __restrict__ dDL,
    u16* __restrict__ dDTH, u16* __restrict__ dDTL,
    float* __restrict__ dBF, u16* __restrict__ dBH, u16* __restrict__ dBL, int off){
  __shared__ float T[128][132];
  int c = blockIdx.x, g = blockIdx.y, z = blockIdx.z;
  int idx = g*32 + c, tid = threadIdx.x;
  size_t base = (size_t)idx * 16384;
  if(c < off){
    if(z == 0){
      for(int i = tid; i < 4096; i += 256) ((uint4*)(dDF + base))[i] = ((const uint4*)(sDF + base))[i];
      for(int i = tid; i < 2048; i += 256){
        ((uint4*)(dDH + base))[i] = ((const uint4*)(sDH + base))[i];
        ((uint4*)(dDL + base))[i] = ((const uint4*)(sDL + base))[i];
        ((uint4*)(dDTH + base))[i] = ((const uint4*)(sDTH + base))[i];
        ((uint4*)(dDTL + base))[i] = ((const uint4*)(sDTL + base))[i];
      }
    } else {
      for(int i = tid; i < 4096; i += 256) ((uint4*)(dBF + base))[i] = ((const uint4*)(sBF + base))[i];
      for(int i = tid; i < 2048; i += 256){
        ((uint4*)(dBH + base))[i] = ((const uint4*)(sBH + base))[i];
        ((uint4*)(dBL + base))[i] = ((const uint4*)(sBL + base))[i];
      }
    }
    return;
  }
  size_t blo = (size_t)(idx - off) * 16384;
  int lane = tid & 63, w = tid >> 6;
  const u16 *Ah, *Al, *Bh, *Bl;
  if(z == 0){ Ah = sDH + base; Al = sDL + base; Bh = sDTH + blo; Bl = sDTL + blo; }
  else      { Ah = sBH + blo;  Al = sBL + blo;  Bh = sDH + base; Bl = sDL + base; }
  f32x4 acc[2][8] = {};
  #pragma unroll
  for(int ks = 0; ks < 4; ++ks){
    bf16x8 ah[2], al[2], bh[8], bl[8];
    #pragma unroll
    for(int mt = 0; mt < 2; ++mt){
      int ro = (w*32 + mt*16 + (lane & 15))*128 + ks*32 + ((lane >> 4) << 3);
      ah[mt] = *(const bf16x8*)(Ah + ro);
      al[mt] = *(const bf16x8*)(Al + ro);
    }
    #pragma unroll
    for(int nt = 0; nt < 8; ++nt){
      int ro = (nt*16 + (lane & 15))*128 + ks*32 + ((lane >> 4) << 3);
      bh[nt] = *(const bf16x8*)(Bh + ro);
      bl[nt] = *(const bf16x8*)(Bl + ro);
    }
    #pragma unroll
    for(int mt = 0; mt < 2; ++mt)
      #pragma unroll
      for(int nt = 0; nt < 8; ++nt)
        acc[mt][nt] = MFMA16(ah[mt], bh[nt],
                      MFMA16(ah[mt], bl[nt],
                      MFMA16(al[mt], bh[nt], acc[mt][nt])));
  }
  if(z == 0){
    #pragma unroll
    for(int mt = 0; mt < 2; ++mt)
      #pragma unroll
      for(int nt = 0; nt < 8; ++nt)
        #pragma unroll
        for(int r = 0; r < 4; ++r){
          int row = w*32 + mt*16 + ((lane >> 4) << 2) + r;
          int col = nt*16 + (lane & 15);
          float v = acc[mt][nt][r] + sDF[base + row*128 + col] + sDF[blo + row*128 + col];
          dDF[base + row*128 + col] = v;
          u16 hi, lo; splitbf(v, hi, lo);
          dDH[base + row*128 + col] = hi;
          dDL[base + row*128 + col] = lo;
          T[row][col] = v;
        }
    __syncthreads();
    int tcol = tid >> 1, half = tid & 1;
    for(int m = 0; m < 64; ++m){
      float v = T[half*64 + m][tcol];
      u16 hi, lo; splitbf(v, hi, lo);
      dDTH[base + (size_t)tcol*128 + half*64 + m] = hi;
      dDTL[base + (size_t)tcol*128 + half*64 + m] = lo;
    }
  } else {
    #pragma unroll
    for(int mt = 0; mt < 2; ++mt)
      #pragma unroll
      for(int nt = 0; nt < 8; ++nt)
        #pragma unroll
        for(int r = 0; r < 4; ++r){
          int row = w*32 + mt*16 + ((lane >> 4) << 2) + r;
          int col = nt*16 + (lane & 15);
          float v = acc[mt][nt][r] + sBF[base + row*128 + col] + sBF[blo + row*128 + col];
          dBF[base + row*128 + col] = v;
          u16 hi, lo; splitbf(v, hi, lo);
          dBH[base + row*128 + col] = hi;
          dBL[base + row*128 + col] = lo;
        }
  }
}

// ---------------- hi/lo MFMA helper for 128x128 compose ----------------
__device__ __forceinline__ void comp_mfma(const u16* Ah, const u16* Al, const u16* Bh, const u16* Bl,
                                          f32x4 (&acc)[2][8], int lane, int w){
  #pragma unroll
  for(int ks = 0; ks < 4; ++ks){
    bf16x8 ah[2], al[2], bh[8], bl[8];
    #pragma unroll
    for(int mt = 0; mt < 2; ++mt){
      int ro = (w*32 + mt*16 + (lane & 15))*128 + ks*32 + ((lane >> 4) << 3);
      ah[mt] = *(const bf16x8*)(Ah + ro);
      al[mt] = *(const bf16x8*)(Al + ro);
    }
    #pragma unroll
    for(int nt = 0; nt < 8; ++nt){
      int ro = (nt*16 + (lane & 15))*128 + ks*32 + ((lane >> 4) << 3);
      bh[nt] = *(const bf16x8*)(Bh + ro);
      bl[nt] = *(const bf16x8*)(Bl + ro);
    }
    #pragma unroll
    for(int mt = 0; mt < 2; ++mt)
      #pragma unroll
      for(int nt = 0; nt < 8; ++nt)
        acc[mt][nt] = MFMA16(ah[mt], bh[nt],
                      MFMA16(ah[mt], bl[nt],
                      MFMA16(al[mt], bh[nt], acc[mt][nt])));
  }
}

// ---------------- generic compose with LDS-staged F-sums ----------------
// z=0: D' = D_a + D_b + D_a*D_b ; z=1: BT' = BT_a + BT_b + nt(BT_b, D_a)
__global__ __launch_bounds__(256) void k_comp(
    const float* __restrict__ bDF, const u16* __restrict__ bDH, const u16* __restrict__ bDL,
    const u16* __restrict__ bDTH, const u16* __restrict__ bDTL,
    const float* __restrict__ bBTF, const u16* __restrict__ bBTH, const u16* __restrict__ bBTL,
    float* __restrict__ pDF, u16* __restrict__ pDH, u16* __restrict__ pDL,
    u16* __restrict__ pDTH, u16* __restrict__ pDTL,
    float* __restrict__ pBTF, u16* __restrict__ pBTH, u16* __restrict__ pBTL,
    CompJobs jobs){
  __shared__ float T[128][132];
  int job = blockIdx.x, z = blockIdx.y, tid = threadIdx.x;
  int a = jobs.a[job], b = jobs.b[job], d = jobs.d[job] - 128;
  size_t ob = (size_t)d * 16384;
  int lane = tid & 63, w = tid >> 6;
  const u16 *Ah, *Al, *Bh, *Bl;
  const float *F1, *F2;
  if(z == 0){
    Ah = selu(bDH, pDH, a);  Al = selu(bDL, pDL, a);
    Bh = selu(bDTH, pDTH, b); Bl = selu(bDTL, pDTL, b);
    F1 = self32(bDF, pDF, a); F2 = self32(bDF, pDF, b);
  } else {
    Ah = selu(bBTH, pBTH, b); Al = selu(bBTL, pBTL, b);
    Bh = selu(bDH, pDH, a);   Bl = selu(bDL, pDL, a);
    F1 = self32(bBTF, pBTF, a); F2 = self32(bBTF, pBTF, b);
  }
  // stage F1+F2 into LDS via coalesced f32x4 loads
  for(int i = tid*4; i < 16384; i += 1024){
    f32x4 v1 = *(const f32x4*)(F1 + i);
    f32x4 v2 = *(const f32x4*)(F2 + i);
    f32x4 sv = v1 + v2;
    int row = i >> 7, col = i & 127;
    *(f32x4*)&T[row][col] = sv;
  }
  __syncthreads();
  f32x4 acc[2][8] = {};
  comp_mfma(Ah, Al, Bh, Bl, acc, lane, w);
  if(z == 0){
    #pragma unroll
    for(int mt = 0; mt < 2; ++mt)
      #pragma unroll
      for(int nt = 0; nt < 8; ++nt)
        #pragma unroll
        for(int r = 0; r < 4; ++r){
          int row = w*32 + mt*16 + ((lane >> 4) << 2) + r;
          int col = nt*16 + (lane & 15);
          float v = acc[mt][nt][r] + T[row][col];
          pDF[ob + row*128 + col] = v;
          u16 hi, lo; splitbf(v, hi, lo);
          pDH[ob + row*128 + col] = hi;
          pDL[ob + row*128 + col] = lo;
          T[row][col] = v;
        }
    __syncthreads();
    int tcol = tid >> 1, half = tid & 1;
    for(int m = 0; m < 64; ++m){
      float v = T[half*64 + m][tcol];
      u16 hi, lo; splitbf(v, hi, lo);
      pDTH[ob + (size_t)tcol*128 + half*64 + m] = hi;
      pDTL[ob + (size_t)tcol*128 + half*64 + m] = lo;
    }
  } else {
    #pragma unroll
    for(int mt = 0; mt < 2; ++mt)
      #pragma unroll
      for(int nt = 0; nt < 8; ++nt)
        #pragma unroll
        for(int r = 0; r < 4; ++r){
          int row = w*32 + mt*16 + ((lane >> 4) << 2) + r;
          int col = nt*16 + (lane & 15);
          float v = acc[mt][nt][r] + T[row][col];
          pBTF[ob + row*128 + col] = v;
          u16 hi, lo; splitbf(v, hi, lo);
          pBTH[ob + row*128 + col] = hi;
          pBTL[ob + row*128 + col] = lo;
        }
  }
}

// ---------------- head starts (parallel, LDS-staged F) ----------------
__global__ __launch_bounds__(256) void k_heads(
    const u16* __restrict__ bDH, const u16* __restrict__ bDL,
    const float* __restrict__ bBTF, const u16* __restrict__ bBTH, const u16* __restrict__ bBTL,
    const u16* __restrict__ pDH, const u16* __restrict__ pDL,
    const float* __restrict__ pBTF, const u16* __restrict__ pBTH, const u16* __restrict__ pBTL,
    float* __restrict__ ttF, u16* __restrict__ ttH, u16* __restrict__ ttL, u16* __restrict__ sj){
  __shared__ float T[128][132];
  int h = blockIdx.x, g = h >> 2, i0 = h & 3;
  int tid = threadIdx.x, lane = tid & 63, w = tid >> 6;
  int psi = (g == 0) ? -1 : (g == 1 ? 136 : (g == 2 ? 140 : 142));
  int phi = (i0 == 0) ? -1 : (i0 == 1 ? g*32 + 31 : (i0 == 2 ? 128 + g : 132 + g));
  const float* Pf = (psi >= 0) ? self32(bBTF, pBTF, psi) : nullptr;
  const float* Ff = (phi >= 0) ? self32(bBTF, pBTF, phi) : nullptr;
  for(int i = tid*4; i < 16384; i += 1024){
    f32x4 sv = {};
    if(Pf) sv += *(const f32x4*)(Pf + i);
    if(Ff) sv += *(const f32x4*)(Ff + i);
    int row = i >> 7, col = i & 127;
    *(f32x4*)&T[row][col] = sv;
  }
  __syncthreads();
  f32x4 acc[2][8] = {};
  if(psi >= 0 && phi >= 0)
    comp_mfma(selu(bBTH,pBTH,psi), selu(bBTL,pBTL,psi), selu(bDH,pDH,phi), selu(bDL,pDL,phi), acc, lane, w);
  #pragma unroll
  for(int mt = 0; mt < 2; ++mt)
    #pragma unroll
    for(int nt = 0; nt < 8; ++nt)
      #pragma unroll
      for(int r = 0; r < 4; ++r){
        int row = w*32 + mt*16 + ((lane >> 4) << 2) + r;
        int col = nt*16 + (lane & 15);
        float v = acc[mt][nt][r] + T[row][col];
        u16 hi, lo; splitbf(v, hi, lo);
        size_t o = (size_t)h*16384 + row*128 + col;
        ttF[o] = v; ttH[o] = hi; ttL[o] = lo;
        sj[(size_t)(h*32)*16384 + row*128 + col] = hi;
      }
}

// ---------------- expand ----------------
__global__ __launch_bounds__(256) void k_expand(const u16* __restrict__ bDH, const u16* __restrict__ bDL,
                                                const float* __restrict__ bBF, const float* __restrict__ ttF,
                                                const u16* __restrict__ ttH, const u16* __restrict__ ttL,
                                                u16* __restrict__ sj){
  int j = blockIdx.x;
  int c = j & 31;
  if(c == 0) return;
  int h = j >> 5, g = h >> 2;
  size_t obase = (size_t)j * 16384;
  size_t mb = (size_t)(g*32 + c - 1) * 16384;
  size_t tb = (size_t)h * 16384;
  int tid = threadIdx.x, lane = tid & 63, w = tid >> 6;
  f32x4 acc[2][8] = {};
  comp_mfma(ttH + tb, ttL + tb, bDH + mb, bDL + mb, acc, lane, w);
  #pragma unroll
  for(int mt = 0; mt < 2; ++mt)
    #pragma unroll
    for(int nt = 0; nt < 8; ++nt)
      #pragma unroll
      for(int r = 0; r < 4; ++r){
        int row = w*32 + mt*16 + ((lane >> 4) << 2) + r;
        int col = nt*16 + (lane & 15);
        float v = acc[mt][nt][r] + ttF[tb + row*128 + col] + bBF[mb + row*128 + col];
        sj[obase + row*128 + col] = f2bf(v);
      }
}

// ---------------- o_lin ----------------
__global__ __launch_bounds__(256) void k_olin(const u16* __restrict__ qlb, const u16* __restrict__ klb,
                                              const u16* __restrict__ wb, const float* __restrict__ u0f,
                                              const u16* __restrict__ sj, float* __restrict__ omix){
  __shared__ u16 ut[128*64];
  __shared__ u16 pl[4][16*64];
  int j = blockIdx.x;
  int h = j >> 5, c = j & 31, g = h >> 2, idx = g*32 + c;
  int tid = threadIdx.x, lane = tid & 63, w = tid >> 6;
  const u16* Sj = sj + (size_t)j * 16384;
  const u16* Q  = qlb + ((size_t)h*2048 + c*64) * 128;
  const u16* Kc = klb + ((size_t)g*2048 + c*64) * 128;
  const u16* W  = wb + (size_t)idx * 8192;
  const float* U0 = u0f + (size_t)idx * 8192;
  bf16x8 aq[4], aw[4];
  #pragma unroll
  for(int ks = 0; ks < 4; ++ks){
    aq[ks] = *(const bf16x8*)(Q + (w*16 + (lane & 15))*128 + ks*32 + ((lane >> 4) << 3));
    aw[ks] = *(const bf16x8*)(W + (w*16 + (lane & 15))*128 + ks*32 + ((lane >> 4) << 3));
  }
  f32x4 t1[8] = {}, ui[8] = {};
  #pragma unroll
  for(int ks = 0; ks < 4; ++ks)
    #pragma unroll
    for(int nt = 0; nt < 8; ++nt){
      bf16x8 b = *(const bf16x8*)(Sj + (nt*16 + (lane & 15))*128 + ks*32 + ((lane >> 4) << 3));
      t1[nt] = MFMA16(aq[ks], b, t1[nt]);
      ui[nt] = MFMA16(aw[ks], b, ui[nt]);
    }
  f32x4 sc[4] = {};
  #pragma unroll
  for(int ks = 0; ks < 4; ++ks)
    #pragma unroll
    for(int nt = 0; nt < 4; ++nt){
      bf16x8 b = *(const bf16x8*)(Kc + (nt*16 + (lane & 15))*128 + ks*32 + ((lane >> 4) << 3));
      sc[nt] = MFMA16(aq[ks], b, sc[nt]);
    }
  #pragma unroll
  for(int nt = 0; nt < 4; ++nt)
    #pragma unroll
    for(int r = 0; r < 4; ++r){
      int row = ((lane >> 4) << 2) + r;
      int col = nt*16 + (lane & 15);
      int grow = w*16 + row;
      float v = (col <= grow) ? sc[nt][r] : 0.f;
      int bo = (row*128 + col*2) ^ ((row & 7) << 4);
      *(u16*)((char*)&pl[w][0] + bo) = f2bf(v);
    }
  #pragma unroll
  for(int nt = 0; nt < 8; ++nt)
    #pragma unroll
    for(int r = 0; r < 4; ++r){
      int kv = w*16 + ((lane >> 4) << 2) + r;
      int d  = nt*16 + (lane & 15);
      float v = U0[kv*128 + d] - ui[nt][r];
      int bo = (d*128 + kv*2) ^ ((d & 7) << 4);
      *(u16*)((char*)ut + bo) = f2bf(v);
    }
  __syncthreads();
  f32x4 o2[8] = {};
  #pragma unroll
  for(int ks2 = 0; ks2 < 2; ++ks2){
    int row = lane & 15;
    int boA = (row*128 + ks2*64 + ((lane >> 4) << 4)) ^ ((row & 7) << 4);
    bf16x8 a = *(const bf16x8*)((const char*)&pl[w][0] + boA);
    #pragma unroll
    for(int nt = 0; nt < 8; ++nt){
      int d = nt*16 + (lane & 15);
      int boB = (d*128 + ks2*64 + ((lane >> 4) << 4)) ^ ((d & 7) << 4);
      bf16x8 b = *(const bf16x8*)((const char*)ut + boB);
      o2[nt] = MFMA16(a, b, o2[nt]);
    }
  }
  #pragma unroll
  for(int nt = 0; nt < 8; ++nt)
    #pragma unroll
    for(int r = 0; r < 4; ++r){
      int grow = c*64 + w*16 + ((lane >> 4) << 2) + r;
      int d = nt*16 + (lane & 15);
      omix[(size_t)grow*2048 + h*128 + d] = 0.5f * (t1[nt][r] + o2[nt][r]);
    }
}

// ---------------- base causal attention: head-major + XCD swizzle, dbuf P-LDS, K prefetch ----------------
__global__ __launch_bounds__(256) void k_attn(const u16* __restrict__ qbf, const u16* __restrict__ kbf,
                                              const u16* __restrict__ vT, const float* __restrict__ omix,
                                              u16* __restrict__ obf,
                                              float* __restrict__ part1, float* __restrict__ part2){
  __shared__ u16 pl[4][2560];
  int rb = blockIdx.x;
  int bid = (rb & 7) * 80 + (rb >> 3);   // XCD-chunked swizzle (640 % 8 == 0)
  int h = bid / 40, j = bid % 40;
  int qB, kt0, kt1, slot = -1;
  if(j < 4){ qB = j; kt0 = 0; kt1 = 4*(qB+1); }
  else {
    int jj = j - 4; int seg;
    if(jj < 8){ qB = 4 + (jj >> 1); seg = jj & 1; }
    else if(jj < 20){ int q = jj - 8; qB = 8 + q/3; seg = q - (qB-8)*3; }
    else { int q = jj - 20; qB = 12 + (q >> 2); seg = q & 3; }
    slot = h*36 + jj;
    kt0 = seg*16;
    int full = 4*(qB+1);
    kt1 = (kt0 + 16 < full) ? kt0 + 16 : full;
  }
  int g = h >> 2;
  int tid = threadIdx.x, lane = tid & 63, w = tid >> 6;
  const u16* K = kbf + (size_t)g*2048*128;
  const u16* V = vT + (size_t)g*128*2048;
  bf16x8 aq[2][4];
  #pragma unroll
  for(int m = 0; m < 2; ++m){
    const u16* Q = qbf + ((size_t)h*2048 + qB*128 + w*32 + m*16) * 128;
    #pragma unroll
    for(int ks = 0; ks < 4; ++ks)
      aq[m][ks] = *(const bf16x8*)(Q + (lane & 15)*128 + ks*32 + ((lane >> 4) << 3));
  }
  f32x4 acc[2][8] = {};
  float lsum[2][4] = {};
  const float scale = 0.08838834764831845f;
  int qr0[2];
  #pragma unroll
  for(int m = 0; m < 2; ++m) qr0[m] = qB*128 + w*32 + m*16 + ((lane >> 4) << 2);
  u16* plw = &pl[w][0];
  bf16x8 kb[8];
  #pragma unroll
  for(int ct = 0; ct < 2; ++ct)
    #pragma unroll
    for(int ks = 0; ks < 4; ++ks)
      kb[ct*4+ks] = *(const bf16x8*)(K + (size_t)(kt0*32 + ct*16 + (lane & 15))*128 + ks*32 + ((lane >> 4) << 3));
  int buf = 0;
  for(int kt = kt0; kt < kt1; ++kt){
    f32x4 s[2][2] = {};
    #pragma unroll
    for(int m = 0; m < 2; ++m)
      #pragma unroll
      for(int ct = 0; ct < 2; ++ct)
        #pragma unroll
        for(int ks = 0; ks < 4; ++ks)
          s[m][ct] = MFMA16(aq[m][ks], kb[ct*4+ks], s[m][ct]);
    bf16x8 kbn[8];
    if(kt + 1 < kt1){
      #pragma unroll
      for(int ct = 0; ct < 2; ++ct)
        #pragma unroll
        for(int ks = 0; ks < 4; ++ks)
          kbn[ct*4+ks] = *(const bf16x8*)(K + (size_t)((kt+1)*32 + ct*16 + (lane & 15))*128 + ks*32 + ((lane >> 4) << 3));
    }
    bf16x8 bv[8];
    #pragma unroll
    for(int nt = 0; nt < 8; ++nt)
      bv[nt] = *(const bf16x8*)(V + (size_t)(nt*16 + (lane & 15))*2048 + kt*32 + ((lane >> 4) << 3));
    #pragma unroll
    for(int m = 0; m < 2; ++m)
      #pragma unroll
      for(int ct = 0; ct < 2; ++ct)
        #pragma unroll
        for(int r = 0; r < 4; ++r){
          int col = kt*32 + ct*16 + (lane & 15);
          float p = (col <= qr0[m] + r) ? __expf(s[m][ct][r] * scale) : 0.f;
          lsum[m][r] += p;
          int row = m*16 + ((lane >> 4) << 2) + r;
          *(u16*)((char*)plw + buf*2560 + row*80 + (ct*16 + (lane & 15))*2) = f2bf(p);
        }
    __builtin_amdgcn_s_setprio(1);
    #pragma unroll
    for(int m = 0; m < 2; ++m){
      bf16x8 ap = *(const bf16x8*)((const char*)plw + buf*2560 + (m*16 + (lane & 15))*80 + ((lane >> 4) << 4));
      #pragma unroll
      for(int nt = 0; nt < 8; ++nt)
        acc[m][nt] = MFMA16(ap, bv[nt], acc[m][nt]);
    }
    __builtin_amdgcn_s_setprio(0);
    #pragma unroll
    for(int i = 0; i < 8; ++i) kb[i] = kbn[i];
    buf ^= 1;
  }
  #pragma unroll
  for(int m = 0; m < 2; ++m)
    #pragma unroll
    for(int r = 0; r < 4; ++r){
      float v = lsum[m][r];
      v += __shfl_xor(v, 1, 64); v += __shfl_xor(v, 2, 64);
      v += __shfl_xor(v, 4, 64); v += __shfl_xor(v, 8, 64);
      lsum[m][r] = v;
    }
  if(slot < 0){
    #pragma unroll
    for(int m = 0; m < 2; ++m)
      #pragma unroll
      for(int nt = 0; nt < 8; ++nt)
        #pragma unroll
        for(int r = 0; r < 4; ++r){
          int row = qB*128 + w*32 + m*16 + ((lane >> 4) << 2) + r;
          int d = nt*16 + (lane & 15);
          size_t o = (size_t)row*2048 + h*128 + d;
          float fin = omix[o] + 0.5f * acc[m][nt][r] / lsum[m][r];
          obf[o] = f2bf(fin);
        }
  } else {
    float* P = slotp(part1, part2, slot);
    #pragma unroll
    for(int m = 0; m < 2; ++m)
      #pragma unroll
      for(int nt = 0; nt < 8; ++nt)
        #pragma unroll
        for(int r = 0; r < 4; ++r){
          int row = w*32 + m*16 + ((lane >> 4) << 2) + r;
          int d = nt*16 + (lane & 15);
          P[(size_t)row*128 + d] = acc[m][nt][r];
        }
    if((lane & 15) == 0)
      #pragma unroll
      for(int m = 0; m < 2; ++m)
        #pragma unroll
        for(int r = 0; r < 4; ++r)
          P[16384 + w*32 + m*16 + ((lane >> 4) << 2) + r] = lsum[m][r];
  }
}

// ---------------- combine attention K-segments; writes final bf16 omix ----------------
__global__ __launch_bounds__(256) void k_acomb(const float* __restrict__ part1, const float* __restrict__ part2,
                                               const float* __restrict__ omix, u16* __restrict__ obf){
  int bid = blockIdx.x;             // h*12 + (qB-4)
  int h = bid / 12, qx = bid % 12, qB = 4 + qx;
  int nseg = (qB >= 12) ? 4 : (qB >= 8) ? 3 : 2;
  int off = (qB < 8) ? (qB-4)*2 : (qB < 12) ? 8 + (qB-8)*3 : 20 + (qB-12)*4;
  int s0 = h*36 + off;
  int tid = threadIdx.x;
  #pragma unroll
  for(int it = 0; it < 16; ++it){
    int i = it*1024 + tid*4;
    int row = i >> 7;
    f32x4 a = {};
    float l = 0.f;
    for(int s = 0; s < nseg; ++s){
      const float* P = slotpc(part1, part2, s0 + s);
      a += *(const f32x4*)(P + i);
      l += P[16384 + row];
    }
    size_t idx = (size_t)(qB*128 + row)*2048 + h*128 + (i & 127);
    f32x4 cur = *(const f32x4*)(omix + idx);
    f32x4 fin = cur + a * (0.5f / l);
    u32 w0 = (u32)f2bf(fin[0]) | ((u32)f2bf(fin[1]) << 16);
    u32 w1 = (u32)f2bf(fin[2]) | ((u32)f2bf(fin[3]) << 16);
    *(u32*)(obf + idx) = w0;
    *(u32*)(obf + idx + 2) = w1;
  }
}

// ---------------- launch ----------------
extern "C" void kernel_launch(void* const* d_in, const int* in_sizes, int n_in,
                              void* d_out, int out_size, void* d_ws, size_t ws_size,
                              hipStream_t stream){
  (void)in_sizes; (void)n_in; (void)out_size; (void)ws_size;
  const float* hs = (const float*)d_in[0];
  const float* Wq = (const float*)d_in[1];
  const float* Wk = (const float*)d_in[2];
  const float* Wv = (const float*)d_in[3];
  const float* Wo = (const float*)d_in[4];
  float* out = (float*)d_out;
  char* ws = (char*)d_ws;

  u16*   hs_bf   = (u16*)(ws + OF_HSBF);
  u16*   wqkv_bf = (u16*)(ws + OF_WQKVBF);
  u16*   wo_bf   = (u16*)(ws + OF_WOBF);
  float* qkv     = (float*)(ws + OF_QKV);
  u16*   qbf     = (u16*)(ws + OF_QBF);
  u16*   kbf     = (u16*)(ws + OF_KBF);
  u16*   vT      = (u16*)(ws + OF_VT);
  u16*   qlb     = (u16*)(ws + OF_QLB);
  float* klf     = (float*)(ws + OF_KLF);
  u16*   klb     = (u16*)(ws + OF_KLB);
  float* glf     = (float*)(ws + OF_GLF);
  float* tinvb   = (float*)(ws + OF_TINV);
  float* wf      = (float*)(ws + OF_WF);
  u16*   wb      = (u16*)(ws + OF_WB);
  float* u0f     = (float*)(ws + OF_U0);
  u16*   sjb     = (u16*)(ws + OF_SJ);
  float* omix    = (float*)(ws + OF_OMIX);
  u16*   obf     = (u16*)(ws + OF_OBF);
  float* aDF  = (float*)(ws + OF_ADF);
  u16*   aDH  = (u16*)(ws + OF_ADH);
  u16*   aDL  = (u16*)(ws + OF_ADL);
  u16*   aDTH = (u16*)(ws + OF_ADTH);
  u16*   aDTL = (u16*)(ws + OF_ADTL);
  float* aBTF = (float*)(ws + OF_ABTF);
  u16*   aBTH = (u16*)(ws + OF_ABTH);
  u16*   aBTL = (u16*)(ws + OF_ABTL);
  float* bDF  = (float*)(ws + OF_BDF);
  u16*   bDH  = (u16*)(ws + OF_BDH);
  u16*   bDL  = (u16*)(ws + OF_BDL);
  u16*   bDTH = (u16*)(ws + OF_BDTH);
  u16*   bDTL = (u16*)(ws + OF_BDTL);
  float* bBTF = (float*)(ws + OF_BBTF);
  u16*   bBTH = (u16*)(ws + OF_BBTH);
  u16*   bBTL = (u16*)(ws + OF_BBTL);
  float* ttF  = (float*)(ws + OF_TTF);
  u16*   ttH  = (u16*)(ws + OF_TTH);
  u16*   ttL  = (u16*)(ws + OF_TTL);
  float* pDF  = (float*)(ws + OF_PDF);
  float* pBTF = (float*)(ws + OF_PBTF);
  u16*   pDH  = (u16*)(ws + OF_PDH);
  u16*   pDL  = (u16*)(ws + OF_PDL);
  u16*   pDTH = (u16*)(ws + OF_PDTH);
  u16*   pDTL = (u16*)(ws + OF_PDTL);
  u16*   pBTH = (u16*)(ws + OF_PBTH);
  u16*   pBTL = (u16*)(ws + OF_PBTL);
  float* apart1 = (float*)(ws + OF_APART1);
  float* apart2 = (float*)(ws + OF_APART2);

  k_f2ball<<<14336, 256, 0, stream>>>(hs, Wq, Wk, Wv, Wo, hs_bf, wqkv_bf, wo_bf);
  k_gemm<<<dim3(24, 16), 256, 0, stream>>>(hs_bf, wqkv_bf, qkv, 2048, 3072);
  k_linvt<<<10496, 256, 0, stream>>>(qkv, qbf, qlb, kbf, klf, klb, glf, vT);

  k_prep1<<<128, 256, 0, stream>>>(klf, glf, tinvb);
  k_prep2a<<<128, 256, 0, stream>>>(klf, glf, qkv, tinvb, wf, wb, u0f);
  k_prep2b<<<128, 256, 0, stream>>>(klf, wf, u0f, aDF, aDH, aDL, aDTH, aDTL, aBTF, aBTH, aBTL);

  k_ks<<<dim3(32, 4, 2), 256, 0, stream>>>(aDF, aDH, aDL, aDTH, aDTL, aBTF, aBTH, aBTL,
                                           bDF, bDH, bDL, bDTH, bDTL, bBTF, bBTH, bBTL, 1);
  k_ks<<<dim3(32, 4, 2), 256, 0, stream>>>(bDF, bDH, bDL, bDTH, bDTL, bBTF, bBTH, bBTL,
                                           aDF, aDH, aDL, aDTH, aDTL, aBTF, aBTH, aBTL, 2);
  k_ks<<<dim3(32, 4, 2), 256, 0, stream>>>(aDF, aDH, aDL, aDTH, aDTL, aBTF, aBTH, aBTL,
                                           bDF, bDH, bDL, bDTH, bDTL, bBTF, bBTH, bBTL, 4);
  k_ks<<<dim3(32, 4, 2), 256, 0, stream>>>(bDF, bDH, bDL, bDTH, bDTL, bBTF, bBTH, bBTL,
                                           aDF, aDH, aDL, aDTH, aDTL, aBTF, aBTH, aBTL, 8);
  k_ks<<<dim3(32, 4, 2), 256, 0, stream>>>(aDF, aDH, aDL, aDTH, aDTL, aBTF, aBTH, aBTL,
                                           bDF, bDH, bDL, bDTH, bDTL, bBTF, bBTH, bBTL, 16);

  // group-operator powers + group-level prefix (pool slots; op_d = op_a AFTER op_b)
  CompJobs j1{}; // Phi_g^2
  for(int g = 0; g < 4; ++g){ j1.a[g] = g*32+31; j1.b[g] = g*32+31; j1.d[g] = 128+g; }
  k_comp<<<dim3(4, 2), 256, 0, stream>>>(bDF, bDH, bDL, bDTH, bDTL, bBTF, bBTH, bBTL,
                                         pDF, pDH, pDL, pDTH, pDTL, pBTF, pBTH, pBTL, j1);
  CompJobs j2{}; // Phi^3, Phi^4
  for(int g = 0; g < 4; ++g){
    j2.a[g]   = 128+g; j2.b[g]   = g*32+31; j2.d[g]   = 132+g;
    j2.a[4+g] = 128+g; j2.b[4+g] = 128+g;   j2.d[4+g] = 136+g;
  }
  k_comp<<<dim3(8, 2), 256, 0, stream>>>(bDF, bDH, bDL, bDTH, bDTL, bBTF, bBTH, bBTL,
                                         pDF, pDH, pDL, pDTH, pDTL, pBTF, pBTH, pBTL, j2);
  CompJobs j3{}; // Psi2; T
  j3.a[0] = 137; j3.b[0] = 136; j3.d[0] = 140;
  j3.a[1] = 138; j3.b[1] = 137; j3.d[1] = 141;
  k_comp<<<dim3(2, 2), 256, 0, stream>>>(bDF, bDH, bDL, bDTH, bDTL, bBTF, bBTH, bBTL,
                                         pDF, pDH, pDL, pDTH, pDTL, pBTF, pBTH, pBTL, j3);
  CompJobs j4{}; // Psi3
  j4.a[0] = 141; j4.b[0] = 136; j4.d[0] = 142;
  k_comp<<<dim3(1, 2), 256, 0, stream>>>(bDF, bDH, bDL, bDTH, bDTL, bBTF, bBTH, bBTL,
                                         pDF, pDH, pDL, pDTH, pDTL, pBTF, pBTH, pBTL, j4);

  k_heads<<<16, 256, 0, stream>>>(bDH, bDL, bBTF, bBTH, bBTL,
                                  pDH, pDL, pBTF, pBTH, pBTL, ttF, ttH, ttL, sjb);
  k_expand<<<512, 256, 0, stream>>>(bDH, bDL, bBTF, ttF, ttH, ttL, sjb);

  k_olin<<<512, 256, 0, stream>>>(qlb, klb, wb, u0f, sjb, omix);
  k_attn<<<640, 256, 0, stream>>>(qbf, kbf, vT, omix, obf, apart1, apart2);
  k_acomb<<<192, 256, 0, stream>>>(apart1, apart2, omix, obf);

  k_gemm<<<dim3(16, 16), 256, 0, stream>>>(obf, wo_bf, out, 2048, 2048);
}

// Round 10
// 655.962 us; speedup vs baseline: 1.3904x; 1.0760x over previous
//
#include <hip/hip_runtime.h>
#include <hip/hip_bf16.h>

typedef unsigned short u16;
typedef unsigned int u32;
typedef __bf16 bf16x8 __attribute__((ext_vector_type(8)));
typedef float f32x4 __attribute__((ext_vector_type(4)));

#define MFMA16(a,b,c) __builtin_amdgcn_mfma_f32_16x16x32_bf16((a),(b),(c),0,0,0)

__device__ __forceinline__ u16 f2bf(float f){
  u32 u = __builtin_bit_cast(u32, f);
  u32 r = (u + 0x7fffu + ((u >> 16) & 1u)) >> 16;
  return (u16)r;
}
__device__ __forceinline__ float bf2f(u16 h){
  u32 u = ((u32)h) << 16;
  return __builtin_bit_cast(float, u);
}
__device__ __forceinline__ void splitbf(float x, u16& hi, u16& lo){
  hi = f2bf(x);
  lo = f2bf(x - bf2f(hi));
}
__device__ __forceinline__ void gload_lds16(const u16* g, u16* l){
  __builtin_amdgcn_global_load_lds((__attribute__((address_space(1))) void*)(g),
                                   (__attribute__((address_space(3))) void*)(l), 16, 0, 0);
}
__device__ __forceinline__ const u16* selu(const u16* barr, const u16* parr, int i){
  return (i < 128) ? (barr + (size_t)i*16384) : (parr + (size_t)(i-128)*16384);
}
__device__ __forceinline__ const float* self32(const float* barr, const float* parr, int i){
  return (i < 128) ? (barr + (size_t)i*16384) : (parr + (size_t)(i-128)*16384);
}
// attention partial slots: 16512 f32 each (128x128 acc + 128 lsum)
__device__ __forceinline__ float* slotp(float* p1, float* p2, int s){
  return (s < 381) ? (p1 + (size_t)s*16512) : (p2 + (size_t)(s-381)*16512);
}
__device__ __forceinline__ const float* slotpc(const float* p1, const float* p2, int s){
  return (s < 381) ? (p1 + (size_t)s*16512) : (p2 + (size_t)(s-381)*16512);
}

// ---------------- workspace layout (bytes) ----------------
constexpr size_t OF_HSBF   = 0;
constexpr size_t OF_WQKVBF = 8388608;
constexpr size_t OF_WOBF   = 20971520;
constexpr size_t OF_QKV    = 29360128;
constexpr size_t OF_QBF    = 54525952;
constexpr size_t OF_KBF    = 62914560;
constexpr size_t OF_VT     = 65011712;
constexpr size_t OF_QLB    = 67108864;
constexpr size_t OF_KLF    = 75497472;
constexpr size_t OF_KLB    = 79691776;
constexpr size_t OF_GLF    = 81788928;
constexpr size_t OF_TINV   = 85983232;
constexpr size_t OF_WF     = 88080384;
constexpr size_t OF_WB     = 92274688;
constexpr size_t OF_U0     = 94371840;
constexpr size_t OF_SJ     = 111149056;
constexpr size_t OF_OMIX   = 127926272;
constexpr size_t OF_OMIXB  = 144703488;
constexpr size_t OF_ADF  = 102760448;
constexpr size_t OF_ABTF = OF_OMIX;
constexpr size_t OF_ADH  = OF_OMIX + 8388608;
constexpr size_t OF_ADL  = OF_OMIX + 12582912;
constexpr size_t OF_ADTH = OF_OMIXB;
constexpr size_t OF_ADTL = OF_OMIXB + 4194304;
constexpr size_t OF_ABTH = OF_KLF;
constexpr size_t OF_ABTL = OF_GLF;
constexpr size_t OF_BDF  = OF_QKV;
constexpr size_t OF_BBTF = OF_QKV + 8388608;
constexpr size_t OF_BDH  = OF_QKV + 16777216;
constexpr size_t OF_BDL  = OF_QKV + 20971520;
constexpr size_t OF_BDTH = OF_HSBF;
constexpr size_t OF_BDTL = OF_HSBF + 4194304;
constexpr size_t OF_BBTH = OF_WQKVBF;
constexpr size_t OF_BBTL = OF_WQKVBF + 4194304;
constexpr size_t OF_TTF  = OF_TINV;
constexpr size_t OF_TTH  = OF_WQKVBF + 8388608;
constexpr size_t OF_TTL  = OF_WQKVBF + 8912896;
constexpr size_t OF_PDF  = OF_ADF;
constexpr size_t OF_PBTF = OF_ADF + 1048576;
constexpr size_t OF_PDH  = OF_ADF + 2097152;
constexpr size_t OF_PDL  = OF_ADF + 2621440;
constexpr size_t OF_PDTH = OF_ADF + 3145728;
constexpr size_t OF_PDTL = OF_ADF + 3670016;
constexpr size_t OF_PBTH = OF_ADF + 4194304;
constexpr size_t OF_PBTL = OF_ADF + 4718592;
constexpr size_t OF_APART1 = OF_QKV;
constexpr size_t OF_APART2 = OF_OMIXB;
constexpr size_t OF_OBF = 0;

struct CompJobs { int a[8]; int b[8]; int d[8]; };

// ---------------- fused f2b of all 5 inputs ----------------
__global__ void k_f2ball(const float* __restrict__ hs, const float* __restrict__ Wq,
                         const float* __restrict__ Wk, const float* __restrict__ Wv,
                         const float* __restrict__ Wo, u16* __restrict__ hs_bf,
                         u16* __restrict__ wqkv_bf, u16* __restrict__ wo_bf){
  int bid = blockIdx.x;
  const float* src; u16* dst; int off;
  if(bid < 4096){ src = hs; dst = hs_bf; off = bid; }
  else if(bid < 8192){ src = Wq; dst = wqkv_bf; off = bid - 4096; }
  else if(bid < 9216){ src = Wk; dst = wqkv_bf + 2048*2048; off = bid - 8192; }
  else if(bid < 10240){ src = Wv; dst = wqkv_bf + 2560*2048; off = bid - 9216; }
  else { src = Wo; dst = wo_bf; off = bid - 10240; }
  int i = (off*256 + threadIdx.x) * 4;
  f32x4 v = *(const f32x4*)(src + i);
  u32 w0 = (u32)f2bf(v[0]) | ((u32)f2bf(v[1]) << 16);
  u32 w1 = (u32)f2bf(v[2]) | ((u32)f2bf(v[3]) << 16);
  *(u32*)(dst + i) = w0;
  *(u32*)(dst + i + 2) = w1;
}

// ---------------- bf16 NT GEMM with XCD-chunked swizzle ----------------
__global__ __launch_bounds__(256) void k_gemm(const u16* __restrict__ A, const u16* __restrict__ B,
                                              float* __restrict__ C, int K, int N){
  __shared__ u16 aL[128*32];
  __shared__ u16 bL[128*32];
  int lin = blockIdx.y * gridDim.x + blockIdx.x;
  int nwg = gridDim.x * gridDim.y;
  int s = (lin & 7) * (nwg >> 3) + (lin >> 3);
  int bn = s % gridDim.x, bm = s / gridDim.x;
  int tid = threadIdx.x, lane = tid & 63, w = tid >> 6;
  int wm = w >> 1, wn = w & 1;
  f32x4 acc[4][4] = {};
  int nK = K >> 5;
  const u16* Abase = A + (size_t)bm * 128 * K;
  const u16* Bbase = B + (size_t)bn * 128 * K;
  for(int kt = 0; kt < nK; ++kt){
    __syncthreads();
    #pragma unroll
    for(int t = 0; t < 2; ++t){
      int row = t*64 + w*16 + (lane >> 2);
      int kc = (lane & 3) * 8;
      gload_lds16(Abase + (size_t)row*K + kt*32 + kc, &aL[(t*64 + w*16)*32]);
      gload_lds16(Bbase + (size_t)row*K + kt*32 + kc, &bL[(t*64 + w*16)*32]);
    }
    __syncthreads();
    bf16x8 af[4], bf[4];
    #pragma unroll
    for(int i = 0; i < 4; ++i){
      af[i] = *(const bf16x8*)&aL[(wm*64 + i*16 + (lane & 15))*32 + ((lane >> 4) << 3)];
      bf[i] = *(const bf16x8*)&bL[(wn*64 + i*16 + (lane & 15))*32 + ((lane >> 4) << 3)];
    }
    #pragma unroll
    for(int i = 0; i < 4; ++i)
      #pragma unroll
      for(int j = 0; j < 4; ++j)
        acc[i][j] = MFMA16(af[i], bf[j], acc[i][j]);
  }
  #pragma unroll
  for(int i = 0; i < 4; ++i)
    #pragma unroll
    for(int j = 0; j < 4; ++j)
      #pragma unroll
      for(int r = 0; r < 4; ++r){
        int row = bm*128 + wm*64 + i*16 + ((lane >> 4) << 2) + r;
        int col = bn*128 + wn*64 + j*16 + (lane & 15);
        C[(size_t)row * N + col] = acc[i][j][r];
      }
}

// ---------------- fused linprep + V-transpose ----------------
__global__ __launch_bounds__(256) void k_linvt(const float* __restrict__ qkv, u16* qbf, u16* qlb,
                                               u16* kbf, float* klf, u16* klb, float* glf,
                                               u16* __restrict__ vT){
  __shared__ float t[64][65];
  int bid = blockIdx.x;
  if(bid < 10240){
    int gtask = bid * 4 + (threadIdx.x >> 6);
    int lane = threadIdx.x & 63;
    int n = gtask / 20, tt = gtask % 20;
    const float* row = (tt < 16) ? (qkv + (size_t)n*3072 + tt*128)
                                 : (qkv + (size_t)n*3072 + 2048 + (tt-16)*128);
    float v0 = row[lane], v1 = row[lane + 64];
    float m = fmaxf(v0, v1);
    #pragma unroll
    for(int o = 1; o < 64; o <<= 1) m = fmaxf(m, __shfl_xor(m, o, 64));
    float e0 = __expf(v0 - m), e1 = __expf(v1 - m);
    float s = e0 + e1;
    #pragma unroll
    for(int o = 1; o < 64; o <<= 1) s += __shfl_xor(s, o, 64);
    float r0 = e0 / s, r1 = e1 / s;
    if(tt < 16){
      size_t base = ((size_t)tt*2048 + n) * 128;
      qbf[base + lane] = f2bf(v0); qbf[base + 64 + lane] = f2bf(v1);
      qlb[base + lane] = f2bf(r0); qlb[base + 64 + lane] = f2bf(r1);
    } else {
      int g = tt - 16;
      size_t base = ((size_t)g*2048 + n) * 128;
      kbf[base + lane] = f2bf(v0); kbf[base + 64 + lane] = f2bf(v1);
      klf[base + lane] = r0;       klf[base + 64 + lane] = r1;
      klb[base + lane] = f2bf(r0); klb[base + 64 + lane] = f2bf(r1);
      float g0 = (fminf(v0, 0.f) - log1pf(__expf(-fabsf(v0)))) * (1.f/16.f);
      float g1 = (fminf(v1, 0.f) - log1pf(__expf(-fabsf(v1)))) * (1.f/16.f);
      glf[base + lane] = g0; glf[base + 64 + lane] = g1;
    }
  } else {
    int v = bid - 10240;
    int nt = v & 31, dt = (v >> 5) & 1, g = v >> 6;
    int tid = threadIdx.x;
    {
      int r = tid >> 2, c0 = (tid & 3) * 16;
      const float* src = qkv + (size_t)(nt*64 + r)*3072 + 2560 + g*128 + dt*64 + c0;
      #pragma unroll
      for(int q = 0; q < 16; q += 4){
        f32x4 vv = *(const f32x4*)(src + q);
        t[r][c0+q] = vv[0]; t[r][c0+q+1] = vv[1]; t[r][c0+q+2] = vv[2]; t[r][c0+q+3] = vv[3];
      }
    }
    __syncthreads();
    {
      int d = tid >> 2, c0 = (tid & 3) * 16;
      u16* dst = vT + ((size_t)g*128 + dt*64 + d)*2048 + (size_t)nt*64 + c0;
      #pragma unroll
      for(int half = 0; half < 2; ++half){
        int b = c0 + half*8;
        u32 w0 = (u32)f2bf(t[b+0][d]) | ((u32)f2bf(t[b+1][d]) << 16);
        u32 w1 = (u32)f2bf(t[b+2][d]) | ((u32)f2bf(t[b+3][d]) << 16);
        u32 w2 = (u32)f2bf(t[b+4][d]) | ((u32)f2bf(t[b+5][d]) << 16);
        u32 w3 = (u32)f2bf(t[b+6][d]) | ((u32)f2bf(t[b+7][d]) << 16);
        *(uint4*)(dst + half*8) = make_uint4(w0, w1, w2, w3);
      }
    }
  }
}

// ---------------- prep1 ----------------
__global__ __launch_bounds__(256) void k_prep1(const float* __restrict__ klf, const float* __restrict__ glf,
                                               float* __restrict__ tinv){
  __shared__ float KlT[128][68];
  __shared__ float Kb[64][132];
  __shared__ float Am[64][68];
  __shared__ float XT[64][68];
  int idx = blockIdx.x, g = idx >> 5, c = idx & 31, tid = threadIdx.x;
  size_t base = ((size_t)g*2048 + c*64) * 128;
  {
    int r = tid >> 2, d0 = (tid & 3) * 32;
    #pragma unroll
    for(int dd = 0; dd < 32; dd += 4){
      f32x4 kv = *(const f32x4*)(klf + base + r*128 + d0 + dd);
      f32x4 gv = *(const f32x4*)(glf + base + r*128 + d0 + dd);
      KlT[d0+dd][r] = kv[0]; KlT[d0+dd+1][r] = kv[1]; KlT[d0+dd+2][r] = kv[2]; KlT[d0+dd+3][r] = kv[3];
      f32x4 kb = kv * gv;
      *(f32x4*)&Kb[r][d0+dd] = kb;
    }
  }
  __syncthreads();
  {
    int i = tid >> 2, j0 = (tid & 3) * 16;
    f32x4 s[4] = {};
    for(int d = 0; d < 128; ++d){
      float kb = Kb[i][d];
      #pragma unroll
      for(int q = 0; q < 4; ++q){
        f32x4 kl = *(const f32x4*)&KlT[d][j0 + q*4];
        s[q] += kb * kl;
      }
    }
    #pragma unroll
    for(int q = 0; q < 4; ++q) *(f32x4*)&Am[i][j0 + q*4] = s[q];
  }
  __syncthreads();
  if(tid < 64){
    int cc = tid;
    float x0 = (cc == 0) ? 1.f : 0.f;
    XT[cc][0] = x0;
    tinv[(size_t)idx*4096 + cc] = x0;
    for(int i = 1; i < 64; ++i){
      float s = (i == cc) ? 1.f : 0.f;
      int i4 = i & ~3;
      for(int jj = 0; jj < i4; jj += 4){
        f32x4 av = *(const f32x4*)&Am[i][jj];
        f32x4 xv = *(const f32x4*)&XT[cc][jj];
        s -= av[0]*xv[0] + av[1]*xv[1] + av[2]*xv[2] + av[3]*xv[3];
      }
      for(int jj = i4; jj < i; ++jj) s -= Am[i][jj] * XT[cc][jj];
      XT[cc][i] = s;
      tinv[(size_t)idx*4096 + i*64 + cc] = s;
    }
  }
}

// ---------------- prep2a ----------------
__global__ __launch_bounds__(256) void k_prep2a(const float* __restrict__ klf, const float* __restrict__ glf,
                                                const float* __restrict__ qkv, const float* __restrict__ tinv,
                                                float* __restrict__ wf, u16* __restrict__ wb, float* __restrict__ u0f){
  __shared__ float Ti[64][68];
  __shared__ float B1[64][132];
  __shared__ float B2[64][132];
  int idx = blockIdx.x, g = idx >> 5, c = idx & 31, tid = threadIdx.x;
  size_t base = ((size_t)g*2048 + c*64) * 128;
  {
    int r = tid >> 2, d0 = (tid & 3) * 32;
    #pragma unroll
    for(int dd = 0; dd < 32; dd += 4){
      f32x4 kv = *(const f32x4*)(klf + base + r*128 + d0 + dd);
      f32x4 gv = *(const f32x4*)(glf + base + r*128 + d0 + dd);
      f32x4 vv = *(const f32x4*)(qkv + (size_t)(c*64 + r)*3072 + 2560 + g*128 + d0 + dd);
      *(f32x4*)&B1[r][d0+dd] = kv * gv;
      *(f32x4*)&B2[r][d0+dd] = vv * gv;
    }
    int c0 = (tid & 3) * 16;
    #pragma unroll
    for(int q = 0; q < 16; q += 4)
      *(f32x4*)&Ti[r][c0+q] = *(const f32x4*)(tinv + (size_t)idx*4096 + r*64 + c0 + q);
  }
  __syncthreads();
  int i = tid >> 2, cc0 = (tid & 3) * 32;
  f32x4 wa[8] = {}; f32x4 ua[8] = {};
  for(int jj = 0; jj < 64; ++jj){
    float a = Ti[i][jj];
    #pragma unroll
    for(int q = 0; q < 8; ++q){
      f32x4 b1 = *(const f32x4*)&B1[jj][cc0 + q*4];
      f32x4 b2 = *(const f32x4*)&B2[jj][cc0 + q*4];
      wa[q] += a * b1; ua[q] += a * b2;
    }
  }
  #pragma unroll
  for(int q = 0; q < 8; ++q){
    *(f32x4*)(wf + (size_t)idx*8192 + i*128 + cc0 + q*4) = wa[q];
    *(f32x4*)(u0f + (size_t)idx*8192 + i*128 + cc0 + q*4) = ua[q];
    u32 w0 = (u32)f2bf(wa[q][0]) | ((u32)f2bf(wa[q][1]) << 16);
    u32 w1 = (u32)f2bf(wa[q][2]) | ((u32)f2bf(wa[q][3]) << 16);
    u32* dst = (u32*)(wb + (size_t)idx*8192 + i*128 + cc0 + q*4);
    dst[0] = w0; dst[1] = w1;
  }
}

// ---------------- prep2b ----------------
__global__ __launch_bounds__(256) void k_prep2b(const float* __restrict__ klf, const float* __restrict__ wf,
                                                const float* __restrict__ u0f,
                                                float* __restrict__ dF, u16* __restrict__ dH, u16* __restrict__ dL,
                                                u16* __restrict__ dTH, u16* __restrict__ dTL,
                                                float* __restrict__ btF, u16* __restrict__ btH, u16* __restrict__ btL){
  __shared__ float Kl[64][132];
  __shared__ float Wm[64][132];
  __shared__ float Um[64][132];
  int idx = blockIdx.x, g = idx >> 5, c = idx & 31, tid = threadIdx.x;
  size_t base = ((size_t)g*2048 + c*64) * 128;
  {
    int r = tid >> 2, d0 = (tid & 3) * 32;
    #pragma unroll
    for(int dd = 0; dd < 32; dd += 4){
      *(f32x4*)&Kl[r][d0+dd] = *(const f32x4*)(klf + base + r*128 + d0 + dd);
      *(f32x4*)&Wm[r][d0+dd] = *(const f32x4*)(wf + (size_t)idx*8192 + r*128 + d0 + dd);
      *(f32x4*)&Um[r][d0+dd] = *(const f32x4*)(u0f + (size_t)idx*8192 + r*128 + d0 + dd);
    }
  }
  __syncthreads();
  int a = tid >> 1, b0 = (tid & 1) * 64;
  f32x4 pa[16] = {}; f32x4 ca[16] = {};
  for(int r = 0; r < 64; ++r){
    float ka = Kl[r][a];
    float ua = Um[r][a];
    #pragma unroll
    for(int q = 0; q < 16; ++q){
      f32x4 wv = *(const f32x4*)&Wm[r][b0 + q*4];
      f32x4 kv = *(const f32x4*)&Kl[r][b0 + q*4];
      pa[q] += ka * wv;
      ca[q] += ua * kv;
    }
  }
  size_t ob = (size_t)idx * 16384;
  #pragma unroll
  for(int q = 0; q < 16; ++q){
    #pragma unroll
    for(int e = 0; e < 4; ++e){
      int b = b0 + q*4 + e;
      float dv = -pa[q][e];
      u16 dh, dl; splitbf(dv, dh, dl);
      dF[ob + a*128 + b] = dv;
      dH[ob + a*128 + b] = dh;
      dL[ob + a*128 + b] = dl;
      dTH[ob + (size_t)b*128 + a] = dh;
      dTL[ob + (size_t)b*128 + a] = dl;
      float cv = ca[q][e];
      u16 ch, cl; splitbf(cv, ch, cl);
      btF[ob + a*128 + b] = cv;
      btH[ob + a*128 + b] = ch;
      btL[ob + a*128 + b] = cl;
    }
  }
}

// ---------------- Kogge-Stone compose round (split-precision) ----------------
__global__ __launch_bounds__(256) void k_ks(
    const float* __restrict__ sDF, const u16* __restrict__ sDH, const u16* __restrict__ sDL,
    const u16* __restrict__ sDTH, const u16* __restrict__ sDTL,
    const float* __restrict__ sBF, const u16* __restrict__ sBH, const u16* __restrict__ sBL,
    float* __restrict__ dDF, u16* __restrict__ dDH, u16* __restrict__ dDL,
    u16* __restrict__ dDTH, u16* __restrict__ dDTL,
    float* __restrict__ dBF, u16* __restrict__ dBH, u16* __restrict__ dBL, int off){
  __shared__ float T[128][132];
  int c = blockIdx.x, g = blockIdx.y, z = blockIdx.z;
  int idx = g*32 + c, tid = threadIdx.x;
  size_t base = (size_t)idx * 16384;
  if(c < off){
    if(z == 0){
      for(int i = tid; i < 4096; i += 256) ((uint4*)(dDF + base))[i] = ((const uint4*)(sDF + base))[i];
      for(int i = tid; i < 2048; i += 256){
        ((uint4*)(dDH + base))[i] = ((const uint4*)(sDH + base))[i];
        ((uint4*)(dDL + base))[i] = ((const uint4*)(sDL + base))[i];
        ((uint4*)(dDTH + base))[i] = ((const uint4*)(sDTH + base))[i];
        ((uint4*)(dDTL + base))[i] = ((const uint4*)(sDTL + base))[i];
      }
    } else {
      for(int i = tid; i < 4096; i += 256) ((uint4*)(dBF + base))[i] = ((const uint4*)(sBF + base))[i];
      for(int i = tid; i < 2048; i += 256){
        ((uint4*)(dBH + base))[i] = ((const uint4*)(sBH + base))[i];
        ((uint4*)(dBL + base))[i] = ((const uint4*)(sBL + base))[i];
      }
    }
    return;
  }
  size_t blo = (size_t)(idx - off) * 16384;
  int lane = tid & 63, w = tid >> 6;
  const u16 *Ah, *Al, *Bh, *Bl;
  if(z == 0){ Ah = sDH + base; Al = sDL + base; Bh = sDTH + blo; Bl = sDTL + blo; }
  else      { Ah = sBH + blo;  Al = sBL + blo;  Bh = sDH + base; Bl = sDL + base; }
  f32x4 acc[2][8] = {};
  #pragma unroll
  for(int ks = 0; ks < 4; ++ks){
    bf16x8 ah[2], al[2], bh[8], bl[8];
    #pragma unroll
    for(int mt = 0; mt < 2; ++mt){
      int ro = (w*32 + mt*16 + (lane & 15))*128 + ks*32 + ((lane >> 4) << 3);
      ah[mt] = *(const bf16x8*)(Ah + ro);
      al[mt] = *(const bf16x8*)(Al + ro);
    }
    #pragma unroll
    for(int nt = 0; nt < 8; ++nt){
      int ro = (nt*16 + (lane & 15))*128 + ks*32 + ((lane >> 4) << 3);
      bh[nt] = *(const bf16x8*)(Bh + ro);
      bl[nt] = *(const bf16x8*)(Bl + ro);
    }
    #pragma unroll
    for(int mt = 0; mt < 2; ++mt)
      #pragma unroll
      for(int nt = 0; nt < 8; ++nt)
        acc[mt][nt] = MFMA16(ah[mt], bh[nt],
                      MFMA16(ah[mt], bl[nt],
                      MFMA16(al[mt], bh[nt], acc[mt][nt])));
  }
  if(z == 0){
    #pragma unroll
    for(int mt = 0; mt < 2; ++mt)
      #pragma unroll
      for(int nt = 0; nt < 8; ++nt)
        #pragma unroll
        for(int r = 0; r < 4; ++r){
          int row = w*32 + mt*16 + ((lane >> 4) << 2) + r;
          int col = nt*16 + (lane & 15);
          float v = acc[mt][nt][r] + sDF[base + row*128 + col] + sDF[blo + row*128 + col];
          dDF[base + row*128 + col] = v;
          u16 hi, lo; splitbf(v, hi, lo);
          dDH[base + row*128 + col] = hi;
          dDL[base + row*128 + col] = lo;
          T[row][col] = v;
        }
    __syncthreads();
    int tcol = tid >> 1, half = tid & 1;
    for(int m = 0; m < 64; ++m){
      float v = T[half*64 + m][tcol];
      u16 hi, lo; splitbf(v, hi, lo);
      dDTH[base + (size_t)tcol*128 + half*64 + m] = hi;
      dDTL[base + (size_t)tcol*128 + half*64 + m] = lo;
    }
  } else {
    #pragma unroll
    for(int mt = 0; mt < 2; ++mt)
      #pragma unroll
      for(int nt = 0; nt < 8; ++nt)
        #pragma unroll
        for(int r = 0; r < 4; ++r){
          int row = w*32 + mt*16 + ((lane >> 4) << 2) + r;
          int col = nt*16 + (lane & 15);
          float v = acc[mt][nt][r] + sBF[base + row*128 + col] + sBF[blo + row*128 + col];
          dBF[base + row*128 + col] = v;
          u16 hi, lo; splitbf(v, hi, lo);
          dBH[base + row*128 + col] = hi;
          dBL[base + row*128 + col] = lo;
        }
  }
}

// ---------------- hi/lo MFMA helper for 128x128 compose ----------------
__device__ __forceinline__ void comp_mfma(const u16* Ah, const u16* Al, const u16* Bh, const u16* Bl,
                                          f32x4 (&acc)[2][8], int lane, int w){
  #pragma unroll
  for(int ks = 0; ks < 4; ++ks){
    bf16x8 ah[2], al[2], bh[8], bl[8];
    #pragma unroll
    for(int mt = 0; mt < 2; ++mt){
      int ro = (w*32 + mt*16 + (lane & 15))*128 + ks*32 + ((lane >> 4) << 3);
      ah[mt] = *(const bf16x8*)(Ah + ro);
      al[mt] = *(const bf16x8*)(Al + ro);
    }
    #pragma unroll
    for(int nt = 0; nt < 8; ++nt){
      int ro = (nt*16 + (lane & 15))*128 + ks*32 + ((lane >> 4) << 3);
      bh[nt] = *(const bf16x8*)(Bh + ro);
      bl[nt] = *(const bf16x8*)(Bl + ro);
    }
    #pragma unroll
    for(int mt = 0; mt < 2; ++mt)
      #pragma unroll
      for(int nt = 0; nt < 8; ++nt)
        acc[mt][nt] = MFMA16(ah[mt], bh[nt],
                      MFMA16(ah[mt], bl[nt],
                      MFMA16(al[mt], bh[nt], acc[mt][nt])));
  }
}

// ---------------- generic compose with LDS-staged F-sums ----------------
__global__ __launch_bounds__(256) void k_comp(
    const float* __restrict__ bDF, const u16* __restrict__ bDH, const u16* __restrict__ bDL,
    const u16* __restrict__ bDTH, const u16* __restrict__ bDTL,
    const float* __restrict__ bBTF, const u16* __restrict__ bBTH, const u16* __restrict__ bBTL,
    float* __restrict__ pDF, u16* __restrict__ pDH, u16* __restrict__ pDL,
    u16* __restrict__ pDTH, u16* __restrict__ pDTL,
    float* __restrict__ pBTF, u16* __restrict__ pBTH, u16* __restrict__ pBTL,
    CompJobs jobs){
  __shared__ float T[128][132];
  int job = blockIdx.x, z = blockIdx.y, tid = threadIdx.x;
  int a = jobs.a[job], b = jobs.b[job], d = jobs.d[job] - 128;
  size_t ob = (size_t)d * 16384;
  int lane = tid & 63, w = tid >> 6;
  const u16 *Ah, *Al, *Bh, *Bl;
  const float *F1, *F2;
  if(z == 0){
    Ah = selu(bDH, pDH, a);  Al = selu(bDL, pDL, a);
    Bh = selu(bDTH, pDTH, b); Bl = selu(bDTL, pDTL, b);
    F1 = self32(bDF, pDF, a); F2 = self32(bDF, pDF, b);
  } else {
    Ah = selu(bBTH, pBTH, b); Al = selu(bBTL, pBTL, b);
    Bh = selu(bDH, pDH, a);   Bl = selu(bDL, pDL, a);
    F1 = self32(bBTF, pBTF, a); F2 = self32(bBTF, pBTF, b);
  }
  for(int i = tid*4; i < 16384; i += 1024){
    f32x4 v1 = *(const f32x4*)(F1 + i);
    f32x4 v2 = *(const f32x4*)(F2 + i);
    f32x4 sv = v1 + v2;
    int row = i >> 7, col = i & 127;
    *(f32x4*)&T[row][col] = sv;
  }
  __syncthreads();
  f32x4 acc[2][8] = {};
  comp_mfma(Ah, Al, Bh, Bl, acc, lane, w);
  if(z == 0){
    #pragma unroll
    for(int mt = 0; mt < 2; ++mt)
      #pragma unroll
      for(int nt = 0; nt < 8; ++nt)
        #pragma unroll
        for(int r = 0; r < 4; ++r){
          int row = w*32 + mt*16 + ((lane >> 4) << 2) + r;
          int col = nt*16 + (lane & 15);
          float v = acc[mt][nt][r] + T[row][col];
          pDF[ob + row*128 + col] = v;
          u16 hi, lo; splitbf(v, hi, lo);
          pDH[ob + row*128 + col] = hi;
          pDL[ob + row*128 + col] = lo;
          T[row][col] = v;
        }
    __syncthreads();
    int tcol = tid >> 1, half = tid & 1;
    for(int m = 0; m < 64; ++m){
      float v = T[half*64 + m][tcol];
      u16 hi, lo; splitbf(v, hi, lo);
      pDTH[ob + (size_t)tcol*128 + half*64 + m] = hi;
      pDTL[ob + (size_t)tcol*128 + half*64 + m] = lo;
    }
  } else {
    #pragma unroll
    for(int mt = 0; mt < 2; ++mt)
      #pragma unroll
      for(int nt = 0; nt < 8; ++nt)
        #pragma unroll
        for(int r = 0; r < 4; ++r){
          int row = w*32 + mt*16 + ((lane >> 4) << 2) + r;
          int col = nt*16 + (lane & 15);
          float v = acc[mt][nt][r] + T[row][col];
          pBTF[ob + row*128 + col] = v;
          u16 hi, lo; splitbf(v, hi, lo);
          pBTH[ob + row*128 + col] = hi;
          pBTL[ob + row*128 + col] = lo;
        }
  }
}

// ---------------- head starts (parallel, LDS-staged F) ----------------
__global__ __launch_bounds__(256) void k_heads(
    const u16* __restrict__ bDH, const u16* __restrict__ bDL,
    const float* __restrict__ bBTF, const u16* __restrict__ bBTH, const u16* __restrict__ bBTL,
    const u16* __restrict__ pDH, const u16* __restrict__ pDL,
    const float* __restrict__ pBTF, const u16* __restrict__ pBTH, const u16* __restrict__ pBTL,
    float* __restrict__ ttF, u16* __restrict__ ttH, u16* __restrict__ ttL, u16* __restrict__ sj){
  __shared__ float T[128][132];
  int h = blockIdx.x, g = h >> 2, i0 = h & 3;
  int tid = threadIdx.x, lane = tid & 63, w = tid >> 6;
  int psi = (g == 0) ? -1 : (g == 1 ? 136 : (g == 2 ? 140 : 142));
  int phi = (i0 == 0) ? -1 : (i0 == 1 ? g*32 + 31 : (i0 == 2 ? 128 + g : 132 + g));
  const float* Pf = (psi >= 0) ? self32(bBTF, pBTF, psi) : nullptr;
  const float* Ff = (phi >= 0) ? self32(bBTF, pBTF, phi) : nullptr;
  for(int i = tid*4; i < 16384; i += 1024){
    f32x4 sv = {};
    if(Pf) sv += *(const f32x4*)(Pf + i);
    if(Ff) sv += *(const f32x4*)(Ff + i);
    int row = i >> 7, col = i & 127;
    *(f32x4*)&T[row][col] = sv;
  }
  __syncthreads();
  f32x4 acc[2][8] = {};
  if(psi >= 0 && phi >= 0)
    comp_mfma(selu(bBTH,pBTH,psi), selu(bBTL,pBTL,psi), selu(bDH,pDH,phi), selu(bDL,pDL,phi), acc, lane, w);
  #pragma unroll
  for(int mt = 0; mt < 2; ++mt)
    #pragma unroll
    for(int nt = 0; nt < 8; ++nt)
      #pragma unroll
      for(int r = 0; r < 4; ++r){
        int row = w*32 + mt*16 + ((lane >> 4) << 2) + r;
        int col = nt*16 + (lane & 15);
        float v = acc[mt][nt][r] + T[row][col];
        u16 hi, lo; splitbf(v, hi, lo);
        size_t o = (size_t)h*16384 + row*128 + col;
        ttF[o] = v; ttH[o] = hi; ttL[o] = lo;
        sj[(size_t)(h*32)*16384 + row*128 + col] = hi;
      }
}

// ---------------- expand ----------------
__global__ __launch_bounds__(256) void k_expand(const u16* __restrict__ bDH, const u16* __restrict__ bDL,
                                                const float* __restrict__ bBF, const float* __restrict__ ttF,
                                                const u16* __restrict__ ttH, const u16* __restrict__ ttL,
                                                u16* __restrict__ sj){
  int j = blockIdx.x;
  int c = j & 31;
  if(c == 0) return;
  int h = j >> 5, g = h >> 2;
  size_t obase = (size_t)j * 16384;
  size_t mb = (size_t)(g*32 + c - 1) * 16384;
  size_t tb = (size_t)h * 16384;
  int tid = threadIdx.x, lane = tid & 63, w = tid >> 6;
  f32x4 acc[2][8] = {};
  comp_mfma(ttH + tb, ttL + tb, bDH + mb, bDL + mb, acc, lane, w);
  #pragma unroll
  for(int mt = 0; mt < 2; ++mt)
    #pragma unroll
    for(int nt = 0; nt < 8; ++nt)
      #pragma unroll
      for(int r = 0; r < 4; ++r){
        int row = w*32 + mt*16 + ((lane >> 4) << 2) + r;
        int col = nt*16 + (lane & 15);
        float v = acc[mt][nt][r] + ttF[tb + row*128 + col] + bBF[mb + row*128 + col];
        sj[obase + row*128 + col] = f2bf(v);
      }
}

// ---------------- o_lin ----------------
__global__ __launch_bounds__(256) void k_olin(const u16* __restrict__ qlb, const u16* __restrict__ klb,
                                              const u16* __restrict__ wb, const float* __restrict__ u0f,
                                              const u16* __restrict__ sj, float* __restrict__ omix){
  __shared__ u16 ut[128*64];
  __shared__ u16 pl[4][16*64];
  int j = blockIdx.x;
  int h = j >> 5, c = j & 31, g = h >> 2, idx = g*32 + c;
  int tid = threadIdx.x, lane = tid & 63, w = tid >> 6;
  const u16* Sj = sj + (size_t)j * 16384;
  const u16* Q  = qlb + ((size_t)h*2048 + c*64) * 128;
  const u16* Kc = klb + ((size_t)g*2048 + c*64) * 128;
  const u16* W  = wb + (size_t)idx * 8192;
  const float* U0 = u0f + (size_t)idx * 8192;
  bf16x8 aq[4], aw[4];
  #pragma unroll
  for(int ks = 0; ks < 4; ++ks){
    aq[ks] = *(const bf16x8*)(Q + (w*16 + (lane & 15))*128 + ks*32 + ((lane >> 4) << 3));
    aw[ks] = *(const bf16x8*)(W + (w*16 + (lane & 15))*128 + ks*32 + ((lane >> 4) << 3));
  }
  f32x4 t1[8] = {}, ui[8] = {};
  #pragma unroll
  for(int ks = 0; ks < 4; ++ks)
    #pragma unroll
    for(int nt = 0; nt < 8; ++nt){
      bf16x8 b = *(const bf16x8*)(Sj + (nt*16 + (lane & 15))*128 + ks*32 + ((lane >> 4) << 3));
      t1[nt] = MFMA16(aq[ks], b, t1[nt]);
      ui[nt] = MFMA16(aw[ks], b, ui[nt]);
    }
  f32x4 sc[4] = {};
  #pragma unroll
  for(int ks = 0; ks < 4; ++ks)
    #pragma unroll
    for(int nt = 0; nt < 4; ++nt){
      bf16x8 b = *(const bf16x8*)(Kc + (nt*16 + (lane & 15))*128 + ks*32 + ((lane >> 4) << 3));
      sc[nt] = MFMA16(aq[ks], b, sc[nt]);
    }
  #pragma unroll
  for(int nt = 0; nt < 4; ++nt)
    #pragma unroll
    for(int r = 0; r < 4; ++r){
      int row = ((lane >> 4) << 2) + r;
      int col = nt*16 + (lane & 15);
      int grow = w*16 + row;
      float v = (col <= grow) ? sc[nt][r] : 0.f;
      int bo = (row*128 + col*2) ^ ((row & 7) << 4);
      *(u16*)((char*)&pl[w][0] + bo) = f2bf(v);
    }
  #pragma unroll
  for(int nt = 0; nt < 8; ++nt)
    #pragma unroll
    for(int r = 0; r < 4; ++r){
      int kv = w*16 + ((lane >> 4) << 2) + r;
      int d  = nt*16 + (lane & 15);
      float v = U0[kv*128 + d] - ui[nt][r];
      int bo = (d*128 + kv*2) ^ ((d & 7) << 4);
      *(u16*)((char*)ut + bo) = f2bf(v);
    }
  __syncthreads();
  f32x4 o2[8] = {};
  #pragma unroll
  for(int ks2 = 0; ks2 < 2; ++ks2){
    int row = lane & 15;
    int boA = (row*128 + ks2*64 + ((lane >> 4) << 4)) ^ ((row & 7) << 4);
    bf16x8 a = *(const bf16x8*)((const char*)&pl[w][0] + boA);
    #pragma unroll
    for(int nt = 0; nt < 8; ++nt){
      int d = nt*16 + (lane & 15);
      int boB = (d*128 + ks2*64 + ((lane >> 4) << 4)) ^ ((d & 7) << 4);
      bf16x8 b = *(const bf16x8*)((const char*)ut + boB);
      o2[nt] = MFMA16(a, b, o2[nt]);
    }
  }
  #pragma unroll
  for(int nt = 0; nt < 8; ++nt)
    #pragma unroll
    for(int r = 0; r < 4; ++r){
      int grow = c*64 + w*16 + ((lane >> 4) << 2) + r;
      int d = nt*16 + (lane & 15);
      omix[(size_t)grow*2048 + h*128 + d] = 0.5f * (t1[nt][r] + o2[nt][r]);
    }
}

// ---------------- base causal attention v4: shared LDS K/V staging (swizzled), m97 2-barrier loop ----------------
__global__ __launch_bounds__(256) void k_attn(const u16* __restrict__ qbf, const u16* __restrict__ kbf,
                                              const u16* __restrict__ vT, const float* __restrict__ omix,
                                              u16* __restrict__ obf,
                                              float* __restrict__ part1, float* __restrict__ part2){
  __shared__ u16 Kl[4096];     // K tile [32 r][128 c] bf16, chunk-swizzled: chunk ^= (r&7)
  __shared__ u16 Vl[4096];     // V tile [128 d][32 n] bf16, chunk-swizzled: chunk ^= ((d>>1)&3)
  __shared__ u16 pl[4][1280];  // per-wave P: 32 rows x 80B
  int rb = blockIdx.x;
  int bid = (rb & 7) * 80 + (rb >> 3);   // XCD-chunked swizzle (640 % 8 == 0)
  int h = bid / 40, j = bid % 40;
  int qB, kt0, kt1, slot = -1;
  if(j < 4){ qB = j; kt0 = 0; kt1 = 4*(qB+1); }
  else {
    int jj = j - 4; int seg;
    if(jj < 8){ qB = 4 + (jj >> 1); seg = jj & 1; }
    else if(jj < 20){ int q = jj - 8; qB = 8 + q/3; seg = q - (qB-8)*3; }
    else { int q = jj - 20; qB = 12 + (q >> 2); seg = q & 3; }
    slot = h*36 + jj;
    kt0 = seg*16;
    int full = 4*(qB+1);
    kt1 = (kt0 + 16 < full) ? kt0 + 16 : full;
  }
  int g = h >> 2;
  int tid = threadIdx.x, lane = tid & 63, w = tid >> 6;
  const u16* K = kbf + (size_t)g*2048*128;
  const u16* V = vT + (size_t)g*128*2048;
  bf16x8 aq[2][4];
  #pragma unroll
  for(int m = 0; m < 2; ++m){
    const u16* Q = qbf + ((size_t)h*2048 + qB*128 + w*32 + m*16) * 128;
    #pragma unroll
    for(int ks = 0; ks < 4; ++ks)
      aq[m][ks] = *(const bf16x8*)(Q + (lane & 15)*128 + ks*32 + ((lane >> 4) << 3));
  }
  f32x4 acc[2][8] = {};
  float lsum[2][4] = {};
  const float scale = 0.08838834764831845f;
  int qr0[2];
  #pragma unroll
  for(int m = 0; m < 2; ++m) qr0[m] = qB*128 + w*32 + m*16 + ((lane >> 4) << 2);
  u16* plw = &pl[w][0];
  for(int kt = kt0; kt < kt1; ++kt){
    __syncthreads();
    // stage K tile (8KB) + V tile (8KB), 2 gload_lds each per wave, pre-swizzled global src
    #pragma unroll
    for(int inst = 0; inst < 2; ++inst){
      int ob = w*2048 + inst*1024;        // wave-uniform LDS byte base; HW adds lane*16
      int lo = ob + lane*16;
      {
        int r = lo >> 8;                  // 0..31
        int gc = ((lo >> 4) & 15) ^ (r & 7);
        gload_lds16(K + (size_t)(kt*32 + r)*128 + gc*8, (u16*)((char*)Kl + ob));
      }
      {
        int d = lo >> 6;                  // 0..127
        int gnb = ((lo >> 4) & 3) ^ ((d >> 1) & 3);
        gload_lds16(V + (size_t)d*2048 + kt*32 + gnb*8, (u16*)((char*)Vl + ob));
      }
    }
    __syncthreads();
    // K frags from LDS (swizzled read) shared by both q-strips
    bf16x8 kb[8];
    #pragma unroll
    for(int ct = 0; ct < 2; ++ct)
      #pragma unroll
      for(int ks = 0; ks < 4; ++ks){
        int r = ct*16 + (lane & 15);
        int pc = (ks*4 + (lane >> 4)) ^ (r & 7);
        kb[ct*4+ks] = *(const bf16x8*)(Kl + r*128 + pc*8);
      }
    f32x4 s[2][2] = {};
    #pragma unroll
    for(int m = 0; m < 2; ++m)
      #pragma unroll
      for(int ct = 0; ct < 2; ++ct)
        #pragma unroll
        for(int ks = 0; ks < 4; ++ks)
          s[m][ct] = MFMA16(aq[m][ks], kb[ct*4+ks], s[m][ct]);
    // V frags from LDS
    bf16x8 bv[8];
    #pragma unroll
    for(int nt = 0; nt < 8; ++nt){
      int d = nt*16 + (lane & 15);
      int pnb = (lane >> 4) ^ ((d >> 1) & 3);
      bv[nt] = *(const bf16x8*)(Vl + d*32 + pnb*8);
    }
    // unnormalized p = exp(s*scale) with causal mask (scores O(+-5), no overflow)
    #pragma unroll
    for(int m = 0; m < 2; ++m)
      #pragma unroll
      for(int ct = 0; ct < 2; ++ct)
        #pragma unroll
        for(int r = 0; r < 4; ++r){
          int col = kt*32 + ct*16 + (lane & 15);
          float p = (col <= qr0[m] + r) ? __expf(s[m][ct][r] * scale) : 0.f;
          lsum[m][r] += p;
          int row = m*16 + ((lane >> 4) << 2) + r;
          *(u16*)((char*)plw + row*80 + (ct*16 + (lane & 15))*2) = f2bf(p);
        }
    __builtin_amdgcn_s_setprio(1);
    #pragma unroll
    for(int m = 0; m < 2; ++m){
      bf16x8 ap = *(const bf16x8*)((const char*)plw + (m*16 + (lane & 15))*80 + ((lane >> 4) << 4));
      #pragma unroll
      for(int nt = 0; nt < 8; ++nt)
        acc[m][nt] = MFMA16(ap, bv[nt], acc[m][nt]);
    }
    __builtin_amdgcn_s_setprio(0);
  }
  #pragma unroll
  for(int m = 0; m < 2; ++m)
    #pragma unroll
    for(int r = 0; r < 4; ++r){
      float v = lsum[m][r];
      v += __shfl_xor(v, 1, 64); v += __shfl_xor(v, 2, 64);
      v += __shfl_xor(v, 4, 64); v += __shfl_xor(v, 8, 64);
      lsum[m][r] = v;
    }
  if(slot < 0){
    #pragma unroll
    for(int m = 0; m < 2; ++m)
      #pragma unroll
      for(int nt = 0; nt < 8; ++nt)
        #pragma unroll
        for(int r = 0; r < 4; ++r){
          int row = qB*128 + w*32 + m*16 + ((lane >> 4) << 2) + r;
          int d = nt*16 + (lane & 15);
          size_t o = (size_t)row*2048 + h*128 + d;
          float fin = omix[o] + 0.5f * acc[m][nt][r] / lsum[m][r];
          obf[o] = f2bf(fin);
        }
  } else {
    float* P = slotp(part1, part2, slot);
    #pragma unroll
    for(int m = 0; m < 2; ++m)
      #pragma unroll
      for(int nt = 0; nt < 8; ++nt)
        #pragma unroll
        for(int r = 0; r < 4; ++r){
          int row = w*32 + m*16 + ((lane >> 4) << 2) + r;
          int d = nt*16 + (lane & 15);
          P[(size_t)row*128 + d] = acc[m][nt][r];
        }
    if((lane & 15) == 0)
      #pragma unroll
      for(int m = 0; m < 2; ++m)
        #pragma unroll
        for(int r = 0; r < 4; ++r)
          P[16384 + w*32 + m*16 + ((lane >> 4) << 2) + r] = lsum[m][r];
  }
}

// ---------------- combine attention K-segments; writes final bf16 omix ----------------
__global__ __launch_bounds__(256) void k_acomb(const float* __restrict__ part1, const float* __restrict__ part2,
                                               const float* __restrict__ omix, u16* __restrict__ obf){
  int bid = blockIdx.x;             // h*12 + (qB-4)
  int h = bid / 12, qx = bid % 12, qB = 4 + qx;
  int nseg = (qB >= 12) ? 4 : (qB >= 8) ? 3 : 2;
  int off = (qB < 8) ? (qB-4)*2 : (qB < 12) ? 8 + (qB-8)*3 : 20 + (qB-12)*4;
  int s0 = h*36 + off;
  int tid = threadIdx.x;
  #pragma unroll
  for(int it = 0; it < 16; ++it){
    int i = it*1024 + tid*4;
    int row = i >> 7;
    f32x4 a = {};
    float l = 0.f;
    for(int s = 0; s < nseg; ++s){
      const float* P = slotpc(part1, part2, s0 + s);
      a += *(const f32x4*)(P + i);
      l += P[16384 + row];
    }
    size_t idx = (size_t)(qB*128 + row)*2048 + h*128 + (i & 127);
    f32x4 cur = *(const f32x4*)(omix + idx);
    f32x4 fin = cur + a * (0.5f / l);
    u32 w0 = (u32)f2bf(fin[0]) | ((u32)f2bf(fin[1]) << 16);
    u32 w1 = (u32)f2bf(fin[2]) | ((u32)f2bf(fin[3]) << 16);
    *(u32*)(obf + idx) = w0;
    *(u32*)(obf + idx + 2) = w1;
  }
}

// ---------------- launch ----------------
extern "C" void kernel_launch(void* const* d_in, const int* in_sizes, int n_in,
                              void* d_out, int out_size, void* d_ws, size_t ws_size,
                              hipStream_t stream){
  (void)in_sizes; (void)n_in; (void)out_size; (void)ws_size;
  const float* hs = (const float*)d_in[0];
  const float* Wq = (const float*)d_in[1];
  const float* Wk = (const float*)d_in[2];
  const float* Wv = (const float*)d_in[3];
  const float* Wo = (const float*)d_in[4];
  float* out = (float*)d_out;
  char* ws = (char*)d_ws;

  u16*   hs_bf   = (u16*)(ws + OF_HSBF);
  u16*   wqkv_bf = (u16*)(ws + OF_WQKVBF);
  u16*   wo_bf   = (u16*)(ws + OF_WOBF);
  float* qkv     = (float*)(ws + OF_QKV);
  u16*   qbf     = (u16*)(ws + OF_QBF);
  u16*   kbf     = (u16*)(ws + OF_KBF);
  u16*   vT      = (u16*)(ws + OF_VT);
  u16*   qlb     = (u16*)(ws + OF_QLB);
  float* klf     = (float*)(ws + OF_KLF);
  u16*   klb     = (u16*)(ws + OF_KLB);
  float* glf     = (float*)(ws + OF_GLF);
  float* tinvb   = (float*)(ws + OF_TINV);
  float* wf      = (float*)(ws + OF_WF);
  u16*   wb      = (u16*)(ws + OF_WB);
  float* u0f     = (float*)(ws + OF_U0);
  u16*   sjb     = (u16*)(ws + OF_SJ);
  float* omix    = (float*)(ws + OF_OMIX);
  u16*   obf     = (u16*)(ws + OF_OBF);
  float* aDF  = (float*)(ws + OF_ADF);
  u16*   aDH  = (u16*)(ws + OF_ADH);
  u16*   aDL  = (u16*)(ws + OF_ADL);
  u16*   aDTH = (u16*)(ws + OF_ADTH);
  u16*   aDTL = (u16*)(ws + OF_ADTL);
  float* aBTF = (float*)(ws + OF_ABTF);
  u16*   aBTH = (u16*)(ws + OF_ABTH);
  u16*   aBTL = (u16*)(ws + OF_ABTL);
  float* bDF  = (float*)(ws + OF_BDF);
  u16*   bDH  = (u16*)(ws + OF_BDH);
  u16*   bDL  = (u16*)(ws + OF_BDL);
  u16*   bDTH = (u16*)(ws + OF_BDTH);
  u16*   bDTL = (u16*)(ws + OF_BDTL);
  float* bBTF = (float*)(ws + OF_BBTF);
  u16*   bBTH = (u16*)(ws + OF_BBTH);
  u16*   bBTL = (u16*)(ws + OF_BBTL);
  float* ttF  = (float*)(ws + OF_TTF);
  u16*   ttH  = (u16*)(ws + OF_TTH);
  u16*   ttL  = (u16*)(ws + OF_TTL);
  float* pDF  = (float*)(ws + OF_PDF);
  float* pBTF = (float*)(ws + OF_PBTF);
  u16*   pDH  = (u16*)(ws + OF_PDH);
  u16*   pDL  = (u16*)(ws + OF_PDL);
  u16*   pDTH = (u16*)(ws + OF_PDTH);
  u16*   pDTL = (u16*)(ws + OF_PDTL);
  u16*   pBTH = (u16*)(ws + OF_PBTH);
  u16*   pBTL = (u16*)(ws + OF_PBTL);
  float* apart1 = (float*)(ws + OF_APART1);
  float* apart2 = (float*)(ws + OF_APART2);

  k_f2ball<<<14336, 256, 0, stream>>>(hs, Wq, Wk, Wv, Wo, hs_bf, wqkv_bf, wo_bf);
  k_gemm<<<dim3(24, 16), 256, 0, stream>>>(hs_bf, wqkv_bf, qkv, 2048, 3072);
  k_linvt<<<10496, 256, 0, stream>>>(qkv, qbf, qlb, kbf, klf, klb, glf, vT);

  k_prep1<<<128, 256, 0, stream>>>(klf, glf, tinvb);
  k_prep2a<<<128, 256, 0, stream>>>(klf, glf, qkv, tinvb, wf, wb, u0f);
  k_prep2b<<<128, 256, 0, stream>>>(klf, wf, u0f, aDF, aDH, aDL, aDTH, aDTL, aBTF, aBTH, aBTL);

  k_ks<<<dim3(32, 4, 2), 256, 0, stream>>>(aDF, aDH, aDL, aDTH, aDTL, aBTF, aBTH, aBTL,
                                           bDF, bDH, bDL, bDTH, bDTL, bBTF, bBTH, bBTL, 1);
  k_ks<<<dim3(32, 4, 2), 256, 0, stream>>>(bDF, bDH, bDL, bDTH, bDTL, bBTF, bBTH, bBTL,
                                           aDF, aDH, aDL, aDTH, aDTL, aBTF, aBTH, aBTL, 2);
  k_ks<<<dim3(32, 4, 2), 256, 0, stream>>>(aDF, aDH, aDL, aDTH, aDTL, aBTF, aBTH, aBTL,
                                           bDF, bDH, bDL, bDTH, bDTL, bBTF, bBTH, bBTL, 4);
  k_ks<<<dim3(32, 4, 2), 256, 0, stream>>>(bDF, bDH, bDL, bDTH, bDTL, bBTF, bBTH, bBTL,
                                           aDF, aDH, aDL, aDTH, aDTL, aBTF, aBTH, aBTL, 8);
  k_ks<<<dim3(32, 4, 2), 256, 0, stream>>>(aDF, aDH, aDL, aDTH, aDTL, aBTF, aBTH, aBTL,
                                           bDF, bDH, bDL, bDTH, bDTL, bBTF, bBTH, bBTL, 16);

  CompJobs j1{}; // Phi_g^2
  for(int g = 0; g < 4; ++g){ j1.a[g] = g*32+31; j1.b[g] = g*32+31; j1.d[g] = 128+g; }
  k_comp<<<dim3(4, 2), 256, 0, stream>>>(bDF, bDH, bDL, bDTH, bDTL, bBTF, bBTH, bBTL,
                                         pDF, pDH, pDL, pDTH, pDTL, pBTF, pBTH, pBTL, j1);
  CompJobs j2{}; // Phi^3, Phi^4
  for(int g = 0; g < 4; ++g){
    j2.a[g]   = 128+g; j2.b[g]   = g*32+31; j2.d[g]   = 132+g;
    j2.a[4+g] = 128+g; j2.b[4+g] = 128+g;   j2.d[4+g] = 136+g;
  }
  k_comp<<<dim3(8, 2), 256, 0, stream>>>(bDF, bDH, bDL, bDTH, bDTL, bBTF, bBTH, bBTL,
                                         pDF, pDH, pDL, pDTH, pDTL, pBTF, pBTH, pBTL, j2);
  CompJobs j3{}; // Psi2; T
  j3.a[0] = 137; j3.b[0] = 136; j3.d[0] = 140;
  j3.a[1] = 138; j3.b[1] = 137; j3.d[1] = 141;
  k_comp<<<dim3(2, 2), 256, 0, stream>>>(bDF, bDH, bDL, bDTH, bDTL, bBTF, bBTH, bBTL,
                                         pDF, pDH, pDL, pDTH, pDTL, pBTF, pBTH, pBTL, j3);
  CompJobs j4{}; // Psi3
  j4.a[0] = 141; j4.b[0] = 136; j4.d[0] = 142;
  k_comp<<<dim3(1, 2), 256, 0, stream>>>(bDF, bDH, bDL, bDTH, bDTL, bBTF, bBTH, bBTL,
                                         pDF, pDH, pDL, pDTH, pDTL, pBTF, pBTH, pBTL, j4);

  k_heads<<<16, 256, 0, stream>>>(bDH, bDL, bBTF, bBTH, bBTL,
                                  pDH, pDL, pBTF, pBTH, pBTL, ttF, ttH, ttL, sjb);
  k_expand<<<512, 256, 0, stream>>>(bDH, bDL, bBTF, ttF, ttH, ttL, sjb);

  k_olin<<<512, 256, 0, stream>>>(qlb, klb, wb, u0f, sjb, omix);
  k_attn<<<640, 256, 0, stream>>>(qbf, kbf, vT, omix, obf, apart1, apart2);
  k_acomb<<<192, 256, 0, stream>>>(apart1, apart2, omix, obf);

  k_gemm<<<dim3(16, 16), 256, 0, stream>>>(obf, wo_bf, out, 2048, 2048);
}

// Round 11
// 649.961 us; speedup vs baseline: 1.4032x; 1.0092x over previous
//
#include <hip/hip_runtime.h>
#include <hip/hip_bf16.h>

typedef unsigned short u16;
typedef unsigned int u32;
typedef __bf16 bf16x8 __attribute__((ext_vector_type(8)));
typedef float f32x4 __attribute__((ext_vector_type(4)));

#define MFMA16(a,b,c) __builtin_amdgcn_mfma_f32_16x16x32_bf16((a),(b),(c),0,0,0)

__device__ __forceinline__ u16 f2bf(float f){
  u32 u = __builtin_bit_cast(u32, f);
  u32 r = (u + 0x7fffu + ((u >> 16) & 1u)) >> 16;
  return (u16)r;
}
__device__ __forceinline__ float bf2f(u16 h){
  u32 u = ((u32)h) << 16;
  return __builtin_bit_cast(float, u);
}
__device__ __forceinline__ void splitbf(float x, u16& hi, u16& lo){
  hi = f2bf(x);
  lo = f2bf(x - bf2f(hi));
}
__device__ __forceinline__ void gload_lds16(const u16* g, u16* l){
  __builtin_amdgcn_global_load_lds((__attribute__((address_space(1))) void*)(g),
                                   (__attribute__((address_space(3))) void*)(l), 16, 0, 0);
}
__device__ __forceinline__ const u16* selu(const u16* barr, const u16* parr, int i){
  return (i < 128) ? (barr + (size_t)i*16384) : (parr + (size_t)(i-128)*16384);
}
__device__ __forceinline__ const float* self32(const float* barr, const float* parr, int i){
  return (i < 128) ? (barr + (size_t)i*16384) : (parr + (size_t)(i-128)*16384);
}
// attention partial slots: 16512 f32 each (128x128 acc + 128 lsum)
__device__ __forceinline__ float* slotp(float* p1, float* p2, int s){
  return (s < 381) ? (p1 + (size_t)s*16512) : (p2 + (size_t)(s-381)*16512);
}
__device__ __forceinline__ const float* slotpc(const float* p1, const float* p2, int s){
  return (s < 381) ? (p1 + (size_t)s*16512) : (p2 + (size_t)(s-381)*16512);
}

// ---------------- workspace layout (bytes) ----------------
constexpr size_t OF_HSBF   = 0;
constexpr size_t OF_WQKVBF = 8388608;
constexpr size_t OF_WOBF   = 20971520;
constexpr size_t OF_QKV    = 29360128;
constexpr size_t OF_QBF    = 54525952;
constexpr size_t OF_KBF    = 62914560;
constexpr size_t OF_VT     = 65011712;
constexpr size_t OF_QLB    = 67108864;
constexpr size_t OF_KLF    = 75497472;
constexpr size_t OF_KLB    = 79691776;
constexpr size_t OF_GLF    = 81788928;
constexpr size_t OF_TINV   = 85983232;
constexpr size_t OF_WF     = 88080384;
constexpr size_t OF_WB     = 92274688;
constexpr size_t OF_U0     = 94371840;
constexpr size_t OF_SJ     = 111149056;
constexpr size_t OF_OMIX   = 127926272;
constexpr size_t OF_OMIXB  = 144703488;
constexpr size_t OF_ADF  = 102760448;
constexpr size_t OF_ABTF = OF_OMIX;
constexpr size_t OF_ADH  = OF_OMIX + 8388608;
constexpr size_t OF_ADL  = OF_OMIX + 12582912;
constexpr size_t OF_ADTH = OF_OMIXB;
constexpr size_t OF_ADTL = OF_OMIXB + 4194304;
constexpr size_t OF_ABTH = OF_KLF;
constexpr size_t OF_ABTL = OF_GLF;
constexpr size_t OF_BDF  = OF_QKV;
constexpr size_t OF_BBTF = OF_QKV + 8388608;
constexpr size_t OF_BDH  = OF_QKV + 16777216;
constexpr size_t OF_BDL  = OF_QKV + 20971520;
constexpr size_t OF_BDTH = OF_HSBF;
constexpr size_t OF_BDTL = OF_HSBF + 4194304;
constexpr size_t OF_BBTH = OF_WQKVBF;
constexpr size_t OF_BBTL = OF_WQKVBF + 4194304;
constexpr size_t OF_TTF  = OF_TINV;
constexpr size_t OF_TTH  = OF_WQKVBF + 8388608;
constexpr size_t OF_TTL  = OF_WQKVBF + 8912896;
constexpr size_t OF_PDF  = OF_ADF;
constexpr size_t OF_PBTF = OF_ADF + 1048576;
constexpr size_t OF_PDH  = OF_ADF + 2097152;
constexpr size_t OF_PDL  = OF_ADF + 2621440;
constexpr size_t OF_PDTH = OF_ADF + 3145728;
constexpr size_t OF_PDTL = OF_ADF + 3670016;
constexpr size_t OF_PBTH = OF_ADF + 4194304;
constexpr size_t OF_PBTL = OF_ADF + 4718592;
constexpr size_t OF_APART1 = OF_QKV;
constexpr size_t OF_APART2 = OF_OMIXB;
constexpr size_t OF_OBF = 0;

struct CompJobs { int a[8]; int b[8]; int d[8]; };

// ---------------- fused f2b of all 5 inputs ----------------
__global__ void k_f2ball(const float* __restrict__ hs, const float* __restrict__ Wq,
                         const float* __restrict__ Wk, const float* __restrict__ Wv,
                         const float* __restrict__ Wo, u16* __restrict__ hs_bf,
                         u16* __restrict__ wqkv_bf, u16* __restrict__ wo_bf){
  int bid = blockIdx.x;
  const float* src; u16* dst; int off;
  if(bid < 4096){ src = hs; dst = hs_bf; off = bid; }
  else if(bid < 8192){ src = Wq; dst = wqkv_bf; off = bid - 4096; }
  else if(bid < 9216){ src = Wk; dst = wqkv_bf + 2048*2048; off = bid - 8192; }
  else if(bid < 10240){ src = Wv; dst = wqkv_bf + 2560*2048; off = bid - 9216; }
  else { src = Wo; dst = wo_bf; off = bid - 10240; }
  int i = (off*256 + threadIdx.x) * 4;
  f32x4 v = *(const f32x4*)(src + i);
  u32 w0 = (u32)f2bf(v[0]) | ((u32)f2bf(v[1]) << 16);
  u32 w1 = (u32)f2bf(v[2]) | ((u32)f2bf(v[3]) << 16);
  *(u32*)(dst + i) = w0;
  *(u32*)(dst + i + 2) = w1;
}

// ---------------- bf16 NT GEMM with XCD-chunked swizzle ----------------
__global__ __launch_bounds__(256) void k_gemm(const u16* __restrict__ A, const u16* __restrict__ B,
                                              float* __restrict__ C, int K, int N){
  __shared__ u16 aL[128*32];
  __shared__ u16 bL[128*32];
  int lin = blockIdx.y * gridDim.x + blockIdx.x;
  int nwg = gridDim.x * gridDim.y;
  int s = (lin & 7) * (nwg >> 3) + (lin >> 3);
  int bn = s % gridDim.x, bm = s / gridDim.x;
  int tid = threadIdx.x, lane = tid & 63, w = tid >> 6;
  int wm = w >> 1, wn = w & 1;
  f32x4 acc[4][4] = {};
  int nK = K >> 5;
  const u16* Abase = A + (size_t)bm * 128 * K;
  const u16* Bbase = B + (size_t)bn * 128 * K;
  for(int kt = 0; kt < nK; ++kt){
    __syncthreads();
    #pragma unroll
    for(int t = 0; t < 2; ++t){
      int row = t*64 + w*16 + (lane >> 2);
      int kc = (lane & 3) * 8;
      gload_lds16(Abase + (size_t)row*K + kt*32 + kc, &aL[(t*64 + w*16)*32]);
      gload_lds16(Bbase + (size_t)row*K + kt*32 + kc, &bL[(t*64 + w*16)*32]);
    }
    __syncthreads();
    bf16x8 af[4], bf[4];
    #pragma unroll
    for(int i = 0; i < 4; ++i){
      af[i] = *(const bf16x8*)&aL[(wm*64 + i*16 + (lane & 15))*32 + ((lane >> 4) << 3)];
      bf[i] = *(const bf16x8*)&bL[(wn*64 + i*16 + (lane & 15))*32 + ((lane >> 4) << 3)];
    }
    #pragma unroll
    for(int i = 0; i < 4; ++i)
      #pragma unroll
      for(int j = 0; j < 4; ++j)
        acc[i][j] = MFMA16(af[i], bf[j], acc[i][j]);
  }
  #pragma unroll
  for(int i = 0; i < 4; ++i)
    #pragma unroll
    for(int j = 0; j < 4; ++j)
      #pragma unroll
      for(int r = 0; r < 4; ++r){
        int row = bm*128 + wm*64 + i*16 + ((lane >> 4) << 2) + r;
        int col = bn*128 + wn*64 + j*16 + (lane & 15);
        C[(size_t)row * N + col] = acc[i][j][r];
      }
}

// ---------------- fused linprep + V-transpose ----------------
__global__ __launch_bounds__(256) void k_linvt(const float* __restrict__ qkv, u16* qbf, u16* qlb,
                                               u16* kbf, float* klf, u16* klb, float* glf,
                                               u16* __restrict__ vT){
  __shared__ float t[64][65];
  int bid = blockIdx.x;
  if(bid < 10240){
    int gtask = bid * 4 + (threadIdx.x >> 6);
    int lane = threadIdx.x & 63;
    int n = gtask / 20, tt = gtask % 20;
    const float* row = (tt < 16) ? (qkv + (size_t)n*3072 + tt*128)
                                 : (qkv + (size_t)n*3072 + 2048 + (tt-16)*128);
    float v0 = row[lane], v1 = row[lane + 64];
    float m = fmaxf(v0, v1);
    #pragma unroll
    for(int o = 1; o < 64; o <<= 1) m = fmaxf(m, __shfl_xor(m, o, 64));
    float e0 = __expf(v0 - m), e1 = __expf(v1 - m);
    float s = e0 + e1;
    #pragma unroll
    for(int o = 1; o < 64; o <<= 1) s += __shfl_xor(s, o, 64);
    float r0 = e0 / s, r1 = e1 / s;
    if(tt < 16){
      size_t base = ((size_t)tt*2048 + n) * 128;
      qbf[base + lane] = f2bf(v0); qbf[base + 64 + lane] = f2bf(v1);
      qlb[base + lane] = f2bf(r0); qlb[base + 64 + lane] = f2bf(r1);
    } else {
      int g = tt - 16;
      size_t base = ((size_t)g*2048 + n) * 128;
      kbf[base + lane] = f2bf(v0); kbf[base + 64 + lane] = f2bf(v1);
      klf[base + lane] = r0;       klf[base + 64 + lane] = r1;
      klb[base + lane] = f2bf(r0); klb[base + 64 + lane] = f2bf(r1);
      float g0 = (fminf(v0, 0.f) - log1pf(__expf(-fabsf(v0)))) * (1.f/16.f);
      float g1 = (fminf(v1, 0.f) - log1pf(__expf(-fabsf(v1)))) * (1.f/16.f);
      glf[base + lane] = g0; glf[base + 64 + lane] = g1;
    }
  } else {
    int v = bid - 10240;
    int nt = v & 31, dt = (v >> 5) & 1, g = v >> 6;
    int tid = threadIdx.x;
    {
      int r = tid >> 2, c0 = (tid & 3) * 16;
      const float* src = qkv + (size_t)(nt*64 + r)*3072 + 2560 + g*128 + dt*64 + c0;
      #pragma unroll
      for(int q = 0; q < 16; q += 4){
        f32x4 vv = *(const f32x4*)(src + q);
        t[r][c0+q] = vv[0]; t[r][c0+q+1] = vv[1]; t[r][c0+q+2] = vv[2]; t[r][c0+q+3] = vv[3];
      }
    }
    __syncthreads();
    {
      int d = tid >> 2, c0 = (tid & 3) * 16;
      u16* dst = vT + ((size_t)g*128 + dt*64 + d)*2048 + (size_t)nt*64 + c0;
      #pragma unroll
      for(int half = 0; half < 2; ++half){
        int b = c0 + half*8;
        u32 w0 = (u32)f2bf(t[b+0][d]) | ((u32)f2bf(t[b+1][d]) << 16);
        u32 w1 = (u32)f2bf(t[b+2][d]) | ((u32)f2bf(t[b+3][d]) << 16);
        u32 w2 = (u32)f2bf(t[b+4][d]) | ((u32)f2bf(t[b+5][d]) << 16);
        u32 w3 = (u32)f2bf(t[b+6][d]) | ((u32)f2bf(t[b+7][d]) << 16);
        *(uint4*)(dst + half*8) = make_uint4(w0, w1, w2, w3);
      }
    }
  }
}

// ---------------- prep1 ----------------
__global__ __launch_bounds__(256) void k_prep1(const float* __restrict__ klf, const float* __restrict__ glf,
                                               float* __restrict__ tinv){
  __shared__ float KlT[128][68];
  __shared__ float Kb[64][132];
  __shared__ float Am[64][68];
  __shared__ float XT[64][68];
  int idx = blockIdx.x, g = idx >> 5, c = idx & 31, tid = threadIdx.x;
  size_t base = ((size_t)g*2048 + c*64) * 128;
  {
    int r = tid >> 2, d0 = (tid & 3) * 32;
    #pragma unroll
    for(int dd = 0; dd < 32; dd += 4){
      f32x4 kv = *(const f32x4*)(klf + base + r*128 + d0 + dd);
      f32x4 gv = *(const f32x4*)(glf + base + r*128 + d0 + dd);
      KlT[d0+dd][r] = kv[0]; KlT[d0+dd+1][r] = kv[1]; KlT[d0+dd+2][r] = kv[2]; KlT[d0+dd+3][r] = kv[3];
      f32x4 kb = kv * gv;
      *(f32x4*)&Kb[r][d0+dd] = kb;
    }
  }
  __syncthreads();
  {
    int i = tid >> 2, j0 = (tid & 3) * 16;
    f32x4 s[4] = {};
    for(int d = 0; d < 128; ++d){
      float kb = Kb[i][d];
      #pragma unroll
      for(int q = 0; q < 4; ++q){
        f32x4 kl = *(const f32x4*)&KlT[d][j0 + q*4];
        s[q] += kb * kl;
      }
    }
    #pragma unroll
    for(int q = 0; q < 4; ++q) *(f32x4*)&Am[i][j0 + q*4] = s[q];
  }
  __syncthreads();
  if(tid < 64){
    int cc = tid;
    float x0 = (cc == 0) ? 1.f : 0.f;
    XT[cc][0] = x0;
    tinv[(size_t)idx*4096 + cc] = x0;
    for(int i = 1; i < 64; ++i){
      float s = (i == cc) ? 1.f : 0.f;
      int i4 = i & ~3;
      for(int jj = 0; jj < i4; jj += 4){
        f32x4 av = *(const f32x4*)&Am[i][jj];
        f32x4 xv = *(const f32x4*)&XT[cc][jj];
        s -= av[0]*xv[0] + av[1]*xv[1] + av[2]*xv[2] + av[3]*xv[3];
      }
      for(int jj = i4; jj < i; ++jj) s -= Am[i][jj] * XT[cc][jj];
      XT[cc][i] = s;
      tinv[(size_t)idx*4096 + i*64 + cc] = s;
    }
  }
}

// ---------------- prep2a: w = Tinv*kb, u0 = Tinv*vb; LDS-restaged coalesced writeback ----------------
__global__ __launch_bounds__(256) void k_prep2a(const float* __restrict__ klf, const float* __restrict__ glf,
                                                const float* __restrict__ qkv, const float* __restrict__ tinv,
                                                float* __restrict__ wf, u16* __restrict__ wb, float* __restrict__ u0f){
  __shared__ char smem[84992];
  float (*Ti)[68]  = (float(*)[68])smem;              // 17408
  float (*B1)[132] = (float(*)[132])(smem + 17408);   // 33792
  float (*B2)[132] = (float(*)[132])(smem + 51200);   // 33792 (ends 84992)
  int idx = blockIdx.x, g = idx >> 5, c = idx & 31, tid = threadIdx.x;
  size_t base = ((size_t)g*2048 + c*64) * 128;
  {
    int r = tid >> 2, d0 = (tid & 3) * 32;
    #pragma unroll
    for(int dd = 0; dd < 32; dd += 4){
      f32x4 kv = *(const f32x4*)(klf + base + r*128 + d0 + dd);
      f32x4 gv = *(const f32x4*)(glf + base + r*128 + d0 + dd);
      f32x4 vv = *(const f32x4*)(qkv + (size_t)(c*64 + r)*3072 + 2560 + g*128 + d0 + dd);
      *(f32x4*)&B1[r][d0+dd] = kv * gv;
      *(f32x4*)&B2[r][d0+dd] = vv * gv;
    }
    int c0 = (tid & 3) * 16;
    #pragma unroll
    for(int q = 0; q < 16; q += 4)
      *(f32x4*)&Ti[r][c0+q] = *(const f32x4*)(tinv + (size_t)idx*4096 + r*64 + c0 + q);
  }
  __syncthreads();
  int i = tid >> 2, cc0 = (tid & 3) * 32;
  f32x4 wa[8] = {}; f32x4 ua[8] = {};
  for(int jj = 0; jj < 64; ++jj){
    float a = Ti[i][jj];
    #pragma unroll
    for(int q = 0; q < 8; ++q){
      f32x4 b1 = *(const f32x4*)&B1[jj][cc0 + q*4];
      f32x4 b2 = *(const f32x4*)&B2[jj][cc0 + q*4];
      wa[q] += a * b1; ua[q] += a * b2;
    }
  }
  __syncthreads();
  // restage into LDS, then coalesced writeback
  float (*Tw)[132] = (float(*)[132])smem;             // 33792
  float (*Tu)[132] = (float(*)[132])(smem + 33792);   // 33792 (ends 67584)
  #pragma unroll
  for(int q = 0; q < 8; ++q){
    *(f32x4*)&Tw[i][cc0 + q*4] = wa[q];
    *(f32x4*)&Tu[i][cc0 + q*4] = ua[q];
  }
  __syncthreads();
  size_t ob = (size_t)idx * 8192;
  #pragma unroll
  for(int c2 = 0; c2 < 8; ++c2){
    int ii = c2*1024 + tid*4;
    int row = ii >> 7, col = ii & 127;
    f32x4 wv = *(const f32x4*)&Tw[row][col];
    f32x4 uv = *(const f32x4*)&Tu[row][col];
    *(f32x4*)(wf + ob + ii) = wv;
    *(f32x4*)(u0f + ob + ii) = uv;
    u32 p0 = (u32)f2bf(wv[0]) | ((u32)f2bf(wv[1]) << 16);
    u32 p1 = (u32)f2bf(wv[2]) | ((u32)f2bf(wv[3]) << 16);
    *(u32*)(wb + ob + ii) = p0;
    *(u32*)(wb + ob + ii + 2) = p1;
  }
}

// ---------------- prep2b: D = -(k^T w), BT = (k^T u0)^T; LDS-restaged coalesced writeback ----------------
__global__ __launch_bounds__(256) void k_prep2b(const float* __restrict__ klf, const float* __restrict__ wf,
                                                const float* __restrict__ u0f,
                                                float* __restrict__ dF, u16* __restrict__ dH, u16* __restrict__ dL,
                                                u16* __restrict__ dTH, u16* __restrict__ dTL,
                                                float* __restrict__ btF, u16* __restrict__ btH, u16* __restrict__ btL){
  __shared__ char smem[101376];
  float (*Kl)[132] = (float(*)[132])smem;             // 33792
  float (*Wm)[132] = (float(*)[132])(smem + 33792);   // 33792
  float (*Um)[132] = (float(*)[132])(smem + 67584);   // 33792 (ends 101376)
  int idx = blockIdx.x, g = idx >> 5, c = idx & 31, tid = threadIdx.x;
  size_t base = ((size_t)g*2048 + c*64) * 128;
  {
    int r = tid >> 2, d0 = (tid & 3) * 32;
    #pragma unroll
    for(int dd = 0; dd < 32; dd += 4){
      *(f32x4*)&Kl[r][d0+dd] = *(const f32x4*)(klf + base + r*128 + d0 + dd);
      *(f32x4*)&Wm[r][d0+dd] = *(const f32x4*)(wf + (size_t)idx*8192 + r*128 + d0 + dd);
      *(f32x4*)&Um[r][d0+dd] = *(const f32x4*)(u0f + (size_t)idx*8192 + r*128 + d0 + dd);
    }
  }
  __syncthreads();
  int a = tid >> 1, b0 = (tid & 1) * 64;
  f32x4 pa[16] = {}; f32x4 ca[16] = {};
  for(int r = 0; r < 64; ++r){
    float ka = Kl[r][a];
    float ua = Um[r][a];
    #pragma unroll
    for(int q = 0; q < 16; ++q){
      f32x4 wv = *(const f32x4*)&Wm[r][b0 + q*4];
      f32x4 kv = *(const f32x4*)&Kl[r][b0 + q*4];
      pa[q] += ka * wv;
      ca[q] += ua * kv;
    }
  }
  __syncthreads();
  size_t ob = (size_t)idx * 16384;
  float (*Td)[132] = (float(*)[132])smem;             // 128*132*4 = 67584 <= 101376
  // ---- D = -pa ----
  #pragma unroll
  for(int q = 0; q < 16; ++q)
    *(f32x4*)&Td[a][b0 + q*4] = -pa[q];
  __syncthreads();
  #pragma unroll
  for(int c2 = 0; c2 < 16; ++c2){
    int ii = c2*1024 + tid*4;
    int row = ii >> 7, col = ii & 127;
    f32x4 dv = *(const f32x4*)&Td[row][col];
    *(f32x4*)(dF + ob + ii) = dv;
    u16 h0,l0,h1,l1,h2,l2,h3,l3;
    splitbf(dv[0], h0, l0); splitbf(dv[1], h1, l1);
    splitbf(dv[2], h2, l2); splitbf(dv[3], h3, l3);
    *(u32*)(dH + ob + ii)     = (u32)h0 | ((u32)h1 << 16);
    *(u32*)(dH + ob + ii + 2) = (u32)h2 | ((u32)h3 << 16);
    *(u32*)(dL + ob + ii)     = (u32)l0 | ((u32)l1 << 16);
    *(u32*)(dL + ob + ii + 2) = (u32)l2 | ((u32)l3 << 16);
  }
  // transposed hi/lo: out element [b][aa] = D[aa][b]
  #pragma unroll
  for(int c2 = 0; c2 < 8; ++c2){
    int o0 = c2*2048 + tid*8;
    int b = o0 >> 7, a0 = o0 & 127;
    u16 th[8], tl[8];
    #pragma unroll
    for(int e = 0; e < 8; ++e){
      float v = Td[a0 + e][b];
      splitbf(v, th[e], tl[e]);
    }
    uint4 ph = make_uint4((u32)th[0] | ((u32)th[1] << 16), (u32)th[2] | ((u32)th[3] << 16),
                          (u32)th[4] | ((u32)th[5] << 16), (u32)th[6] | ((u32)th[7] << 16));
    uint4 plv = make_uint4((u32)tl[0] | ((u32)tl[1] << 16), (u32)tl[2] | ((u32)tl[3] << 16),
                           (u32)tl[4] | ((u32)tl[5] << 16), (u32)tl[6] | ((u32)tl[7] << 16));
    *(uint4*)(dTH + ob + o0) = ph;
    *(uint4*)(dTL + ob + o0) = plv;
  }
  __syncthreads();
  // ---- BT = ca ----
  #pragma unroll
  for(int q = 0; q < 16; ++q)
    *(f32x4*)&Td[a][b0 + q*4] = ca[q];
  __syncthreads();
  #pragma unroll
  for(int c2 = 0; c2 < 16; ++c2){
    int ii = c2*1024 + tid*4;
    int row = ii >> 7, col = ii & 127;
    f32x4 cv = *(const f32x4*)&Td[row][col];
    *(f32x4*)(btF + ob + ii) = cv;
    u16 h0,l0,h1,l1,h2,l2,h3,l3;
    splitbf(cv[0], h0, l0); splitbf(cv[1], h1, l1);
    splitbf(cv[2], h2, l2); splitbf(cv[3], h3, l3);
    *(u32*)(btH + ob + ii)     = (u32)h0 | ((u32)h1 << 16);
    *(u32*)(btH + ob + ii + 2) = (u32)h2 | ((u32)h3 << 16);
    *(u32*)(btL + ob + ii)     = (u32)l0 | ((u32)l1 << 16);
    *(u32*)(btL + ob + ii + 2) = (u32)l2 | ((u32)l3 << 16);
  }
}

// ---------------- Kogge-Stone compose round (split-precision) ----------------
__global__ __launch_bounds__(256) void k_ks(
    const float* __restrict__ sDF, const u16* __restrict__ sDH, const u16* __restrict__ sDL,
    const u16* __restrict__ sDTH, const u16* __restrict__ sDTL,
    const float* __restrict__ sBF, const u16* __restrict__ sBH, const u16* __restrict__ sBL,
    float* __restrict__ dDF, u16* __restrict__ dDH, u16* __restrict__ dDL,
    u16* __restrict__ dDTH, u16* __restrict__ dDTL,
    float* __restrict__ dBF, u16* __restrict__ dBH, u16* __restrict__ dBL, int off){
  __shared__ float T[128][132];
  int c = blockIdx.x, g = blockIdx.y, z = blockIdx.z;
  int idx = g*32 + c, tid = threadIdx.x;
  size_t base = (size_t)idx * 16384;
  if(c < off){
    if(z == 0){
      for(int i = tid; i < 4096; i += 256) ((uint4*)(dDF + base))[i] = ((const uint4*)(sDF + base))[i];
      for(int i = tid; i < 2048; i += 256){
        ((uint4*)(dDH + base))[i] = ((const uint4*)(sDH + base))[i];
        ((uint4*)(dDL + base))[i] = ((const uint4*)(sDL + base))[i];
        ((uint4*)(dDTH + base))[i] = ((const uint4*)(sDTH + base))[i];
        ((uint4*)(dDTL + base))[i] = ((const uint4*)(sDTL + base))[i];
      }
    } else {
      for(int i = tid; i < 4096; i += 256) ((uint4*)(dBF + base))[i] = ((const uint4*)(sBF + base))[i];
      for(int i = tid; i < 2048; i += 256){
        ((uint4*)(dBH + base))[i] = ((const uint4*)(sBH + base))[i];
        ((uint4*)(dBL + base))[i] = ((const uint4*)(sBL + base))[i];
      }
    }
    return;
  }
  size_t blo = (size_t)(idx - off) * 16384;
  int lane = tid & 63, w = tid >> 6;
  const u16 *Ah, *Al, *Bh, *Bl;
  if(z == 0){ Ah = sDH + base; Al = sDL + base; Bh = sDTH + blo; Bl = sDTL + blo; }
  else      { Ah = sBH + blo;  Al = sBL + blo;  Bh = sDH + base; Bl = sDL + base; }
  f32x4 acc[2][8] = {};
  #pragma unroll
  for(int ks = 0; ks < 4; ++ks){
    bf16x8 ah[2], al[2], bh[8], bl[8];
    #pragma unroll
    for(int mt = 0; mt < 2; ++mt){
      int ro = (w*32 + mt*16 + (lane & 15))*128 + ks*32 + ((lane >> 4) << 3);
      ah[mt] = *(const bf16x8*)(Ah + ro);
      al[mt] = *(const bf16x8*)(Al + ro);
    }
    #pragma unroll
    for(int nt = 0; nt < 8; ++nt){
      int ro = (nt*16 + (lane & 15))*128 + ks*32 + ((lane >> 4) << 3);
      bh[nt] = *(const bf16x8*)(Bh + ro);
      bl[nt] = *(const bf16x8*)(Bl + ro);
    }
    #pragma unroll
    for(int mt = 0; mt < 2; ++mt)
      #pragma unroll
      for(int nt = 0; nt < 8; ++nt)
        acc[mt][nt] = MFMA16(ah[mt], bh[nt],
                      MFMA16(ah[mt], bl[nt],
                      MFMA16(al[mt], bh[nt], acc[mt][nt])));
  }
  if(z == 0){
    #pragma unroll
    for(int mt = 0; mt < 2; ++mt)
      #pragma unroll
      for(int nt = 0; nt < 8; ++nt)
        #pragma unroll
        for(int r = 0; r < 4; ++r){
          int row = w*32 + mt*16 + ((lane >> 4) << 2) + r;
          int col = nt*16 + (lane & 15);
          float v = acc[mt][nt][r] + sDF[base + row*128 + col] + sDF[blo + row*128 + col];
          dDF[base + row*128 + col] = v;
          u16 hi, lo; splitbf(v, hi, lo);
          dDH[base + row*128 + col] = hi;
          dDL[base + row*128 + col] = lo;
          T[row][col] = v;
        }
    __syncthreads();
    int tcol = tid >> 1, half = tid & 1;
    for(int m = 0; m < 64; ++m){
      float v = T[half*64 + m][tcol];
      u16 hi, lo; splitbf(v, hi, lo);
      dDTH[base + (size_t)tcol*128 + half*64 + m] = hi;
      dDTL[base + (size_t)tcol*128 + half*64 + m] = lo;
    }
  } else {
    #pragma unroll
    for(int mt = 0; mt < 2; ++mt)
      #pragma unroll
      for(int nt = 0; nt < 8; ++nt)
        #pragma unroll
        for(int r = 0; r < 4; ++r){
          int row = w*32 + mt*16 + ((lane >> 4) << 2) + r;
          int col = nt*16 + (lane & 15);
          float v = acc[mt][nt][r] + sBF[base + row*128 + col] + sBF[blo + row*128 + col];
          dBF[base + row*128 + col] = v;
          u16 hi, lo; splitbf(v, hi, lo);
          dBH[base + row*128 + col] = hi;
          dBL[base + row*128 + col] = lo;
        }
  }
}

// ---------------- hi/lo MFMA helper for 128x128 compose ----------------
__device__ __forceinline__ void comp_mfma(const u16* Ah, const u16* Al, const u16* Bh, const u16* Bl,
                                          f32x4 (&acc)[2][8], int lane, int w){
  #pragma unroll
  for(int ks = 0; ks < 4; ++ks){
    bf16x8 ah[2], al[2], bh[8], bl[8];
    #pragma unroll
    for(int mt = 0; mt < 2; ++mt){
      int ro = (w*32 + mt*16 + (lane & 15))*128 + ks*32 + ((lane >> 4) << 3);
      ah[mt] = *(const bf16x8*)(Ah + ro);
      al[mt] = *(const bf16x8*)(Al + ro);
    }
    #pragma unroll
    for(int nt = 0; nt < 8; ++nt){
      int ro = (nt*16 + (lane & 15))*128 + ks*32 + ((lane >> 4) << 3);
      bh[nt] = *(const bf16x8*)(Bh + ro);
      bl[nt] = *(const bf16x8*)(Bl + ro);
    }
    #pragma unroll
    for(int mt = 0; mt < 2; ++mt)
      #pragma unroll
      for(int nt = 0; nt < 8; ++nt)
        acc[mt][nt] = MFMA16(ah[mt], bh[nt],
                      MFMA16(ah[mt], bl[nt],
                      MFMA16(al[mt], bh[nt], acc[mt][nt])));
  }
}

// ---------------- generic compose with LDS-staged F-sums ----------------
__global__ __launch_bounds__(256) void k_comp(
    const float* __restrict__ bDF, const u16* __restrict__ bDH, const u16* __restrict__ bDL,
    const u16* __restrict__ bDTH, const u16* __restrict__ bDTL,
    const float* __restrict__ bBTF, const u16* __restrict__ bBTH, const u16* __restrict__ bBTL,
    float* __restrict__ pDF, u16* __restrict__ pDH, u16* __restrict__ pDL,
    u16* __restrict__ pDTH, u16* __restrict__ pDTL,
    float* __restrict__ pBTF, u16* __restrict__ pBTH, u16* __restrict__ pBTL,
    CompJobs jobs){
  __shared__ float T[128][132];
  int job = blockIdx.x, z = blockIdx.y, tid = threadIdx.x;
  int a = jobs.a[job], b = jobs.b[job], d = jobs.d[job] - 128;
  size_t ob = (size_t)d * 16384;
  int lane = tid & 63, w = tid >> 6;
  const u16 *Ah, *Al, *Bh, *Bl;
  const float *F1, *F2;
  if(z == 0){
    Ah = selu(bDH, pDH, a);  Al = selu(bDL, pDL, a);
    Bh = selu(bDTH, pDTH, b); Bl = selu(bDTL, pDTL, b);
    F1 = self32(bDF, pDF, a); F2 = self32(bDF, pDF, b);
  } else {
    Ah = selu(bBTH, pBTH, b); Al = selu(bBTL, pBTL, b);
    Bh = selu(bDH, pDH, a);   Bl = selu(bDL, pDL, a);
    F1 = self32(bBTF, pBTF, a); F2 = self32(bBTF, pBTF, b);
  }
  for(int i = tid*4; i < 16384; i += 1024){
    f32x4 v1 = *(const f32x4*)(F1 + i);
    f32x4 v2 = *(const f32x4*)(F2 + i);
    f32x4 sv = v1 + v2;
    int row = i >> 7, col = i & 127;
    *(f32x4*)&T[row][col] = sv;
  }
  __syncthreads();
  f32x4 acc[2][8] = {};
  comp_mfma(Ah, Al, Bh, Bl, acc, lane, w);
  if(z == 0){
    #pragma unroll
    for(int mt = 0; mt < 2; ++mt)
      #pragma unroll
      for(int nt = 0; nt < 8; ++nt)
        #pragma unroll
        for(int r = 0; r < 4; ++r){
          int row = w*32 + mt*16 + ((lane >> 4) << 2) + r;
          int col = nt*16 + (lane & 15);
          float v = acc[mt][nt][r] + T[row][col];
          pDF[ob + row*128 + col] = v;
          u16 hi, lo; splitbf(v, hi, lo);
          pDH[ob + row*128 + col] = hi;
          pDL[ob + row*128 + col] = lo;
          T[row][col] = v;
        }
    __syncthreads();
    int tcol = tid >> 1, half = tid & 1;
    for(int m = 0; m < 64; ++m){
      float v = T[half*64 + m][tcol];
      u16 hi, lo; splitbf(v, hi, lo);
      pDTH[ob + (size_t)tcol*128 + half*64 + m] = hi;
      pDTL[ob + (size_t)tcol*128 + half*64 + m] = lo;
    }
  } else {
    #pragma unroll
    for(int mt = 0; mt < 2; ++mt)
      #pragma unroll
      for(int nt = 0; nt < 8; ++nt)
        #pragma unroll
        for(int r = 0; r < 4; ++r){
          int row = w*32 + mt*16 + ((lane >> 4) << 2) + r;
          int col = nt*16 + (lane & 15);
          float v = acc[mt][nt][r] + T[row][col];
          pBTF[ob + row*128 + col] = v;
          u16 hi, lo; splitbf(v, hi, lo);
          pBTH[ob + row*128 + col] = hi;
          pBTL[ob + row*128 + col] = lo;
        }
  }
}

// ---------------- head starts (parallel, LDS-staged F) ----------------
__global__ __launch_bounds__(256) void k_heads(
    const u16* __restrict__ bDH, const u16* __restrict__ bDL,
    const float* __restrict__ bBTF, const u16* __restrict__ bBTH, const u16* __restrict__ bBTL,
    const u16* __restrict__ pDH, const u16* __restrict__ pDL,
    const float* __restrict__ pBTF, const u16* __restrict__ pBTH, const u16* __restrict__ pBTL,
    float* __restrict__ ttF, u16* __restrict__ ttH, u16* __restrict__ ttL, u16* __restrict__ sj){
  __shared__ float T[128][132];
  int h = blockIdx.x, g = h >> 2, i0 = h & 3;
  int tid = threadIdx.x, lane = tid & 63, w = tid >> 6;
  int psi = (g == 0) ? -1 : (g == 1 ? 136 : (g == 2 ? 140 : 142));
  int phi = (i0 == 0) ? -1 : (i0 == 1 ? g*32 + 31 : (i0 == 2 ? 128 + g : 132 + g));
  const float* Pf = (psi >= 0) ? self32(bBTF, pBTF, psi) : nullptr;
  const float* Ff = (phi >= 0) ? self32(bBTF, pBTF, phi) : nullptr;
  for(int i = tid*4; i < 16384; i += 1024){
    f32x4 sv = {};
    if(Pf) sv += *(const f32x4*)(Pf + i);
    if(Ff) sv += *(const f32x4*)(Ff + i);
    int row = i >> 7, col = i & 127;
    *(f32x4*)&T[row][col] = sv;
  }
  __syncthreads();
  f32x4 acc[2][8] = {};
  if(psi >= 0 && phi >= 0)
    comp_mfma(selu(bBTH,pBTH,psi), selu(bBTL,pBTL,psi), selu(bDH,pDH,phi), selu(bDL,pDL,phi), acc, lane, w);
  #pragma unroll
  for(int mt = 0; mt < 2; ++mt)
    #pragma unroll
    for(int nt = 0; nt < 8; ++nt)
      #pragma unroll
      for(int r = 0; r < 4; ++r){
        int row = w*32 + mt*16 + ((lane >> 4) << 2) + r;
        int col = nt*16 + (lane & 15);
        float v = acc[mt][nt][r] + T[row][col];
        u16 hi, lo; splitbf(v, hi, lo);
        size_t o = (size_t)h*16384 + row*128 + col;
        ttF[o] = v; ttH[o] = hi; ttL[o] = lo;
        sj[(size_t)(h*32)*16384 + row*128 + col] = hi;
      }
}

// ---------------- expand ----------------
__global__ __launch_bounds__(256) void k_expand(const u16* __restrict__ bDH, const u16* __restrict__ bDL,
                                                const float* __restrict__ bBF, const float* __restrict__ ttF,
                                                const u16* __restrict__ ttH, const u16* __restrict__ ttL,
                                                u16* __restrict__ sj){
  int j = blockIdx.x;
  int c = j & 31;
  if(c == 0) return;
  int h = j >> 5, g = h >> 2;
  size_t obase = (size_t)j * 16384;
  size_t mb = (size_t)(g*32 + c - 1) * 16384;
  size_t tb = (size_t)h * 16384;
  int tid = threadIdx.x, lane = tid & 63, w = tid >> 6;
  f32x4 acc[2][8] = {};
  comp_mfma(ttH + tb, ttL + tb, bDH + mb, bDL + mb, acc, lane, w);
  #pragma unroll
  for(int mt = 0; mt < 2; ++mt)
    #pragma unroll
    for(int nt = 0; nt < 8; ++nt)
      #pragma unroll
      for(int r = 0; r < 4; ++r){
        int row = w*32 + mt*16 + ((lane >> 4) << 2) + r;
        int col = nt*16 + (lane & 15);
        float v = acc[mt][nt][r] + ttF[tb + row*128 + col] + bBF[mb + row*128 + col];
        sj[obase + row*128 + col] = f2bf(v);
      }
}

// ---------------- o_lin ----------------
__global__ __launch_bounds__(256) void k_olin(const u16* __restrict__ qlb, const u16* __restrict__ klb,
                                              const u16* __restrict__ wb, const float* __restrict__ u0f,
                                              const u16* __restrict__ sj, float* __restrict__ omix){
  __shared__ u16 ut[128*64];
  __shared__ u16 pl[4][16*64];
  int j = blockIdx.x;
  int h = j >> 5, c = j & 31, g = h >> 2, idx = g*32 + c;
  int tid = threadIdx.x, lane = tid & 63, w = tid >> 6;
  const u16* Sj = sj + (size_t)j * 16384;
  const u16* Q  = qlb + ((size_t)h*2048 + c*64) * 128;
  const u16* Kc = klb + ((size_t)g*2048 + c*64) * 128;
  const u16* W  = wb + (size_t)idx * 8192;
  const float* U0 = u0f + (size_t)idx * 8192;
  bf16x8 aq[4], aw[4];
  #pragma unroll
  for(int ks = 0; ks < 4; ++ks){
    aq[ks] = *(const bf16x8*)(Q + (w*16 + (lane & 15))*128 + ks*32 + ((lane >> 4) << 3));
    aw[ks] = *(const bf16x8*)(W + (w*16 + (lane & 15))*128 + ks*32 + ((lane >> 4) << 3));
  }
  f32x4 t1[8] = {}, ui[8] = {};
  #pragma unroll
  for(int ks = 0; ks < 4; ++ks)
    #pragma unroll
    for(int nt = 0; nt < 8; ++nt){
      bf16x8 b = *(const bf16x8*)(Sj + (nt*16 + (lane & 15))*128 + ks*32 + ((lane >> 4) << 3));
      t1[nt] = MFMA16(aq[ks], b, t1[nt]);
      ui[nt] = MFMA16(aw[ks], b, ui[nt]);
    }
  f32x4 sc[4] = {};
  #pragma unroll
  for(int ks = 0; ks < 4; ++ks)
    #pragma unroll
    for(int nt = 0; nt < 4; ++nt){
      bf16x8 b = *(const bf16x8*)(Kc + (nt*16 + (lane & 15))*128 + ks*32 + ((lane >> 4) << 3));
      sc[nt] = MFMA16(aq[ks], b, sc[nt]);
    }
  #pragma unroll
  for(int nt = 0; nt < 4; ++nt)
    #pragma unroll
    for(int r = 0; r < 4; ++r){
      int row = ((lane >> 4) << 2) + r;
      int col = nt*16 + (lane & 15);
      int grow = w*16 + row;
      float v = (col <= grow) ? sc[nt][r] : 0.f;
      int bo = (row*128 + col*2) ^ ((row & 7) << 4);
      *(u16*)((char*)&pl[w][0] + bo) = f2bf(v);
    }
  #pragma unroll
  for(int nt = 0; nt < 8; ++nt)
    #pragma unroll
    for(int r = 0; r < 4; ++r){
      int kv = w*16 + ((lane >> 4) << 2) + r;
      int d  = nt*16 + (lane & 15);
      float v = U0[kv*128 + d] - ui[nt][r];
      int bo = (d*128 + kv*2) ^ ((d & 7) << 4);
      *(u16*)((char*)ut + bo) = f2bf(v);
    }
  __syncthreads();
  f32x4 o2[8] = {};
  #pragma unroll
  for(int ks2 = 0; ks2 < 2; ++ks2){
    int row = lane & 15;
    int boA = (row*128 + ks2*64 + ((lane >> 4) << 4)) ^ ((row & 7) << 4);
    bf16x8 a = *(const bf16x8*)((const char*)&pl[w][0] + boA);
    #pragma unroll
    for(int nt = 0; nt < 8; ++nt){
      int d = nt*16 + (lane & 15);
      int boB = (d*128 + ks2*64 + ((lane >> 4) << 4)) ^ ((d & 7) << 4);
      bf16x8 b = *(const bf16x8*)((const char*)ut + boB);
      o2[nt] = MFMA16(a, b, o2[nt]);
    }
  }
  #pragma unroll
  for(int nt = 0; nt < 8; ++nt)
    #pragma unroll
    for(int r = 0; r < 4; ++r){
      int grow = c*64 + w*16 + ((lane >> 4) << 2) + r;
      int d = nt*16 + (lane & 15);
      omix[(size_t)grow*2048 + h*128 + d] = 0.5f * (t1[nt][r] + o2[nt][r]);
    }
}

// ---------------- base causal attention v4: shared LDS K/V staging (swizzled), m97 2-barrier loop ----------------
__global__ __launch_bounds__(256) void k_attn(const u16* __restrict__ qbf, const u16* __restrict__ kbf,
                                              const u16* __restrict__ vT, const float* __restrict__ omix,
                                              u16* __restrict__ obf,
                                              float* __restrict__ part1, float* __restrict__ part2){
  __shared__ u16 Kl[4096];     // K tile [32 r][128 c] bf16, chunk-swizzled: chunk ^= (r&7)
  __shared__ u16 Vl[4096];     // V tile [128 d][32 n] bf16, chunk-swizzled: chunk ^= ((d>>1)&3)
  __shared__ u16 pl[4][1280];  // per-wave P: 32 rows x 80B
  int rb = blockIdx.x;
  int bid = (rb & 7) * 80 + (rb >> 3);   // XCD-chunked swizzle (640 % 8 == 0)
  int h = bid / 40, j = bid % 40;
  int qB, kt0, kt1, slot = -1;
  if(j < 4){ qB = j; kt0 = 0; kt1 = 4*(qB+1); }
  else {
    int jj = j - 4; int seg;
    if(jj < 8){ qB = 4 + (jj >> 1); seg = jj & 1; }
    else if(jj < 20){ int q = jj - 8; qB = 8 + q/3; seg = q - (qB-8)*3; }
    else { int q = jj - 20; qB = 12 + (q >> 2); seg = q & 3; }
    slot = h*36 + jj;
    kt0 = seg*16;
    int full = 4*(qB+1);
    kt1 = (kt0 + 16 < full) ? kt0 + 16 : full;
  }
  int g = h >> 2;
  int tid = threadIdx.x, lane = tid & 63, w = tid >> 6;
  const u16* K = kbf + (size_t)g*2048*128;
  const u16* V = vT + (size_t)g*128*2048;
  bf16x8 aq[2][4];
  #pragma unroll
  for(int m = 0; m < 2; ++m){
    const u16* Q = qbf + ((size_t)h*2048 + qB*128 + w*32 + m*16) * 128;
    #pragma unroll
    for(int ks = 0; ks < 4; ++ks)
      aq[m][ks] = *(const bf16x8*)(Q + (lane & 15)*128 + ks*32 + ((lane >> 4) << 3));
  }
  f32x4 acc[2][8] = {};
  float lsum[2][4] = {};
  const float scale = 0.08838834764831845f;
  int qr0[2];
  #pragma unroll
  for(int m = 0; m < 2; ++m) qr0[m] = qB*128 + w*32 + m*16 + ((lane >> 4) << 2);
  u16* plw = &pl[w][0];
  for(int kt = kt0; kt < kt1; ++kt){
    __syncthreads();
    #pragma unroll
    for(int inst = 0; inst < 2; ++inst){
      int ob = w*2048 + inst*1024;
      int lo = ob + lane*16;
      {
        int r = lo >> 8;
        int gc = ((lo >> 4) & 15) ^ (r & 7);
        gload_lds16(K + (size_t)(kt*32 + r)*128 + gc*8, (u16*)((char*)Kl + ob));
      }
      {
        int d = lo >> 6;
        int gnb = ((lo >> 4) & 3) ^ ((d >> 1) & 3);
        gload_lds16(V + (size_t)d*2048 + kt*32 + gnb*8, (u16*)((char*)Vl + ob));
      }
    }
    __syncthreads();
    bf16x8 kb[8];
    #pragma unroll
    for(int ct = 0; ct < 2; ++ct)
      #pragma unroll
      for(int ks = 0; ks < 4; ++ks){
        int r = ct*16 + (lane & 15);
        int pc = (ks*4 + (lane >> 4)) ^ (r & 7);
        kb[ct*4+ks] = *(const bf16x8*)(Kl + r*128 + pc*8);
      }
    f32x4 s[2][2] = {};
    #pragma unroll
    for(int m = 0; m < 2; ++m)
      #pragma unroll
      for(int ct = 0; ct < 2; ++ct)
        #pragma unroll
        for(int ks = 0; ks < 4; ++ks)
          s[m][ct] = MFMA16(aq[m][ks], kb[ct*4+ks], s[m][ct]);
    bf16x8 bv[8];
    #pragma unroll
    for(int nt = 0; nt < 8; ++nt){
      int d = nt*16 + (lane & 15);
      int pnb = (lane >> 4) ^ ((d >> 1) & 3);
      bv[nt] = *(const bf16x8*)(Vl + d*32 + pnb*8);
    }
    #pragma unroll
    for(int m = 0; m < 2; ++m)
      #pragma unroll
      for(int ct = 0; ct < 2; ++ct)
        #pragma unroll
        for(int r = 0; r < 4; ++r){
          int col = kt*32 + ct*16 + (lane & 15);
          float p = (col <= qr0[m] + r) ? __expf(s[m][ct][r] * scale) : 0.f;
          lsum[m][r] += p;
          int row = m*16 + ((lane >> 4) << 2) + r;
          *(u16*)((char*)plw + row*80 + (ct*16 + (lane & 15))*2) = f2bf(p);
        }
    __builtin_amdgcn_s_setprio(1);
    #pragma unroll
    for(int m = 0; m < 2; ++m){
      bf16x8 ap = *(const bf16x8*)((const char*)plw + (m*16 + (lane & 15))*80 + ((lane >> 4) << 4));
      #pragma unroll
      for(int nt = 0; nt < 8; ++nt)
        acc[m][nt] = MFMA16(ap, bv[nt], acc[m][nt]);
    }
    __builtin_amdgcn_s_setprio(0);
  }
  #pragma unroll
  for(int m = 0; m < 2; ++m)
    #pragma unroll
    for(int r = 0; r < 4; ++r){
      float v = lsum[m][r];
      v += __shfl_xor(v, 1, 64); v += __shfl_xor(v, 2, 64);
      v += __shfl_xor(v, 4, 64); v += __shfl_xor(v, 8, 64);
      lsum[m][r] = v;
    }
  if(slot < 0){
    #pragma unroll
    for(int m = 0; m < 2; ++m)
      #pragma unroll
      for(int nt = 0; nt < 8; ++nt)
        #pragma unroll
        for(int r = 0; r < 4; ++r){
          int row = qB*128 + w*32 + m*16 + ((lane >> 4) << 2) + r;
          int d = nt*16 + (lane & 15);
          size_t o = (size_t)row*2048 + h*128 + d;
          float fin = omix[o] + 0.5f * acc[m][nt][r] / lsum[m][r];
          obf[o] = f2bf(fin);
        }
  } else {
    float* P = slotp(part1, part2, slot);
    #pragma unroll
    for(int m = 0; m < 2; ++m)
      #pragma unroll
      for(int nt = 0; nt < 8; ++nt)
        #pragma unroll
        for(int r = 0; r < 4; ++r){
          int row = w*32 + m*16 + ((lane >> 4) << 2) + r;
          int d = nt*16 + (lane & 15);
          P[(size_t)row*128 + d] = acc[m][nt][r];
        }
    if((lane & 15) == 0)
      #pragma unroll
      for(int m = 0; m < 2; ++m)
        #pragma unroll
        for(int r = 0; r < 4; ++r)
          P[16384 + w*32 + m*16 + ((lane >> 4) << 2) + r] = lsum[m][r];
  }
}

// ---------------- combine attention K-segments; writes final bf16 omix ----------------
__global__ __launch_bounds__(256) void k_acomb(const float* __restrict__ part1, const float* __restrict__ part2,
                                               const float* __restrict__ omix, u16* __restrict__ obf){
  int bid = blockIdx.x;             // h*12 + (qB-4)
  int h = bid / 12, qx = bid % 12, qB = 4 + qx;
  int nseg = (qB >= 12) ? 4 : (qB >= 8) ? 3 : 2;
  int off = (qB < 8) ? (qB-4)*2 : (qB < 12) ? 8 + (qB-8)*3 : 20 + (qB-12)*4;
  int s0 = h*36 + off;
  int tid = threadIdx.x;
  #pragma unroll
  for(int it = 0; it < 16; ++it){
    int i = it*1024 + tid*4;
    int row = i >> 7;
    f32x4 a = {};
    float l = 0.f;
    for(int s = 0; s < nseg; ++s){
      const float* P = slotpc(part1, part2, s0 + s);
      a += *(const f32x4*)(P + i);
      l += P[16384 + row];
    }
    size_t idx = (size_t)(qB*128 + row)*2048 + h*128 + (i & 127);
    f32x4 cur = *(const f32x4*)(omix + idx);
    f32x4 fin = cur + a * (0.5f / l);
    u32 w0 = (u32)f2bf(fin[0]) | ((u32)f2bf(fin[1]) << 16);
    u32 w1 = (u32)f2bf(fin[2]) | ((u32)f2bf(fin[3]) << 16);
    *(u32*)(obf + idx) = w0;
    *(u32*)(obf + idx + 2) = w1;
  }
}

// ---------------- launch ----------------
extern "C" void kernel_launch(void* const* d_in, const int* in_sizes, int n_in,
                              void* d_out, int out_size, void* d_ws, size_t ws_size,
                              hipStream_t stream){
  (void)in_sizes; (void)n_in; (void)out_size; (void)ws_size;
  const float* hs = (const float*)d_in[0];
  const float* Wq = (const float*)d_in[1];
  const float* Wk = (const float*)d_in[2];
  const float* Wv = (const float*)d_in[3];
  const float* Wo = (const float*)d_in[4];
  float* out = (float*)d_out;
  char* ws = (char*)d_ws;

  u16*   hs_bf   = (u16*)(ws + OF_HSBF);
  u16*   wqkv_bf = (u16*)(ws + OF_WQKVBF);
  u16*   wo_bf   = (u16*)(ws + OF_WOBF);
  float* qkv     = (float*)(ws + OF_QKV);
  u16*   qbf     = (u16*)(ws + OF_QBF);
  u16*   kbf     = (u16*)(ws + OF_KBF);
  u16*   vT      = (u16*)(ws + OF_VT);
  u16*   qlb     = (u16*)(ws + OF_QLB);
  float* klf     = (float*)(ws + OF_KLF);
  u16*   klb     = (u16*)(ws + OF_KLB);
  float* glf     = (float*)(ws + OF_GLF);
  float* tinvb   = (float*)(ws + OF_TINV);
  float* wf      = (float*)(ws + OF_WF);
  u16*   wb      = (u16*)(ws + OF_WB);
  float* u0f     = (float*)(ws + OF_U0);
  u16*   sjb     = (u16*)(ws + OF_SJ);
  float* omix    = (float*)(ws + OF_OMIX);
  u16*   obf     = (u16*)(ws + OF_OBF);
  float* aDF  = (float*)(ws + OF_ADF);
  u16*   aDH  = (u16*)(ws + OF_ADH);
  u16*   aDL  = (u16*)(ws + OF_ADL);
  u16*   aDTH = (u16*)(ws + OF_ADTH);
  u16*   aDTL = (u16*)(ws + OF_ADTL);
  float* aBTF = (float*)(ws + OF_ABTF);
  u16*   aBTH = (u16*)(ws + OF_ABTH);
  u16*   aBTL = (u16*)(ws + OF_ABTL);
  float* bDF  = (float*)(ws + OF_BDF);
  u16*   bDH  = (u16*)(ws + OF_BDH);
  u16*   bDL  = (u16*)(ws + OF_BDL);
  u16*   bDTH = (u16*)(ws + OF_BDTH);
  u16*   bDTL = (u16*)(ws + OF_BDTL);
  float* bBTF = (float*)(ws + OF_BBTF);
  u16*   bBTH = (u16*)(ws + OF_BBTH);
  u16*   bBTL = (u16*)(ws + OF_BBTL);
  float* ttF  = (float*)(ws + OF_TTF);
  u16*   ttH  = (u16*)(ws + OF_TTH);
  u16*   ttL  = (u16*)(ws + OF_TTL);
  float* pDF  = (float*)(ws + OF_PDF);
  float* pBTF = (float*)(ws + OF_PBTF);
  u16*   pDH  = (u16*)(ws + OF_PDH);
  u16*   pDL  = (u16*)(ws + OF_PDL);
  u16*   pDTH = (u16*)(ws + OF_PDTH);
  u16*   pDTL = (u16*)(ws + OF_PDTL);
  u16*   pBTH = (u16*)(ws + OF_PBTH);
  u16*   pBTL = (u16*)(ws + OF_PBTL);
  float* apart1 = (float*)(ws + OF_APART1);
  float* apart2 = (float*)(ws + OF_APART2);

  k_f2ball<<<14336, 256, 0, stream>>>(hs, Wq, Wk, Wv, Wo, hs_bf, wqkv_bf, wo_bf);
  k_gemm<<<dim3(24, 16), 256, 0, stream>>>(hs_bf, wqkv_bf, qkv, 2048, 3072);
  k_linvt<<<10496, 256, 0, stream>>>(qkv, qbf, qlb, kbf, klf, klb, glf, vT);

  k_prep1<<<128, 256, 0, stream>>>(klf, glf, tinvb);
  k_prep2a<<<128, 256, 0, stream>>>(klf, glf, qkv, tinvb, wf, wb, u0f);
  k_prep2b<<<128, 256, 0, stream>>>(klf, wf, u0f, aDF, aDH, aDL, aDTH, aDTL, aBTF, aBTH, aBTL);

  k_ks<<<dim3(32, 4, 2), 256, 0, stream>>>(aDF, aDH, aDL, aDTH, aDTL, aBTF, aBTH, aBTL,
                                           bDF, bDH, bDL, bDTH, bDTL, bBTF, bBTH, bBTL, 1);
  k_ks<<<dim3(32, 4, 2), 256, 0, stream>>>(bDF, bDH, bDL, bDTH, bDTL, bBTF, bBTH, bBTL,
                                           aDF, aDH, aDL, aDTH, aDTL, aBTF, aBTH, aBTL, 2);
  k_ks<<<dim3(32, 4, 2), 256, 0, stream>>>(aDF, aDH, aDL, aDTH, aDTL, aBTF, aBTH, aBTL,
                                           bDF, bDH, bDL, bDTH, bDTL, bBTF, bBTH, bBTL, 4);
  k_ks<<<dim3(32, 4, 2), 256, 0, stream>>>(bDF, bDH, bDL, bDTH, bDTL, bBTF, bBTH, bBTL,
                                           aDF, aDH, aDL, aDTH, aDTL, aBTF, aBTH, aBTL, 8);
  k_ks<<<dim3(32, 4, 2), 256, 0, stream>>>(aDF, aDH, aDL, aDTH, aDTL, aBTF, aBTH, aBTL,
                                           bDF, bDH, bDL, bDTH, bDTL, bBTF, bBTH, bBTL, 16);

  CompJobs j1{}; // Phi_g^2
  for(int g = 0; g < 4; ++g){ j1.a[g] = g*32+31; j1.b[g] = g*32+31; j1.d[g] = 128+g; }
  k_comp<<<dim3(4, 2), 256, 0, stream>>>(bDF, bDH, bDL, bDTH, bDTL, bBTF, bBTH, bBTL,
                                         pDF, pDH, pDL, pDTH, pDTL, pBTF, pBTH, pBTL, j1);
  CompJobs j2{}; // Phi^3, Phi^4
  for(int g = 0; g < 4; ++g){
    j2.a[g]   = 128+g; j2.b[g]   = g*32+31; j2.d[g]   = 132+g;
    j2.a[4+g] = 128+g; j2.b[4+g] = 128+g;   j2.d[4+g] = 136+g;
  }
  k_comp<<<dim3(8, 2), 256, 0, stream>>>(bDF, bDH, bDL, bDTH, bDTL, bBTF, bBTH, bBTL,
                                         pDF, pDH, pDL, pDTH, pDTL, pBTF, pBTH, pBTL, j2);
  CompJobs j3{}; // Psi2; T
  j3.a[0] = 137; j3.b[0] = 136; j3.d[0] = 140;
  j3.a[1] = 138; j3.b[1] = 137; j3.d[1] = 141;
  k_comp<<<dim3(2, 2), 256, 0, stream>>>(bDF, bDH, bDL, bDTH, bDTL, bBTF, bBTH, bBTL,
                                         pDF, pDH, pDL, pDTH, pDTL, pBTF, pBTH, pBTL, j3);
  CompJobs j4{}; // Psi3
  j4.a[0] = 141; j4.b[0] = 136; j4.d[0] = 142;
  k_comp<<<dim3(1, 2), 256, 0, stream>>>(bDF, bDH, bDL, bDTH, bDTL, bBTF, bBTH, bBTL,
                                         pDF, pDH, pDL, pDTH, pDTL, pBTF, pBTH, pBTL, j4);

  k_heads<<<16, 256, 0, stream>>>(bDH, bDL, bBTF, bBTH, bBTL,
                                  pDH, pDL, pBTF, pBTH, pBTL, ttF, ttH, ttL, sjb);
  k_expand<<<512, 256, 0, stream>>>(bDH, bDL, bBTF, ttF, ttH, ttL, sjb);

  k_olin<<<512, 256, 0, stream>>>(qlb, klb, wb, u0f, sjb, omix);
  k_attn<<<640, 256, 0, stream>>>(qbf, kbf, vT, omix, obf, apart1, apart2);
  k_acomb<<<192, 256, 0, stream>>>(apart1, apart2, omix, obf);

  k_gemm<<<dim3(16, 16), 256, 0, stream>>>(obf, wo_bf, out, 2048, 2048);
}

// Round 12
// 617.438 us; speedup vs baseline: 1.4772x; 1.0527x over previous
//
#include <hip/hip_runtime.h>
#include <hip/hip_bf16.h>

typedef unsigned short u16;
typedef unsigned int u32;
typedef __bf16 bf16x8 __attribute__((ext_vector_type(8)));
typedef float f32x4 __attribute__((ext_vector_type(4)));

#define MFMA16(a,b,c) __builtin_amdgcn_mfma_f32_16x16x32_bf16((a),(b),(c),0,0,0)

__device__ __forceinline__ u16 f2bf(float f){
  u32 u = __builtin_bit_cast(u32, f);
  u32 r = (u + 0x7fffu + ((u >> 16) & 1u)) >> 16;
  return (u16)r;
}
__device__ __forceinline__ float bf2f(u16 h){
  u32 u = ((u32)h) << 16;
  return __builtin_bit_cast(float, u);
}
__device__ __forceinline__ void splitbf(float x, u16& hi, u16& lo){
  hi = f2bf(x);
  lo = f2bf(x - bf2f(hi));
}
__device__ __forceinline__ void gload_lds16(const u16* g, u16* l){
  __builtin_amdgcn_global_load_lds((__attribute__((address_space(1))) void*)(g),
                                   (__attribute__((address_space(3))) void*)(l), 16, 0, 0);
}
__device__ __forceinline__ const u16* selu(const u16* barr, const u16* parr, int i){
  return (i < 128) ? (barr + (size_t)i*16384) : (parr + (size_t)(i-128)*16384);
}
__device__ __forceinline__ const float* self32(const float* barr, const float* parr, int i){
  return (i < 128) ? (barr + (size_t)i*16384) : (parr + (size_t)(i-128)*16384);
}
// attention partial slots: 16512 f32 each (128x128 acc + 128 lsum)
__device__ __forceinline__ float* slotp(float* p1, float* p2, int s){
  return (s < 381) ? (p1 + (size_t)s*16512) : (p2 + (size_t)(s-381)*16512);
}
__device__ __forceinline__ const float* slotpc(const float* p1, const float* p2, int s){
  return (s < 381) ? (p1 + (size_t)s*16512) : (p2 + (size_t)(s-381)*16512);
}
// chunk-XOR swizzled [128][132] f32 tile addressing (16B chunks; colc = col>>2)
__device__ __forceinline__ float* tdq(float* Td, int row, int colc){
  return Td + row*132 + ((colc ^ ((row >> 3) & 7)) << 2);
}

// ---------------- workspace layout (bytes) ----------------
constexpr size_t OF_HSBF   = 0;
constexpr size_t OF_WQKVBF = 8388608;
constexpr size_t OF_WOBF   = 20971520;
constexpr size_t OF_QKV    = 29360128;
constexpr size_t OF_QBF    = 54525952;
constexpr size_t OF_KBF    = 62914560;
constexpr size_t OF_VT     = 65011712;
constexpr size_t OF_QLB    = 67108864;
constexpr size_t OF_KLF    = 75497472;
constexpr size_t OF_KLB    = 79691776;
constexpr size_t OF_GLF    = 81788928;
constexpr size_t OF_TINV   = 85983232;
constexpr size_t OF_WF     = 88080384;
constexpr size_t OF_WB     = 92274688;
constexpr size_t OF_U0     = 94371840;
constexpr size_t OF_SJ     = 111149056;
constexpr size_t OF_OMIX   = 127926272;
constexpr size_t OF_OMIXB  = 144703488;
constexpr size_t OF_ADF  = 102760448;
constexpr size_t OF_ABTF = OF_OMIX;
constexpr size_t OF_ADH  = OF_OMIX + 8388608;
constexpr size_t OF_ADL  = OF_OMIX + 12582912;
constexpr size_t OF_ADTH = OF_OMIXB;
constexpr size_t OF_ADTL = OF_OMIXB + 4194304;
constexpr size_t OF_ABTH = OF_KLF;
constexpr size_t OF_ABTL = OF_GLF;
constexpr size_t OF_BDF  = OF_QKV;
constexpr size_t OF_BBTF = OF_QKV + 8388608;
constexpr size_t OF_BDH  = OF_QKV + 16777216;
constexpr size_t OF_BDL  = OF_QKV + 20971520;
constexpr size_t OF_BDTH = OF_HSBF;
constexpr size_t OF_BDTL = OF_HSBF + 4194304;
constexpr size_t OF_BBTH = OF_WQKVBF;
constexpr size_t OF_BBTL = OF_WQKVBF + 4194304;
constexpr size_t OF_TTF  = OF_TINV;
constexpr size_t OF_TTH  = OF_WQKVBF + 8388608;
constexpr size_t OF_TTL  = OF_WQKVBF + 8912896;
constexpr size_t OF_PDF  = OF_ADF;
constexpr size_t OF_PBTF = OF_ADF + 1048576;
constexpr size_t OF_PDH  = OF_ADF + 2097152;
constexpr size_t OF_PDL  = OF_ADF + 2621440;
constexpr size_t OF_PDTH = OF_ADF + 3145728;
constexpr size_t OF_PDTL = OF_ADF + 3670016;
constexpr size_t OF_PBTH = OF_ADF + 4194304;
constexpr size_t OF_PBTL = OF_ADF + 4718592;
constexpr size_t OF_APART1 = OF_QKV;
constexpr size_t OF_APART2 = OF_OMIXB;
constexpr size_t OF_OBF = 0;

struct CompJobs { int a[8]; int b[8]; int d[8]; };

// ---------------- fused f2b of all 5 inputs ----------------
__global__ void k_f2ball(const float* __restrict__ hs, const float* __restrict__ Wq,
                         const float* __restrict__ Wk, const float* __restrict__ Wv,
                         const float* __restrict__ Wo, u16* __restrict__ hs_bf,
                         u16* __restrict__ wqkv_bf, u16* __restrict__ wo_bf){
  int bid = blockIdx.x;
  const float* src; u16* dst; int off;
  if(bid < 4096){ src = hs; dst = hs_bf; off = bid; }
  else if(bid < 8192){ src = Wq; dst = wqkv_bf; off = bid - 4096; }
  else if(bid < 9216){ src = Wk; dst = wqkv_bf + 2048*2048; off = bid - 8192; }
  else if(bid < 10240){ src = Wv; dst = wqkv_bf + 2560*2048; off = bid - 9216; }
  else { src = Wo; dst = wo_bf; off = bid - 10240; }
  int i = (off*256 + threadIdx.x) * 4;
  f32x4 v = *(const f32x4*)(src + i);
  u32 w0 = (u32)f2bf(v[0]) | ((u32)f2bf(v[1]) << 16);
  u32 w1 = (u32)f2bf(v[2]) | ((u32)f2bf(v[3]) << 16);
  *(u32*)(dst + i) = w0;
  *(u32*)(dst + i + 2) = w1;
}

// ---------------- bf16 NT GEMM with XCD-chunked swizzle ----------------
__global__ __launch_bounds__(256) void k_gemm(const u16* __restrict__ A, const u16* __restrict__ B,
                                              float* __restrict__ C, int K, int N){
  __shared__ u16 aL[128*32];
  __shared__ u16 bL[128*32];
  int lin = blockIdx.y * gridDim.x + blockIdx.x;
  int nwg = gridDim.x * gridDim.y;
  int s = (lin & 7) * (nwg >> 3) + (lin >> 3);
  int bn = s % gridDim.x, bm = s / gridDim.x;
  int tid = threadIdx.x, lane = tid & 63, w = tid >> 6;
  int wm = w >> 1, wn = w & 1;
  f32x4 acc[4][4] = {};
  int nK = K >> 5;
  const u16* Abase = A + (size_t)bm * 128 * K;
  const u16* Bbase = B + (size_t)bn * 128 * K;
  for(int kt = 0; kt < nK; ++kt){
    __syncthreads();
    #pragma unroll
    for(int t = 0; t < 2; ++t){
      int row = t*64 + w*16 + (lane >> 2);
      int kc = (lane & 3) * 8;
      gload_lds16(Abase + (size_t)row*K + kt*32 + kc, &aL[(t*64 + w*16)*32]);
      gload_lds16(Bbase + (size_t)row*K + kt*32 + kc, &bL[(t*64 + w*16)*32]);
    }
    __syncthreads();
    bf16x8 af[4], bf[4];
    #pragma unroll
    for(int i = 0; i < 4; ++i){
      af[i] = *(const bf16x8*)&aL[(wm*64 + i*16 + (lane & 15))*32 + ((lane >> 4) << 3)];
      bf[i] = *(const bf16x8*)&bL[(wn*64 + i*16 + (lane & 15))*32 + ((lane >> 4) << 3)];
    }
    #pragma unroll
    for(int i = 0; i < 4; ++i)
      #pragma unroll
      for(int j = 0; j < 4; ++j)
        acc[i][j] = MFMA16(af[i], bf[j], acc[i][j]);
  }
  #pragma unroll
  for(int i = 0; i < 4; ++i)
    #pragma unroll
    for(int j = 0; j < 4; ++j)
      #pragma unroll
      for(int r = 0; r < 4; ++r){
        int row = bm*128 + wm*64 + i*16 + ((lane >> 4) << 2) + r;
        int col = bn*128 + wn*64 + j*16 + (lane & 15);
        C[(size_t)row * N + col] = acc[i][j][r];
      }
}

// ---------------- fused linprep + V-transpose ----------------
__global__ __launch_bounds__(256) void k_linvt(const float* __restrict__ qkv, u16* qbf, u16* qlb,
                                               u16* kbf, float* klf, u16* klb, float* glf,
                                               u16* __restrict__ vT){
  __shared__ float t[64][65];
  int bid = blockIdx.x;
  if(bid < 10240){
    int gtask = bid * 4 + (threadIdx.x >> 6);
    int lane = threadIdx.x & 63;
    int n = gtask / 20, tt = gtask % 20;
    const float* row = (tt < 16) ? (qkv + (size_t)n*3072 + tt*128)
                                 : (qkv + (size_t)n*3072 + 2048 + (tt-16)*128);
    float v0 = row[lane], v1 = row[lane + 64];
    float m = fmaxf(v0, v1);
    #pragma unroll
    for(int o = 1; o < 64; o <<= 1) m = fmaxf(m, __shfl_xor(m, o, 64));
    float e0 = __expf(v0 - m), e1 = __expf(v1 - m);
    float s = e0 + e1;
    #pragma unroll
    for(int o = 1; o < 64; o <<= 1) s += __shfl_xor(s, o, 64);
    float r0 = e0 / s, r1 = e1 / s;
    if(tt < 16){
      size_t base = ((size_t)tt*2048 + n) * 128;
      qbf[base + lane] = f2bf(v0); qbf[base + 64 + lane] = f2bf(v1);
      qlb[base + lane] = f2bf(r0); qlb[base + 64 + lane] = f2bf(r1);
    } else {
      int g = tt - 16;
      size_t base = ((size_t)g*2048 + n) * 128;
      kbf[base + lane] = f2bf(v0); kbf[base + 64 + lane] = f2bf(v1);
      klf[base + lane] = r0;       klf[base + 64 + lane] = r1;
      klb[base + lane] = f2bf(r0); klb[base + 64 + lane] = f2bf(r1);
      float g0 = (fminf(v0, 0.f) - log1pf(__expf(-fabsf(v0)))) * (1.f/16.f);
      float g1 = (fminf(v1, 0.f) - log1pf(__expf(-fabsf(v1)))) * (1.f/16.f);
      glf[base + lane] = g0; glf[base + 64 + lane] = g1;
    }
  } else {
    int v = bid - 10240;
    int nt = v & 31, dt = (v >> 5) & 1, g = v >> 6;
    int tid = threadIdx.x;
    {
      int r = tid >> 2, c0 = (tid & 3) * 16;
      const float* src = qkv + (size_t)(nt*64 + r)*3072 + 2560 + g*128 + dt*64 + c0;
      #pragma unroll
      for(int q = 0; q < 16; q += 4){
        f32x4 vv = *(const f32x4*)(src + q);
        t[r][c0+q] = vv[0]; t[r][c0+q+1] = vv[1]; t[r][c0+q+2] = vv[2]; t[r][c0+q+3] = vv[3];
      }
    }
    __syncthreads();
    {
      int d = tid >> 2, c0 = (tid & 3) * 16;
      u16* dst = vT + ((size_t)g*128 + dt*64 + d)*2048 + (size_t)nt*64 + c0;
      #pragma unroll
      for(int half = 0; half < 2; ++half){
        int b = c0 + half*8;
        u32 w0 = (u32)f2bf(t[b+0][d]) | ((u32)f2bf(t[b+1][d]) << 16);
        u32 w1 = (u32)f2bf(t[b+2][d]) | ((u32)f2bf(t[b+3][d]) << 16);
        u32 w2 = (u32)f2bf(t[b+4][d]) | ((u32)f2bf(t[b+5][d]) << 16);
        u32 w3 = (u32)f2bf(t[b+6][d]) | ((u32)f2bf(t[b+7][d]) << 16);
        *(uint4*)(dst + half*8) = make_uint4(w0, w1, w2, w3);
      }
    }
  }
}

// ---------------- prep1 ----------------
__global__ __launch_bounds__(256) void k_prep1(const float* __restrict__ klf, const float* __restrict__ glf,
                                               float* __restrict__ tinv){
  __shared__ float KlT[128][68];
  __shared__ float Kb[64][132];
  __shared__ float Am[64][68];
  __shared__ float XT[64][68];
  int idx = blockIdx.x, g = idx >> 5, c = idx & 31, tid = threadIdx.x;
  size_t base = ((size_t)g*2048 + c*64) * 128;
  {
    int r = tid >> 2, d0 = (tid & 3) * 32;
    #pragma unroll
    for(int dd = 0; dd < 32; dd += 4){
      f32x4 kv = *(const f32x4*)(klf + base + r*128 + d0 + dd);
      f32x4 gv = *(const f32x4*)(glf + base + r*128 + d0 + dd);
      KlT[d0+dd][r] = kv[0]; KlT[d0+dd+1][r] = kv[1]; KlT[d0+dd+2][r] = kv[2]; KlT[d0+dd+3][r] = kv[3];
      f32x4 kb = kv * gv;
      *(f32x4*)&Kb[r][d0+dd] = kb;
    }
  }
  __syncthreads();
  {
    int i = tid >> 2, j0 = (tid & 3) * 16;
    f32x4 s[4] = {};
    for(int d = 0; d < 128; ++d){
      float kb = Kb[i][d];
      #pragma unroll
      for(int q = 0; q < 4; ++q){
        f32x4 kl = *(const f32x4*)&KlT[d][j0 + q*4];
        s[q] += kb * kl;
      }
    }
    #pragma unroll
    for(int q = 0; q < 4; ++q) *(f32x4*)&Am[i][j0 + q*4] = s[q];
  }
  __syncthreads();
  if(tid < 64){
    int cc = tid;
    float x0 = (cc == 0) ? 1.f : 0.f;
    XT[cc][0] = x0;
    tinv[(size_t)idx*4096 + cc] = x0;
    for(int i = 1; i < 64; ++i){
      float s = (i == cc) ? 1.f : 0.f;
      int i4 = i & ~3;
      for(int jj = 0; jj < i4; jj += 4){
        f32x4 av = *(const f32x4*)&Am[i][jj];
        f32x4 xv = *(const f32x4*)&XT[cc][jj];
        s -= av[0]*xv[0] + av[1]*xv[1] + av[2]*xv[2] + av[3]*xv[3];
      }
      for(int jj = i4; jj < i; ++jj) s -= Am[i][jj] * XT[cc][jj];
      XT[cc][i] = s;
      tinv[(size_t)idx*4096 + i*64 + cc] = s;
    }
  }
}

// ---------------- prep2a (split by z: z=0 -> w/wb, z=1 -> u0); coalesced writeback ----------------
__global__ __launch_bounds__(256) void k_prep2a(const float* __restrict__ klf, const float* __restrict__ glf,
                                                const float* __restrict__ qkv, const float* __restrict__ tinv,
                                                float* __restrict__ wf, u16* __restrict__ wb, float* __restrict__ u0f){
  __shared__ char smem[51200];
  float (*Ti)[68] = (float(*)[68])smem;               // 17408
  float (*B)[132] = (float(*)[132])(smem + 17408);    // 33792 (ends 51200)
  int bid = blockIdx.x, idx = bid >> 1, z = bid & 1;
  int g = idx >> 5, c = idx & 31, tid = threadIdx.x;
  size_t base = ((size_t)g*2048 + c*64) * 128;
  {
    int r = tid >> 2, d0 = (tid & 3) * 32;
    #pragma unroll
    for(int dd = 0; dd < 32; dd += 4){
      f32x4 gv = *(const f32x4*)(glf + base + r*128 + d0 + dd);
      f32x4 xv;
      if(z == 0) xv = *(const f32x4*)(klf + base + r*128 + d0 + dd);
      else       xv = *(const f32x4*)(qkv + (size_t)(c*64 + r)*3072 + 2560 + g*128 + d0 + dd);
      *(f32x4*)&B[r][d0+dd] = xv * gv;
    }
    int c0 = (tid & 3) * 16;
    #pragma unroll
    for(int q = 0; q < 16; q += 4)
      *(f32x4*)&Ti[r][c0+q] = *(const f32x4*)(tinv + (size_t)idx*4096 + r*64 + c0 + q);
  }
  __syncthreads();
  int i = tid >> 2, cc0 = (tid & 3) * 32;
  f32x4 wa[8] = {};
  for(int jj = 0; jj < 64; ++jj){
    float a = Ti[i][jj];
    #pragma unroll
    for(int q = 0; q < 8; ++q)
      wa[q] += a * *(const f32x4*)&B[jj][cc0 + q*4];
  }
  __syncthreads();
  float (*Tw)[132] = (float(*)[132])smem;             // 33792 <= 51200
  #pragma unroll
  for(int q = 0; q < 8; ++q)
    *(f32x4*)&Tw[i][cc0 + q*4] = wa[q];
  __syncthreads();
  size_t ob = (size_t)idx * 8192;
  #pragma unroll
  for(int c2 = 0; c2 < 8; ++c2){
    int ii = c2*1024 + tid*4;
    int row = ii >> 7, col = ii & 127;
    f32x4 wv = *(const f32x4*)&Tw[row][col];
    if(z == 0){
      *(f32x4*)(wf + ob + ii) = wv;
      u32 p0 = (u32)f2bf(wv[0]) | ((u32)f2bf(wv[1]) << 16);
      u32 p1 = (u32)f2bf(wv[2]) | ((u32)f2bf(wv[3]) << 16);
      *(u32*)(wb + ob + ii) = p0;
      *(u32*)(wb + ob + ii + 2) = p1;
    } else {
      *(f32x4*)(u0f + ob + ii) = wv;
    }
  }
}

// ---------------- prep2b (split by z: z=0 -> D (+transpose), z=1 -> BT); swizzled restage ----------------
__global__ __launch_bounds__(256) void k_prep2b(const float* __restrict__ klf, const float* __restrict__ wf,
                                                const float* __restrict__ u0f,
                                                float* __restrict__ dF, u16* __restrict__ dH, u16* __restrict__ dL,
                                                u16* __restrict__ dTH, u16* __restrict__ dTL,
                                                float* __restrict__ btF, u16* __restrict__ btH, u16* __restrict__ btL){
  __shared__ char smem[67584];
  float (*Kl)[132] = (float(*)[132])smem;             // 33792
  float (*Wm)[132] = (float(*)[132])(smem + 33792);   // 33792 (ends 67584)
  int bid = blockIdx.x, idx = bid >> 1, z = bid & 1;
  int g = idx >> 5, c = idx & 31, tid = threadIdx.x;
  size_t base = ((size_t)g*2048 + c*64) * 128;
  {
    int r = tid >> 2, d0 = (tid & 3) * 32;
    const float* src = (z == 0) ? wf : u0f;
    #pragma unroll
    for(int dd = 0; dd < 32; dd += 4){
      *(f32x4*)&Kl[r][d0+dd] = *(const f32x4*)(klf + base + r*128 + d0 + dd);
      *(f32x4*)&Wm[r][d0+dd] = *(const f32x4*)(src + (size_t)idx*8192 + r*128 + d0 + dd);
    }
  }
  __syncthreads();
  int a = tid >> 1, b0 = (tid & 1) * 64;
  f32x4 pa[16] = {};
  if(z == 0){
    // D[a][b] = -sum_r Kl[r][a]*Wm[r][b]
    for(int r = 0; r < 64; ++r){
      float ka = Kl[r][a];
      #pragma unroll
      for(int q = 0; q < 16; ++q)
        pa[q] += ka * *(const f32x4*)&Wm[r][b0 + q*4];
    }
    #pragma unroll
    for(int q = 0; q < 16; ++q) pa[q] = -pa[q];
  } else {
    // BT[a][b] = sum_r Um[r][a]*Kl[r][b]  (Wm holds u0)
    for(int r = 0; r < 64; ++r){
      float ua = Wm[r][a];
      #pragma unroll
      for(int q = 0; q < 16; ++q)
        pa[q] += ua * *(const f32x4*)&Kl[r][b0 + q*4];
    }
  }
  __syncthreads();
  float* Td = (float*)smem;   // 128*132*4 = 67584, chunk-XOR swizzled
  #pragma unroll
  for(int q = 0; q < 16; ++q)
    *(f32x4*)tdq(Td, a, (b0 >> 2) + q) = pa[q];
  __syncthreads();
  size_t ob = (size_t)idx * 16384;
  if(z == 0){
    #pragma unroll
    for(int c2 = 0; c2 < 16; ++c2){
      int ii = c2*1024 + tid*4;
      int row = ii >> 7, col = ii & 127;
      f32x4 dv = *(const f32x4*)tdq(Td, row, col >> 2);
      *(f32x4*)(dF + ob + ii) = dv;
      u16 h0,l0,h1,l1,h2,l2,h3,l3;
      splitbf(dv[0], h0, l0); splitbf(dv[1], h1, l1);
      splitbf(dv[2], h2, l2); splitbf(dv[3], h3, l3);
      *(u32*)(dH + ob + ii)     = (u32)h0 | ((u32)h1 << 16);
      *(u32*)(dH + ob + ii + 2) = (u32)h2 | ((u32)h3 << 16);
      *(u32*)(dL + ob + ii)     = (u32)l0 | ((u32)l1 << 16);
      *(u32*)(dL + ob + ii + 2) = (u32)l2 | ((u32)l3 << 16);
    }
    // transposed hi/lo: out [b][a0..a0+7]
    #pragma unroll
    for(int c2 = 0; c2 < 8; ++c2){
      int o0 = c2*2048 + tid*8;
      int b = o0 >> 7, a0 = o0 & 127;
      u16 th[8], tl[8];
      #pragma unroll
      for(int e = 0; e < 8; ++e){
        float v = *((const float*)tdq(Td, a0 + e, b >> 2) + (b & 3));
        splitbf(v, th[e], tl[e]);
      }
      uint4 ph = make_uint4((u32)th[0] | ((u32)th[1] << 16), (u32)th[2] | ((u32)th[3] << 16),
                            (u32)th[4] | ((u32)th[5] << 16), (u32)th[6] | ((u32)th[7] << 16));
      uint4 plv = make_uint4((u32)tl[0] | ((u32)tl[1] << 16), (u32)tl[2] | ((u32)tl[3] << 16),
                             (u32)tl[4] | ((u32)tl[5] << 16), (u32)tl[6] | ((u32)tl[7] << 16));
      *(uint4*)(dTH + ob + o0) = ph;
      *(uint4*)(dTL + ob + o0) = plv;
    }
  } else {
    #pragma unroll
    for(int c2 = 0; c2 < 16; ++c2){
      int ii = c2*1024 + tid*4;
      int row = ii >> 7, col = ii & 127;
      f32x4 cv = *(const f32x4*)tdq(Td, row, col >> 2);
      *(f32x4*)(btF + ob + ii) = cv;
      u16 h0,l0,h1,l1,h2,l2,h3,l3;
      splitbf(cv[0], h0, l0); splitbf(cv[1], h1, l1);
      splitbf(cv[2], h2, l2); splitbf(cv[3], h3, l3);
      *(u32*)(btH + ob + ii)     = (u32)h0 | ((u32)h1 << 16);
      *(u32*)(btH + ob + ii + 2) = (u32)h2 | ((u32)h3 << 16);
      *(u32*)(btL + ob + ii)     = (u32)l0 | ((u32)l1 << 16);
      *(u32*)(btL + ob + ii + 2) = (u32)l2 | ((u32)l3 << 16);
    }
  }
}

// ---------------- Kogge-Stone compose round (split-precision) ----------------
__global__ __launch_bounds__(256) void k_ks(
    const float* __restrict__ sDF, const u16* __restrict__ sDH, const u16* __restrict__ sDL,
    const u16* __restrict__ sDTH, const u16* __restrict__ sDTL,
    const float* __restrict__ sBF, const u16* __restrict__ sBH, const u16* __restrict__ sBL,
    float* __restrict__ dDF, u16* __restrict__ dDH, u16* __restrict__ dDL,
    u16* __restrict__ dDTH, u16* __restrict__ dDTL,
    float* __restrict__ dBF, u16* __restrict__ dBH, u16* __restrict__ dBL, int off){
  __shared__ float T[128][132];
  int c = blockIdx.x, g = blockIdx.y, z = blockIdx.z;
  int idx = g*32 + c, tid = threadIdx.x;
  size_t base = (size_t)idx * 16384;
  if(c < off){
    if(z == 0){
      for(int i = tid; i < 4096; i += 256) ((uint4*)(dDF + base))[i] = ((const uint4*)(sDF + base))[i];
      for(int i = tid; i < 2048; i += 256){
        ((uint4*)(dDH + base))[i] = ((const uint4*)(sDH + base))[i];
        ((uint4*)(dDL + base))[i] = ((const uint4*)(sDL + base))[i];
        ((uint4*)(dDTH + base))[i] = ((const uint4*)(sDTH + base))[i];
        ((uint4*)(dDTL + base))[i] = ((const uint4*)(sDTL + base))[i];
      }
    } else {
      for(int i = tid; i < 4096; i += 256) ((uint4*)(dBF + base))[i] = ((const uint4*)(sBF + base))[i];
      for(int i = tid; i < 2048; i += 256){
        ((uint4*)(dBH + base))[i] = ((const uint4*)(sBH + base))[i];
        ((uint4*)(dBL + base))[i] = ((const uint4*)(sBL + base))[i];
      }
    }
    return;
  }
  size_t blo = (size_t)(idx - off) * 16384;
  int lane = tid & 63, w = tid >> 6;
  const u16 *Ah, *Al, *Bh, *Bl;
  if(z == 0){ Ah = sDH + base; Al = sDL + base; Bh = sDTH + blo; Bl = sDTL + blo; }
  else      { Ah = sBH + blo;  Al = sBL + blo;  Bh = sDH + base; Bl = sDL + base; }
  f32x4 acc[2][8] = {};
  #pragma unroll
  for(int ks = 0; ks < 4; ++ks){
    bf16x8 ah[2], al[2], bh[8], bl[8];
    #pragma unroll
    for(int mt = 0; mt < 2; ++mt){
      int ro = (w*32 + mt*16 + (lane & 15))*128 + ks*32 + ((lane >> 4) << 3);
      ah[mt] = *(const bf16x8*)(Ah + ro);
      al[mt] = *(const bf16x8*)(Al + ro);
    }
    #pragma unroll
    for(int nt = 0; nt < 8; ++nt){
      int ro = (nt*16 + (lane & 15))*128 + ks*32 + ((lane >> 4) << 3);
      bh[nt] = *(const bf16x8*)(Bh + ro);
      bl[nt] = *(const bf16x8*)(Bl + ro);
    }
    #pragma unroll
    for(int mt = 0; mt < 2; ++mt)
      #pragma unroll
      for(int nt = 0; nt < 8; ++nt)
        acc[mt][nt] = MFMA16(ah[mt], bh[nt],
                      MFMA16(ah[mt], bl[nt],
                      MFMA16(al[mt], bh[nt], acc[mt][nt])));
  }
  if(z == 0){
    #pragma unroll
    for(int mt = 0; mt < 2; ++mt)
      #pragma unroll
      for(int nt = 0; nt < 8; ++nt)
        #pragma unroll
        for(int r = 0; r < 4; ++r){
          int row = w*32 + mt*16 + ((lane >> 4) << 2) + r;
          int col = nt*16 + (lane & 15);
          float v = acc[mt][nt][r] + sDF[base + row*128 + col] + sDF[blo + row*128 + col];
          dDF[base + row*128 + col] = v;
          u16 hi, lo; splitbf(v, hi, lo);
          dDH[base + row*128 + col] = hi;
          dDL[base + row*128 + col] = lo;
          T[row][col] = v;
        }
    __syncthreads();
    int tcol = tid >> 1, half = tid & 1;
    for(int m = 0; m < 64; ++m){
      float v = T[half*64 + m][tcol];
      u16 hi, lo; splitbf(v, hi, lo);
      dDTH[base + (size_t)tcol*128 + half*64 + m] = hi;
      dDTL[base + (size_t)tcol*128 + half*64 + m] = lo;
    }
  } else {
    #pragma unroll
    for(int mt = 0; mt < 2; ++mt)
      #pragma unroll
      for(int nt = 0; nt < 8; ++nt)
        #pragma unroll
        for(int r = 0; r < 4; ++r){
          int row = w*32 + mt*16 + ((lane >> 4) << 2) + r;
          int col = nt*16 + (lane & 15);
          float v = acc[mt][nt][r] + sBF[base + row*128 + col] + sBF[blo + row*128 + col];
          dBF[base + row*128 + col] = v;
          u16 hi, lo; splitbf(v, hi, lo);
          dBH[base + row*128 + col] = hi;
          dBL[base + row*128 + col] = lo;
        }
  }
}

// ---------------- hi/lo MFMA helper for 128x128 compose ----------------
__device__ __forceinline__ void comp_mfma(const u16* Ah, const u16* Al, const u16* Bh, const u16* Bl,
                                          f32x4 (&acc)[2][8], int lane, int w){
  #pragma unroll
  for(int ks = 0; ks < 4; ++ks){
    bf16x8 ah[2], al[2], bh[8], bl[8];
    #pragma unroll
    for(int mt = 0; mt < 2; ++mt){
      int ro = (w*32 + mt*16 + (lane & 15))*128 + ks*32 + ((lane >> 4) << 3);
      ah[mt] = *(const bf16x8*)(Ah + ro);
      al[mt] = *(const bf16x8*)(Al + ro);
    }
    #pragma unroll
    for(int nt = 0; nt < 8; ++nt){
      int ro = (nt*16 + (lane & 15))*128 + ks*32 + ((lane >> 4) << 3);
      bh[nt] = *(const bf16x8*)(Bh + ro);
      bl[nt] = *(const bf16x8*)(Bl + ro);
    }
    #pragma unroll
    for(int mt = 0; mt < 2; ++mt)
      #pragma unroll
      for(int nt = 0; nt < 8; ++nt)
        acc[mt][nt] = MFMA16(ah[mt], bh[nt],
                      MFMA16(ah[mt], bl[nt],
                      MFMA16(al[mt], bh[nt], acc[mt][nt])));
  }
}

// ---------------- generic compose with LDS-staged F-sums ----------------
__global__ __launch_bounds__(256) void k_comp(
    const float* __restrict__ bDF, const u16* __restrict__ bDH, const u16* __restrict__ bDL,
    const u16* __restrict__ bDTH, const u16* __restrict__ bDTL,
    const float* __restrict__ bBTF, const u16* __restrict__ bBTH, const u16* __restrict__ bBTL,
    float* __restrict__ pDF, u16* __restrict__ pDH, u16* __restrict__ pDL,
    u16* __restrict__ pDTH, u16* __restrict__ pDTL,
    float* __restrict__ pBTF, u16* __restrict__ pBTH, u16* __restrict__ pBTL,
    CompJobs jobs){
  __shared__ float T[128][132];
  int job = blockIdx.x, z = blockIdx.y, tid = threadIdx.x;
  int a = jobs.a[job], b = jobs.b[job], d = jobs.d[job] - 128;
  size_t ob = (size_t)d * 16384;
  int lane = tid & 63, w = tid >> 6;
  const u16 *Ah, *Al, *Bh, *Bl;
  const float *F1, *F2;
  if(z == 0){
    Ah = selu(bDH, pDH, a);  Al = selu(bDL, pDL, a);
    Bh = selu(bDTH, pDTH, b); Bl = selu(bDTL, pDTL, b);
    F1 = self32(bDF, pDF, a); F2 = self32(bDF, pDF, b);
  } else {
    Ah = selu(bBTH, pBTH, b); Al = selu(bBTL, pBTL, b);
    Bh = selu(bDH, pDH, a);   Bl = selu(bDL, pDL, a);
    F1 = self32(bBTF, pBTF, a); F2 = self32(bBTF, pBTF, b);
  }
  for(int i = tid*4; i < 16384; i += 1024){
    f32x4 v1 = *(const f32x4*)(F1 + i);
    f32x4 v2 = *(const f32x4*)(F2 + i);
    f32x4 sv = v1 + v2;
    int row = i >> 7, col = i & 127;
    *(f32x4*)&T[row][col] = sv;
  }
  __syncthreads();
  f32x4 acc[2][8] = {};
  comp_mfma(Ah, Al, Bh, Bl, acc, lane, w);
  if(z == 0){
    #pragma unroll
    for(int mt = 0; mt < 2; ++mt)
      #pragma unroll
      for(int nt = 0; nt < 8; ++nt)
        #pragma unroll
        for(int r = 0; r < 4; ++r){
          int row = w*32 + mt*16 + ((lane >> 4) << 2) + r;
          int col = nt*16 + (lane & 15);
          float v = acc[mt][nt][r] + T[row][col];
          pDF[ob + row*128 + col] = v;
          u16 hi, lo; splitbf(v, hi, lo);
          pDH[ob + row*128 + col] = hi;
          pDL[ob + row*128 + col] = lo;
          T[row][col] = v;
        }
    __syncthreads();
    int tcol = tid >> 1, half = tid & 1;
    for(int m = 0; m < 64; ++m){
      float v = T[half*64 + m][tcol];
      u16 hi, lo; splitbf(v, hi, lo);
      pDTH[ob + (size_t)tcol*128 + half*64 + m] = hi;
      pDTL[ob + (size_t)tcol*128 + half*64 + m] = lo;
    }
  } else {
    #pragma unroll
    for(int mt = 0; mt < 2; ++mt)
      #pragma unroll
      for(int nt = 0; nt < 8; ++nt)
        #pragma unroll
        for(int r = 0; r < 4; ++r){
          int row = w*32 + mt*16 + ((lane >> 4) << 2) + r;
          int col = nt*16 + (lane & 15);
          float v = acc[mt][nt][r] + T[row][col];
          pBTF[ob + row*128 + col] = v;
          u16 hi, lo; splitbf(v, hi, lo);
          pBTH[ob + row*128 + col] = hi;
          pBTL[ob + row*128 + col] = lo;
        }
  }
}

// ---------------- head starts (parallel, LDS-staged F) ----------------
__global__ __launch_bounds__(256) void k_heads(
    const u16* __restrict__ bDH, const u16* __restrict__ bDL,
    const float* __restrict__ bBTF, const u16* __restrict__ bBTH, const u16* __restrict__ bBTL,
    const u16* __restrict__ pDH, const u16* __restrict__ pDL,
    const float* __restrict__ pBTF, const u16* __restrict__ pBTH, const u16* __restrict__ pBTL,
    float* __restrict__ ttF, u16* __restrict__ ttH, u16* __restrict__ ttL, u16* __restrict__ sj){
  __shared__ float T[128][132];
  int h = blockIdx.x, g = h >> 2, i0 = h & 3;
  int tid = threadIdx.x, lane = tid & 63, w = tid >> 6;
  int psi = (g == 0) ? -1 : (g == 1 ? 136 : (g == 2 ? 140 : 142));
  int phi = (i0 == 0) ? -1 : (i0 == 1 ? g*32 + 31 : (i0 == 2 ? 128 + g : 132 + g));
  const float* Pf = (psi >= 0) ? self32(bBTF, pBTF, psi) : nullptr;
  const float* Ff = (phi >= 0) ? self32(bBTF, pBTF, phi) : nullptr;
  for(int i = tid*4; i < 16384; i += 1024){
    f32x4 sv = {};
    if(Pf) sv += *(const f32x4*)(Pf + i);
    if(Ff) sv += *(const f32x4*)(Ff + i);
    int row = i >> 7, col = i & 127;
    *(f32x4*)&T[row][col] = sv;
  }
  __syncthreads();
  f32x4 acc[2][8] = {};
  if(psi >= 0 && phi >= 0)
    comp_mfma(selu(bBTH,pBTH,psi), selu(bBTL,pBTL,psi), selu(bDH,pDH,phi), selu(bDL,pDL,phi), acc, lane, w);
  #pragma unroll
  for(int mt = 0; mt < 2; ++mt)
    #pragma unroll
    for(int nt = 0; nt < 8; ++nt)
      #pragma unroll
      for(int r = 0; r < 4; ++r){
        int row = w*32 + mt*16 + ((lane >> 4) << 2) + r;
        int col = nt*16 + (lane & 15);
        float v = acc[mt][nt][r] + T[row][col];
        u16 hi, lo; splitbf(v, hi, lo);
        size_t o = (size_t)h*16384 + row*128 + col;
        ttF[o] = v; ttH[o] = hi; ttL[o] = lo;
        sj[(size_t)(h*32)*16384 + row*128 + col] = hi;
      }
}

// ---------------- expand ----------------
__global__ __launch_bounds__(256) void k_expand(const u16* __restrict__ bDH, const u16* __restrict__ bDL,
                                                const float* __restrict__ bBF, const float* __restrict__ ttF,
                                                const u16* __restrict__ ttH, const u16* __restrict__ ttL,
                                                u16* __restrict__ sj){
  int j = blockIdx.x;
  int c = j & 31;
  if(c == 0) return;
  int h = j >> 5, g = h >> 2;
  size_t obase = (size_t)j * 16384;
  size_t mb = (size_t)(g*32 + c - 1) * 16384;
  size_t tb = (size_t)h * 16384;
  int tid = threadIdx.x, lane = tid & 63, w = tid >> 6;
  f32x4 acc[2][8] = {};
  comp_mfma(ttH + tb, ttL + tb, bDH + mb, bDL + mb, acc, lane, w);
  #pragma unroll
  for(int mt = 0; mt < 2; ++mt)
    #pragma unroll
    for(int nt = 0; nt < 8; ++nt)
      #pragma unroll
      for(int r = 0; r < 4; ++r){
        int row = w*32 + mt*16 + ((lane >> 4) << 2) + r;
        int col = nt*16 + (lane & 15);
        float v = acc[mt][nt][r] + ttF[tb + row*128 + col] + bBF[mb + row*128 + col];
        sj[obase + row*128 + col] = f2bf(v);
      }
}

// ---------------- o_lin ----------------
__global__ __launch_bounds__(256) void k_olin(const u16* __restrict__ qlb, const u16* __restrict__ klb,
                                              const u16* __restrict__ wb, const float* __restrict__ u0f,
                                              const u16* __restrict__ sj, float* __restrict__ omix){
  __shared__ u16 ut[128*64];
  __shared__ u16 pl[4][16*64];
  int j = blockIdx.x;
  int h = j >> 5, c = j & 31, g = h >> 2, idx = g*32 + c;
  int tid = threadIdx.x, lane = tid & 63, w = tid >> 6;
  const u16* Sj = sj + (size_t)j * 16384;
  const u16* Q  = qlb + ((size_t)h*2048 + c*64) * 128;
  const u16* Kc = klb + ((size_t)g*2048 + c*64) * 128;
  const u16* W  = wb + (size_t)idx * 8192;
  const float* U0 = u0f + (size_t)idx * 8192;
  bf16x8 aq[4], aw[4];
  #pragma unroll
  for(int ks = 0; ks < 4; ++ks){
    aq[ks] = *(const bf16x8*)(Q + (w*16 + (lane & 15))*128 + ks*32 + ((lane >> 4) << 3));
    aw[ks] = *(const bf16x8*)(W + (w*16 + (lane & 15))*128 + ks*32 + ((lane >> 4) << 3));
  }
  f32x4 t1[8] = {}, ui[8] = {};
  #pragma unroll
  for(int ks = 0; ks < 4; ++ks)
    #pragma unroll
    for(int nt = 0; nt < 8; ++nt){
      bf16x8 b = *(const bf16x8*)(Sj + (nt*16 + (lane & 15))*128 + ks*32 + ((lane >> 4) << 3));
      t1[nt] = MFMA16(aq[ks], b, t1[nt]);
      ui[nt] = MFMA16(aw[ks], b, ui[nt]);
    }
  f32x4 sc[4] = {};
  #pragma unroll
  for(int ks = 0; ks < 4; ++ks)
    #pragma unroll
    for(int nt = 0; nt < 4; ++nt){
      bf16x8 b = *(const bf16x8*)(Kc + (nt*16 + (lane & 15))*128 + ks*32 + ((lane >> 4) << 3));
      sc[nt] = MFMA16(aq[ks], b, sc[nt]);
    }
  #pragma unroll
  for(int nt = 0; nt < 4; ++nt)
    #pragma unroll
    for(int r = 0; r < 4; ++r){
      int row = ((lane >> 4) << 2) + r;
      int col = nt*16 + (lane & 15);
      int grow = w*16 + row;
      float v = (col <= grow) ? sc[nt][r] : 0.f;
      int bo = (row*128 + col*2) ^ ((row & 7) << 4);
      *(u16*)((char*)&pl[w][0] + bo) = f2bf(v);
    }
  #pragma unroll
  for(int nt = 0; nt < 8; ++nt)
    #pragma unroll
    for(int r = 0; r < 4; ++r){
      int kv = w*16 + ((lane >> 4) << 2) + r;
      int d  = nt*16 + (lane & 15);
      float v = U0[kv*128 + d] - ui[nt][r];
      int bo = (d*128 + kv*2) ^ ((d & 7) << 4);
      *(u16*)((char*)ut + bo) = f2bf(v);
    }
  __syncthreads();
  f32x4 o2[8] = {};
  #pragma unroll
  for(int ks2 = 0; ks2 < 2; ++ks2){
    int row = lane & 15;
    int boA = (row*128 + ks2*64 + ((lane >> 4) << 4)) ^ ((row & 7) << 4);
    bf16x8 a = *(const bf16x8*)((const char*)&pl[w][0] + boA);
    #pragma unroll
    for(int nt = 0; nt < 8; ++nt){
      int d = nt*16 + (lane & 15);
      int boB = (d*128 + ks2*64 + ((lane >> 4) << 4)) ^ ((d & 7) << 4);
      bf16x8 b = *(const bf16x8*)((const char*)ut + boB);
      o2[nt] = MFMA16(a, b, o2[nt]);
    }
  }
  #pragma unroll
  for(int nt = 0; nt < 8; ++nt)
    #pragma unroll
    for(int r = 0; r < 4; ++r){
      int grow = c*64 + w*16 + ((lane >> 4) << 2) + r;
      int d = nt*16 + (lane & 15);
      omix[(size_t)grow*2048 + h*128 + d] = 0.5f * (t1[nt][r] + o2[nt][r]);
    }
}

// ---------------- base causal attention v4: shared LDS K/V staging (swizzled), m97 2-barrier loop ----------------
__global__ __launch_bounds__(256) void k_attn(const u16* __restrict__ qbf, const u16* __restrict__ kbf,
                                              const u16* __restrict__ vT, const float* __restrict__ omix,
                                              u16* __restrict__ obf,
                                              float* __restrict__ part1, float* __restrict__ part2){
  __shared__ u16 Kl[4096];     // K tile [32 r][128 c] bf16, chunk-swizzled: chunk ^= (r&7)
  __shared__ u16 Vl[4096];     // V tile [128 d][32 n] bf16, chunk-swizzled: chunk ^= ((d>>1)&3)
  __shared__ u16 pl[4][1280];  // per-wave P: 32 rows x 80B
  int rb = blockIdx.x;
  int bid = (rb & 7) * 80 + (rb >> 3);   // XCD-chunked swizzle (640 % 8 == 0)
  int h = bid / 40, j = bid % 40;
  int qB, kt0, kt1, slot = -1;
  if(j < 4){ qB = j; kt0 = 0; kt1 = 4*(qB+1); }
  else {
    int jj = j - 4; int seg;
    if(jj < 8){ qB = 4 + (jj >> 1); seg = jj & 1; }
    else if(jj < 20){ int q = jj - 8; qB = 8 + q/3; seg = q - (qB-8)*3; }
    else { int q = jj - 20; qB = 12 + (q >> 2); seg = q & 3; }
    slot = h*36 + jj;
    kt0 = seg*16;
    int full = 4*(qB+1);
    kt1 = (kt0 + 16 < full) ? kt0 + 16 : full;
  }
  int g = h >> 2;
  int tid = threadIdx.x, lane = tid & 63, w = tid >> 6;
  const u16* K = kbf + (size_t)g*2048*128;
  const u16* V = vT + (size_t)g*128*2048;
  bf16x8 aq[2][4];
  #pragma unroll
  for(int m = 0; m < 2; ++m){
    const u16* Q = qbf + ((size_t)h*2048 + qB*128 + w*32 + m*16) * 128;
    #pragma unroll
    for(int ks = 0; ks < 4; ++ks)
      aq[m][ks] = *(const bf16x8*)(Q + (lane & 15)*128 + ks*32 + ((lane >> 4) << 3));
  }
  f32x4 acc[2][8] = {};
  float lsum[2][4] = {};
  const float scale = 0.08838834764831845f;
  int qr0[2];
  #pragma unroll
  for(int m = 0; m < 2; ++m) qr0[m] = qB*128 + w*32 + m*16 + ((lane >> 4) << 2);
  u16* plw = &pl[w][0];
  for(int kt = kt0; kt < kt1; ++kt){
    __syncthreads();
    #pragma unroll
    for(int inst = 0; inst < 2; ++inst){
      int ob = w*2048 + inst*1024;
      int lo = ob + lane*16;
      {
        int r = lo >> 8;
        int gc = ((lo >> 4) & 15) ^ (r & 7);
        gload_lds16(K + (size_t)(kt*32 + r)*128 + gc*8, (u16*)((char*)Kl + ob));
      }
      {
        int d = lo >> 6;
        int gnb = ((lo >> 4) & 3) ^ ((d >> 1) & 3);
        gload_lds16(V + (size_t)d*2048 + kt*32 + gnb*8, (u16*)((char*)Vl + ob));
      }
    }
    __syncthreads();
    bf16x8 kb[8];
    #pragma unroll
    for(int ct = 0; ct < 2; ++ct)
      #pragma unroll
      for(int ks = 0; ks < 4; ++ks){
        int r = ct*16 + (lane & 15);
        int pc = (ks*4 + (lane >> 4)) ^ (r & 7);
        kb[ct*4+ks] = *(const bf16x8*)(Kl + r*128 + pc*8);
      }
    f32x4 s[2][2] = {};
    #pragma unroll
    for(int m = 0; m < 2; ++m)
      #pragma unroll
      for(int ct = 0; ct < 2; ++ct)
        #pragma unroll
        for(int ks = 0; ks < 4; ++ks)
          s[m][ct] = MFMA16(aq[m][ks], kb[ct*4+ks], s[m][ct]);
    bf16x8 bv[8];
    #pragma unroll
    for(int nt = 0; nt < 8; ++nt){
      int d = nt*16 + (lane & 15);
      int pnb = (lane >> 4) ^ ((d >> 1) & 3);
      bv[nt] = *(const bf16x8*)(Vl + d*32 + pnb*8);
    }
    #pragma unroll
    for(int m = 0; m < 2; ++m)
      #pragma unroll
      for(int ct = 0; ct < 2; ++ct)
        #pragma unroll
        for(int r = 0; r < 4; ++r){
          int col = kt*32 + ct*16 + (lane & 15);
          float p = (col <= qr0[m] + r) ? __expf(s[m][ct][r] * scale) : 0.f;
          lsum[m][r] += p;
          int row = m*16 + ((lane >> 4) << 2) + r;
          *(u16*)((char*)plw + row*80 + (ct*16 + (lane & 15))*2) = f2bf(p);
        }
    __builtin_amdgcn_s_setprio(1);
    #pragma unroll
    for(int m = 0; m < 2; ++m){
      bf16x8 ap = *(const bf16x8*)((const char*)plw + (m*16 + (lane & 15))*80 + ((lane >> 4) << 4));
      #pragma unroll
      for(int nt = 0; nt < 8; ++nt)
        acc[m][nt] = MFMA16(ap, bv[nt], acc[m][nt]);
    }
    __builtin_amdgcn_s_setprio(0);
  }
  #pragma unroll
  for(int m = 0; m < 2; ++m)
    #pragma unroll
    for(int r = 0; r < 4; ++r){
      float v = lsum[m][r];
      v += __shfl_xor(v, 1, 64); v += __shfl_xor(v, 2, 64);
      v += __shfl_xor(v, 4, 64); v += __shfl_xor(v, 8, 64);
      lsum[m][r] = v;
    }
  if(slot < 0){
    #pragma unroll
    for(int m = 0; m < 2; ++m)
      #pragma unroll
      for(int nt = 0; nt < 8; ++nt)
        #pragma unroll
        for(int r = 0; r < 4; ++r){
          int row = qB*128 + w*32 + m*16 + ((lane >> 4) << 2) + r;
          int d = nt*16 + (lane & 15);
          size_t o = (size_t)row*2048 + h*128 + d;
          float fin = omix[o] + 0.5f * acc[m][nt][r] / lsum[m][r];
          obf[o] = f2bf(fin);
        }
  } else {
    float* P = slotp(part1, part2, slot);
    #pragma unroll
    for(int m = 0; m < 2; ++m)
      #pragma unroll
      for(int nt = 0; nt < 8; ++nt)
        #pragma unroll
        for(int r = 0; r < 4; ++r){
          int row = w*32 + m*16 + ((lane >> 4) << 2) + r;
          int d = nt*16 + (lane & 15);
          P[(size_t)row*128 + d] = acc[m][nt][r];
        }
    if((lane & 15) == 0)
      #pragma unroll
      for(int m = 0; m < 2; ++m)
        #pragma unroll
        for(int r = 0; r < 4; ++r)
          P[16384 + w*32 + m*16 + ((lane >> 4) << 2) + r] = lsum[m][r];
  }
}

// ---------------- combine attention K-segments; writes final bf16 omix ----------------
__global__ __launch_bounds__(256) void k_acomb(const float* __restrict__ part1, const float* __restrict__ part2,
                                               const float* __restrict__ omix, u16* __restrict__ obf){
  int bid = blockIdx.x;             // h*12 + (qB-4)
  int h = bid / 12, qx = bid % 12, qB = 4 + qx;
  int nseg = (qB >= 12) ? 4 : (qB >= 8) ? 3 : 2;
  int off = (qB < 8) ? (qB-4)*2 : (qB < 12) ? 8 + (qB-8)*3 : 20 + (qB-12)*4;
  int s0 = h*36 + off;
  int tid = threadIdx.x;
  #pragma unroll
  for(int it = 0; it < 16; ++it){
    int i = it*1024 + tid*4;
    int row = i >> 7;
    f32x4 a = {};
    float l = 0.f;
    for(int s = 0; s < nseg; ++s){
      const float* P = slotpc(part1, part2, s0 + s);
      a += *(const f32x4*)(P + i);
      l += P[16384 + row];
    }
    size_t idx = (size_t)(qB*128 + row)*2048 + h*128 + (i & 127);
    f32x4 cur = *(const f32x4*)(omix + idx);
    f32x4 fin = cur + a * (0.5f / l);
    u32 w0 = (u32)f2bf(fin[0]) | ((u32)f2bf(fin[1]) << 16);
    u32 w1 = (u32)f2bf(fin[2]) | ((u32)f2bf(fin[3]) << 16);
    *(u32*)(obf + idx) = w0;
    *(u32*)(obf + idx + 2) = w1;
  }
}

// ---------------- launch ----------------
extern "C" void kernel_launch(void* const* d_in, const int* in_sizes, int n_in,
                              void* d_out, int out_size, void* d_ws, size_t ws_size,
                              hipStream_t stream){
  (void)in_sizes; (void)n_in; (void)out_size; (void)ws_size;
  const float* hs = (const float*)d_in[0];
  const float* Wq = (const float*)d_in[1];
  const float* Wk = (const float*)d_in[2];
  const float* Wv = (const float*)d_in[3];
  const float* Wo = (const float*)d_in[4];
  float* out = (float*)d_out;
  char* ws = (char*)d_ws;

  u16*   hs_bf   = (u16*)(ws + OF_HSBF);
  u16*   wqkv_bf = (u16*)(ws + OF_WQKVBF);
  u16*   wo_bf   = (u16*)(ws + OF_WOBF);
  float* qkv     = (float*)(ws + OF_QKV);
  u16*   qbf     = (u16*)(ws + OF_QBF);
  u16*   kbf     = (u16*)(ws + OF_KBF);
  u16*   vT      = (u16*)(ws + OF_VT);
  u16*   qlb     = (u16*)(ws + OF_QLB);
  float* klf     = (float*)(ws + OF_KLF);
  u16*   klb     = (u16*)(ws + OF_KLB);
  float* glf     = (float*)(ws + OF_GLF);
  float* tinvb   = (float*)(ws + OF_TINV);
  float* wf      = (float*)(ws + OF_WF);
  u16*   wb      = (u16*)(ws + OF_WB);
  float* u0f     = (float*)(ws + OF_U0);
  u16*   sjb     = (u16*)(ws + OF_SJ);
  float* omix    = (float*)(ws + OF_OMIX);
  u16*   obf     = (u16*)(ws + OF_OBF);
  float* aDF  = (float*)(ws + OF_ADF);
  u16*   aDH  = (u16*)(ws + OF_ADH);
  u16*   aDL  = (u16*)(ws + OF_ADL);
  u16*   aDTH = (u16*)(ws + OF_ADTH);
  u16*   aDTL = (u16*)(ws + OF_ADTL);
  float* aBTF = (float*)(ws + OF_ABTF);
  u16*   aBTH = (u16*)(ws + OF_ABTH);
  u16*   aBTL = (u16*)(ws + OF_ABTL);
  float* bDF  = (float*)(ws + OF_BDF);
  u16*   bDH  = (u16*)(ws + OF_BDH);
  u16*   bDL  = (u16*)(ws + OF_BDL);
  u16*   bDTH = (u16*)(ws + OF_BDTH);
  u16*   bDTL = (u16*)(ws + OF_BDTL);
  float* bBTF = (float*)(ws + OF_BBTF);
  u16*   bBTH = (u16*)(ws + OF_BBTH);
  u16*   bBTL = (u16*)(ws + OF_BBTL);
  float* ttF  = (float*)(ws + OF_TTF);
  u16*   ttH  = (u16*)(ws + OF_TTH);
  u16*   ttL  = (u16*)(ws + OF_TTL);
  float* pDF  = (float*)(ws + OF_PDF);
  float* pBTF = (float*)(ws + OF_PBTF);
  u16*   pDH  = (u16*)(ws + OF_PDH);
  u16*   pDL  = (u16*)(ws + OF_PDL);
  u16*   pDTH = (u16*)(ws + OF_PDTH);
  u16*   pDTL = (u16*)(ws + OF_PDTL);
  u16*   pBTH = (u16*)(ws + OF_PBTH);
  u16*   pBTL = (u16*)(ws + OF_PBTL);
  float* apart1 = (float*)(ws + OF_APART1);
  float* apart2 = (float*)(ws + OF_APART2);

  k_f2ball<<<14336, 256, 0, stream>>>(hs, Wq, Wk, Wv, Wo, hs_bf, wqkv_bf, wo_bf);
  k_gemm<<<dim3(24, 16), 256, 0, stream>>>(hs_bf, wqkv_bf, qkv, 2048, 3072);
  k_linvt<<<10496, 256, 0, stream>>>(qkv, qbf, qlb, kbf, klf, klb, glf, vT);

  k_prep1<<<128, 256, 0, stream>>>(klf, glf, tinvb);
  k_prep2a<<<256, 256, 0, stream>>>(klf, glf, qkv, tinvb, wf, wb, u0f);
  k_prep2b<<<256, 256, 0, stream>>>(klf, wf, u0f, aDF, aDH, aDL, aDTH, aDTL, aBTF, aBTH, aBTL);

  k_ks<<<dim3(32, 4, 2), 256, 0, stream>>>(aDF, aDH, aDL, aDTH, aDTL, aBTF, aBTH, aBTL,
                                           bDF, bDH, bDL, bDTH, bDTL, bBTF, bBTH, bBTL, 1);
  k_ks<<<dim3(32, 4, 2), 256, 0, stream>>>(bDF, bDH, bDL, bDTH, bDTL, bBTF, bBTH, bBTL,
                                           aDF, aDH, aDL, aDTH, aDTL, aBTF, aBTH, aBTL, 2);
  k_ks<<<dim3(32, 4, 2), 256, 0, stream>>>(aDF, aDH, aDL, aDTH, aDTL, aBTF, aBTH, aBTL,
                                           bDF, bDH, bDL, bDTH, bDTL, bBTF, bBTH, bBTL, 4);
  k_ks<<<dim3(32, 4, 2), 256, 0, stream>>>(bDF, bDH, bDL, bDTH, bDTL, bBTF, bBTH, bBTL,
                                           aDF, aDH, aDL, aDTH, aDTL, aBTF, aBTH, aBTL, 8);
  k_ks<<<dim3(32, 4, 2), 256, 0, stream>>>(aDF, aDH, aDL, aDTH, aDTL, aBTF, aBTH, aBTL,
                                           bDF, bDH, bDL, bDTH, bDTL, bBTF, bBTH, bBTL, 16);

  CompJobs j1{}; // Phi_g^2
  for(int g = 0; g < 4; ++g){ j1.a[g] = g*32+31; j1.b[g] = g*32+31; j1.d[g] = 128+g; }
  k_comp<<<dim3(4, 2), 256, 0, stream>>>(bDF, bDH, bDL, bDTH, bDTL, bBTF, bBTH, bBTL,
                                         pDF, pDH, pDL, pDTH, pDTL, pBTF, pBTH, pBTL, j1);
  CompJobs j2{}; // Phi^3, Phi^4
  for(int g = 0; g < 4; ++g){
    j2.a[g]   = 128+g; j2.b[g]   = g*32+31; j2.d[g]   = 132+g;
    j2.a[4+g] = 128+g; j2.b[4+g] = 128+g;   j2.d[4+g] = 136+g;
  }
  k_comp<<<dim3(8, 2), 256, 0, stream>>>(bDF, bDH, bDL, bDTH, bDTL, bBTF, bBTH, bBTL,
                                         pDF, pDH, pDL, pDTH, pDTL, pBTF, pBTH, pBTL, j2);
  CompJobs j3{}; // Psi2; T
  j3.a[0] = 137; j3.b[0] = 136; j3.d[0] = 140;
  j3.a[1] = 138; j3.b[1] = 137; j3.d[1] = 141;
  k_comp<<<dim3(2, 2), 256, 0, stream>>>(bDF, bDH, bDL, bDTH, bDTL, bBTF, bBTH, bBTL,
                                         pDF, pDH, pDL, pDTH, pDTL, pBTF, pBTH, pBTL, j3);
  CompJobs j4{}; // Psi3
  j4.a[0] = 141; j4.b[0] = 136; j4.d[0] = 142;
  k_comp<<<dim3(1, 2), 256, 0, stream>>>(bDF, bDH, bDL, bDTH, bDTL, bBTF, bBTH, bBTL,
                                         pDF, pDH, pDL, pDTH, pDTL, pBTF, pBTH, pBTL, j4);

  k_heads<<<16, 256, 0, stream>>>(bDH, bDL, bBTF, bBTH, bBTL,
                                  pDH, pDL, pBTF, pBTH, pBTL, ttF, ttH, ttL, sjb);
  k_expand<<<512, 256, 0, stream>>>(bDH, bDL, bBTF, ttF, ttH, ttL, sjb);

  k_olin<<<512, 256, 0, stream>>>(qlb, klb, wb, u0f, sjb, omix);
  k_attn<<<640, 256, 0, stream>>>(qbf, kbf, vT, omix, obf, apart1, apart2);
  k_acomb<<<192, 256, 0, stream>>>(apart1, apart2, omix, obf);

  k_gemm<<<dim3(16, 16), 256, 0, stream>>>(obf, wo_bf, out, 2048, 2048);
}

// Round 13
// 601.814 us; speedup vs baseline: 1.5155x; 1.0260x over previous
//
#include <hip/hip_runtime.h>
#include <hip/hip_bf16.h>

typedef unsigned short u16;
typedef unsigned int u32;
typedef __bf16 bf16x8 __attribute__((ext_vector_type(8)));
typedef float f32x4 __attribute__((ext_vector_type(4)));

#define MFMA16(a,b,c) __builtin_amdgcn_mfma_f32_16x16x32_bf16((a),(b),(c),0,0,0)

__device__ __forceinline__ u16 f2bf(float f){
  u32 u = __builtin_bit_cast(u32, f);
  u32 r = (u + 0x7fffu + ((u >> 16) & 1u)) >> 16;
  return (u16)r;
}
__device__ __forceinline__ float bf2f(u16 h){
  u32 u = ((u32)h) << 16;
  return __builtin_bit_cast(float, u);
}
__device__ __forceinline__ void splitbf(float x, u16& hi, u16& lo){
  hi = f2bf(x);
  lo = f2bf(x - bf2f(hi));
}
__device__ __forceinline__ void gload_lds16(const u16* g, u16* l){
  __builtin_amdgcn_global_load_lds((__attribute__((address_space(1))) void*)(g),
                                   (__attribute__((address_space(3))) void*)(l), 16, 0, 0);
}
__device__ __forceinline__ const u16* selu(const u16* barr, const u16* parr, int i){
  return (i < 128) ? (barr + (size_t)i*16384) : (parr + (size_t)(i-128)*16384);
}
__device__ __forceinline__ const float* self32(const float* barr, const float* parr, int i){
  return (i < 128) ? (barr + (size_t)i*16384) : (parr + (size_t)(i-128)*16384);
}
// attention partial slots: 16512 f32 each (128x128 acc + 128 lsum)
__device__ __forceinline__ float* slotp(float* p1, float* p2, int s){
  return (s < 381) ? (p1 + (size_t)s*16512) : (p2 + (size_t)(s-381)*16512);
}
__device__ __forceinline__ const float* slotpc(const float* p1, const float* p2, int s){
  return (s < 381) ? (p1 + (size_t)s*16512) : (p2 + (size_t)(s-381)*16512);
}
// chunk-XOR swizzled [128][132] f32 tile addressing (16B chunks; colc = col>>2)
__device__ __forceinline__ float* tdq(float* Td, int row, int colc){
  return Td + row*132 + ((colc ^ ((row >> 3) & 7)) << 2);
}

// ---------------- workspace layout (bytes) ----------------
constexpr size_t OF_HSBF   = 0;
constexpr size_t OF_WQKVBF = 8388608;
constexpr size_t OF_WOBF   = 20971520;
constexpr size_t OF_QKV    = 29360128;
constexpr size_t OF_QBF    = 54525952;
constexpr size_t OF_KBF    = 62914560;
constexpr size_t OF_VT     = 65011712;
constexpr size_t OF_QLB    = 67108864;
constexpr size_t OF_KLF    = 75497472;
constexpr size_t OF_KLB    = 79691776;
constexpr size_t OF_GLF    = 81788928;
constexpr size_t OF_TINV   = 85983232;
constexpr size_t OF_WF     = 88080384;
constexpr size_t OF_WB     = 92274688;
constexpr size_t OF_U0     = 94371840;
constexpr size_t OF_SJ     = 111149056;
constexpr size_t OF_OMIX   = 127926272;
constexpr size_t OF_OMIXB  = 144703488;
constexpr size_t OF_ADF  = 102760448;
constexpr size_t OF_ABTF = OF_OMIX;
constexpr size_t OF_ADH  = OF_OMIX + 8388608;
constexpr size_t OF_ADL  = OF_OMIX + 12582912;
constexpr size_t OF_ADTH = OF_OMIXB;
constexpr size_t OF_ADTL = OF_OMIXB + 4194304;
constexpr size_t OF_ABTH = OF_KLF;
constexpr size_t OF_ABTL = OF_GLF;
constexpr size_t OF_BDF  = OF_QKV;
constexpr size_t OF_BBTF = OF_QKV + 8388608;
constexpr size_t OF_BDH  = OF_QKV + 16777216;
constexpr size_t OF_BDL  = OF_QKV + 20971520;
constexpr size_t OF_BDTH = OF_HSBF;
constexpr size_t OF_BDTL = OF_HSBF + 4194304;
constexpr size_t OF_BBTH = OF_WQKVBF;
constexpr size_t OF_BBTL = OF_WQKVBF + 4194304;
constexpr size_t OF_TTF  = OF_TINV;
constexpr size_t OF_TTH  = OF_WQKVBF + 8388608;
constexpr size_t OF_TTL  = OF_WQKVBF + 8912896;
constexpr size_t OF_PDF  = OF_ADF;
constexpr size_t OF_PBTF = OF_ADF + 1048576;
constexpr size_t OF_PDH  = OF_ADF + 2097152;
constexpr size_t OF_PDL  = OF_ADF + 2621440;
constexpr size_t OF_PDTH = OF_ADF + 3145728;
constexpr size_t OF_PDTL = OF_ADF + 3670016;
constexpr size_t OF_PBTH = OF_ADF + 4194304;
constexpr size_t OF_PBTL = OF_ADF + 4718592;
constexpr size_t OF_APART1 = OF_QKV;
constexpr size_t OF_APART2 = OF_OMIXB;
constexpr size_t OF_OBF = 0;
// split-K overlays:
constexpr size_t OF_QKVB  = OF_SJ;               // qkv half-1 (25.2MB; SJ region dead until k_heads)
constexpr size_t OF_OUTH0 = OF_QKV;              // gemm2 partial 0 (16.7MB; apart1 dead after acomb)
constexpr size_t OF_OUTH1 = OF_QKV + 16777216;   // gemm2 partial 1 (ends 62914560; qbf dead after attn)

struct CompJobs { int a[8]; int b[8]; int d[8]; };

// ---------------- fused f2b of all 5 inputs ----------------
__global__ void k_f2ball(const float* __restrict__ hs, const float* __restrict__ Wq,
                         const float* __restrict__ Wk, const float* __restrict__ Wv,
                         const float* __restrict__ Wo, u16* __restrict__ hs_bf,
                         u16* __restrict__ wqkv_bf, u16* __restrict__ wo_bf){
  int bid = blockIdx.x;
  const float* src; u16* dst; int off;
  if(bid < 4096){ src = hs; dst = hs_bf; off = bid; }
  else if(bid < 8192){ src = Wq; dst = wqkv_bf; off = bid - 4096; }
  else if(bid < 9216){ src = Wk; dst = wqkv_bf + 2048*2048; off = bid - 8192; }
  else if(bid < 10240){ src = Wv; dst = wqkv_bf + 2560*2048; off = bid - 9216; }
  else { src = Wo; dst = wo_bf; off = bid - 10240; }
  int i = (off*256 + threadIdx.x) * 4;
  f32x4 v = *(const f32x4*)(src + i);
  u32 w0 = (u32)f2bf(v[0]) | ((u32)f2bf(v[1]) << 16);
  u32 w1 = (u32)f2bf(v[2]) | ((u32)f2bf(v[3]) << 16);
  *(u32*)(dst + i) = w0;
  *(u32*)(dst + i + 2) = w1;
}

// ---------------- bf16 NT GEMM, split-K over blockIdx.z, XCD-chunked swizzle ----------------
__global__ __launch_bounds__(256) void k_gemm(const u16* __restrict__ A, const u16* __restrict__ B,
                                              float* __restrict__ C0, float* __restrict__ C1,
                                              int K, int N){
  __shared__ u16 aL[128*32];
  __shared__ u16 bL[128*32];
  int nxy = gridDim.x * gridDim.y;
  int nwg = nxy * gridDim.z;
  int lin = (blockIdx.z * gridDim.y + blockIdx.y) * gridDim.x + blockIdx.x;
  int s = (lin & 7) * (nwg >> 3) + (lin >> 3);
  int z = s / nxy; int rem = s - z * nxy;
  int bn = rem % gridDim.x, bm = rem / gridDim.x;
  float* C = (z == 0) ? C0 : C1;
  int kspan = K / gridDim.z;
  int k0 = z * kspan;
  int tid = threadIdx.x, lane = tid & 63, w = tid >> 6;
  int wm = w >> 1, wn = w & 1;
  f32x4 acc[4][4] = {};
  int nK = kspan >> 5;
  const u16* Abase = A + (size_t)bm * 128 * K + k0;
  const u16* Bbase = B + (size_t)bn * 128 * K + k0;
  for(int kt = 0; kt < nK; ++kt){
    __syncthreads();
    #pragma unroll
    for(int t = 0; t < 2; ++t){
      int row = t*64 + w*16 + (lane >> 2);
      int kc = (lane & 3) * 8;
      gload_lds16(Abase + (size_t)row*K + kt*32 + kc, &aL[(t*64 + w*16)*32]);
      gload_lds16(Bbase + (size_t)row*K + kt*32 + kc, &bL[(t*64 + w*16)*32]);
    }
    __syncthreads();
    bf16x8 af[4], bf[4];
    #pragma unroll
    for(int i = 0; i < 4; ++i){
      af[i] = *(const bf16x8*)&aL[(wm*64 + i*16 + (lane & 15))*32 + ((lane >> 4) << 3)];
      bf[i] = *(const bf16x8*)&bL[(wn*64 + i*16 + (lane & 15))*32 + ((lane >> 4) << 3)];
    }
    #pragma unroll
    for(int i = 0; i < 4; ++i)
      #pragma unroll
      for(int j = 0; j < 4; ++j)
        acc[i][j] = MFMA16(af[i], bf[j], acc[i][j]);
  }
  #pragma unroll
  for(int i = 0; i < 4; ++i)
    #pragma unroll
    for(int j = 0; j < 4; ++j)
      #pragma unroll
      for(int r = 0; r < 4; ++r){
        int row = bm*128 + wm*64 + i*16 + ((lane >> 4) << 2) + r;
        int col = bn*128 + wn*64 + j*16 + (lane & 15);
        C[(size_t)row * N + col] = acc[i][j][r];
      }
}

// ---------------- combine gemm2 split-K partials: out = h0 + h1 ----------------
__global__ void k_ocomb(const float* __restrict__ h0, const float* __restrict__ h1,
                        float* __restrict__ out){
  int i = (blockIdx.x * 256 + threadIdx.x) * 4;
  f32x4 a = *(const f32x4*)(h0 + i);
  f32x4 b = *(const f32x4*)(h1 + i);
  *(f32x4*)(out + i) = a + b;
}

// ---------------- fused linprep + V-transpose (sums split-K halves; writes combined V back) ----------------
__global__ __launch_bounds__(256) void k_linvt(float* __restrict__ qkv, const float* __restrict__ qkvB,
                                               u16* qbf, u16* qlb,
                                               u16* kbf, float* klf, u16* klb, float* glf,
                                               u16* __restrict__ vT){
  __shared__ float t[64][65];
  int bid = blockIdx.x;
  if(bid < 10240){
    int gtask = bid * 4 + (threadIdx.x >> 6);
    int lane = threadIdx.x & 63;
    int n = gtask / 20, tt = gtask % 20;
    size_t ro = (tt < 16) ? ((size_t)n*3072 + tt*128)
                          : ((size_t)n*3072 + 2048 + (tt-16)*128);
    const float* rowA = qkv + ro;
    const float* rowB = qkvB + ro;
    float v0 = rowA[lane] + rowB[lane];
    float v1 = rowA[lane + 64] + rowB[lane + 64];
    float m = fmaxf(v0, v1);
    #pragma unroll
    for(int o = 1; o < 64; o <<= 1) m = fmaxf(m, __shfl_xor(m, o, 64));
    float e0 = __expf(v0 - m), e1 = __expf(v1 - m);
    float s = e0 + e1;
    #pragma unroll
    for(int o = 1; o < 64; o <<= 1) s += __shfl_xor(s, o, 64);
    float r0 = e0 / s, r1 = e1 / s;
    if(tt < 16){
      size_t base = ((size_t)tt*2048 + n) * 128;
      qbf[base + lane] = f2bf(v0); qbf[base + 64 + lane] = f2bf(v1);
      qlb[base + lane] = f2bf(r0); qlb[base + 64 + lane] = f2bf(r1);
    } else {
      int g = tt - 16;
      size_t base = ((size_t)g*2048 + n) * 128;
      kbf[base + lane] = f2bf(v0); kbf[base + 64 + lane] = f2bf(v1);
      klf[base + lane] = r0;       klf[base + 64 + lane] = r1;
      klb[base + lane] = f2bf(r0); klb[base + 64 + lane] = f2bf(r1);
      float g0 = (fminf(v0, 0.f) - log1pf(__expf(-fabsf(v0)))) * (1.f/16.f);
      float g1 = (fminf(v1, 0.f) - log1pf(__expf(-fabsf(v1)))) * (1.f/16.f);
      glf[base + lane] = g0; glf[base + 64 + lane] = g1;
    }
  } else {
    int v = bid - 10240;
    int nt = v & 31, dt = (v >> 5) & 1, g = v >> 6;
    int tid = threadIdx.x;
    {
      int r = tid >> 2, c0 = (tid & 3) * 16;
      size_t so = (size_t)(nt*64 + r)*3072 + 2560 + g*128 + dt*64 + c0;
      float* srcA = qkv + so;
      const float* srcB = qkvB + so;
      #pragma unroll
      for(int q = 0; q < 16; q += 4){
        f32x4 vv = *(const f32x4*)(srcA + q) + *(const f32x4*)(srcB + q);
        *(f32x4*)(srcA + q) = vv;   // write combined V back for prep2a
        t[r][c0+q] = vv[0]; t[r][c0+q+1] = vv[1]; t[r][c0+q+2] = vv[2]; t[r][c0+q+3] = vv[3];
      }
    }
    __syncthreads();
    {
      int d = tid >> 2, c0 = (tid & 3) * 16;
      u16* dst = vT + ((size_t)g*128 + dt*64 + d)*2048 + (size_t)nt*64 + c0;
      #pragma unroll
      for(int half = 0; half < 2; ++half){
        int b = c0 + half*8;
        u32 w0 = (u32)f2bf(t[b+0][d]) | ((u32)f2bf(t[b+1][d]) << 16);
        u32 w1 = (u32)f2bf(t[b+2][d]) | ((u32)f2bf(t[b+3][d]) << 16);
        u32 w2 = (u32)f2bf(t[b+4][d]) | ((u32)f2bf(t[b+5][d]) << 16);
        u32 w3 = (u32)f2bf(t[b+6][d]) | ((u32)f2bf(t[b+7][d]) << 16);
        *(uint4*)(dst + half*8) = make_uint4(w0, w1, w2, w3);
      }
    }
  }
}

// ---------------- prep1 ----------------
__global__ __launch_bounds__(256) void k_prep1(const float* __restrict__ klf, const float* __restrict__ glf,
                                               float* __restrict__ tinv){
  __shared__ float KlT[128][68];
  __shared__ float Kb[64][132];
  __shared__ float Am[64][68];
  __shared__ float XT[64][68];
  int idx = blockIdx.x, g = idx >> 5, c = idx & 31, tid = threadIdx.x;
  size_t base = ((size_t)g*2048 + c*64) * 128;
  {
    int r = tid >> 2, d0 = (tid & 3) * 32;
    #pragma unroll
    for(int dd = 0; dd < 32; dd += 4){
      f32x4 kv = *(const f32x4*)(klf + base + r*128 + d0 + dd);
      f32x4 gv = *(const f32x4*)(glf + base + r*128 + d0 + dd);
      KlT[d0+dd][r] = kv[0]; KlT[d0+dd+1][r] = kv[1]; KlT[d0+dd+2][r] = kv[2]; KlT[d0+dd+3][r] = kv[3];
      f32x4 kb = kv * gv;
      *(f32x4*)&Kb[r][d0+dd] = kb;
    }
  }
  __syncthreads();
  {
    int i = tid >> 2, j0 = (tid & 3) * 16;
    f32x4 s[4] = {};
    for(int d = 0; d < 128; ++d){
      float kb = Kb[i][d];
      #pragma unroll
      for(int q = 0; q < 4; ++q){
        f32x4 kl = *(const f32x4*)&KlT[d][j0 + q*4];
        s[q] += kb * kl;
      }
    }
    #pragma unroll
    for(int q = 0; q < 4; ++q) *(f32x4*)&Am[i][j0 + q*4] = s[q];
  }
  __syncthreads();
  if(tid < 64){
    int cc = tid;
    float x0 = (cc == 0) ? 1.f : 0.f;
    XT[cc][0] = x0;
    tinv[(size_t)idx*4096 + cc] = x0;
    for(int i = 1; i < 64; ++i){
      float s = (i == cc) ? 1.f : 0.f;
      int i4 = i & ~3;
      for(int jj = 0; jj < i4; jj += 4){
        f32x4 av = *(const f32x4*)&Am[i][jj];
        f32x4 xv = *(const f32x4*)&XT[cc][jj];
        s -= av[0]*xv[0] + av[1]*xv[1] + av[2]*xv[2] + av[3]*xv[3];
      }
      for(int jj = i4; jj < i; ++jj) s -= Am[i][jj] * XT[cc][jj];
      XT[cc][i] = s;
      tinv[(size_t)idx*4096 + i*64 + cc] = s;
    }
  }
}

// ---------------- prep2a (split by z: z=0 -> w/wb, z=1 -> u0); coalesced writeback ----------------
__global__ __launch_bounds__(256) void k_prep2a(const float* __restrict__ klf, const float* __restrict__ glf,
                                                const float* __restrict__ qkv, const float* __restrict__ tinv,
                                                float* __restrict__ wf, u16* __restrict__ wb, float* __restrict__ u0f){
  __shared__ char smem[51200];
  float (*Ti)[68] = (float(*)[68])smem;               // 17408
  float (*B)[132] = (float(*)[132])(smem + 17408);    // 33792 (ends 51200)
  int bid = blockIdx.x, idx = bid >> 1, z = bid & 1;
  int g = idx >> 5, c = idx & 31, tid = threadIdx.x;
  size_t base = ((size_t)g*2048 + c*64) * 128;
  {
    int r = tid >> 2, d0 = (tid & 3) * 32;
    #pragma unroll
    for(int dd = 0; dd < 32; dd += 4){
      f32x4 gv = *(const f32x4*)(glf + base + r*128 + d0 + dd);
      f32x4 xv;
      if(z == 0) xv = *(const f32x4*)(klf + base + r*128 + d0 + dd);
      else       xv = *(const f32x4*)(qkv + (size_t)(c*64 + r)*3072 + 2560 + g*128 + d0 + dd);
      *(f32x4*)&B[r][d0+dd] = xv * gv;
    }
    int c0 = (tid & 3) * 16;
    #pragma unroll
    for(int q = 0; q < 16; q += 4)
      *(f32x4*)&Ti[r][c0+q] = *(const f32x4*)(tinv + (size_t)idx*4096 + r*64 + c0 + q);
  }
  __syncthreads();
  int i = tid >> 2, cc0 = (tid & 3) * 32;
  f32x4 wa[8] = {};
  for(int jj = 0; jj < 64; ++jj){
    float a = Ti[i][jj];
    #pragma unroll
    for(int q = 0; q < 8; ++q)
      wa[q] += a * *(const f32x4*)&B[jj][cc0 + q*4];
  }
  __syncthreads();
  float (*Tw)[132] = (float(*)[132])smem;
  #pragma unroll
  for(int q = 0; q < 8; ++q)
    *(f32x4*)&Tw[i][cc0 + q*4] = wa[q];
  __syncthreads();
  size_t ob = (size_t)idx * 8192;
  #pragma unroll
  for(int c2 = 0; c2 < 8; ++c2){
    int ii = c2*1024 + tid*4;
    int row = ii >> 7, col = ii & 127;
    f32x4 wv = *(const f32x4*)&Tw[row][col];
    if(z == 0){
      *(f32x4*)(wf + ob + ii) = wv;
      u32 p0 = (u32)f2bf(wv[0]) | ((u32)f2bf(wv[1]) << 16);
      u32 p1 = (u32)f2bf(wv[2]) | ((u32)f2bf(wv[3]) << 16);
      *(u32*)(wb + ob + ii) = p0;
      *(u32*)(wb + ob + ii + 2) = p1;
    } else {
      *(f32x4*)(u0f + ob + ii) = wv;
    }
  }
}

// ---------------- prep2b (split by z: z=0 -> D (+transpose), z=1 -> BT); swizzled restage ----------------
__global__ __launch_bounds__(256) void k_prep2b(const float* __restrict__ klf, const float* __restrict__ wf,
                                                const float* __restrict__ u0f,
                                                float* __restrict__ dF, u16* __restrict__ dH, u16* __restrict__ dL,
                                                u16* __restrict__ dTH, u16* __restrict__ dTL,
                                                float* __restrict__ btF, u16* __restrict__ btH, u16* __restrict__ btL){
  __shared__ char smem[67584];
  float (*Kl)[132] = (float(*)[132])smem;
  float (*Wm)[132] = (float(*)[132])(smem + 33792);
  int bid = blockIdx.x, idx = bid >> 1, z = bid & 1;
  int g = idx >> 5, c = idx & 31, tid = threadIdx.x;
  size_t base = ((size_t)g*2048 + c*64) * 128;
  {
    int r = tid >> 2, d0 = (tid & 3) * 32;
    const float* src = (z == 0) ? wf : u0f;
    #pragma unroll
    for(int dd = 0; dd < 32; dd += 4){
      *(f32x4*)&Kl[r][d0+dd] = *(const f32x4*)(klf + base + r*128 + d0 + dd);
      *(f32x4*)&Wm[r][d0+dd] = *(const f32x4*)(src + (size_t)idx*8192 + r*128 + d0 + dd);
    }
  }
  __syncthreads();
  int a = tid >> 1, b0 = (tid & 1) * 64;
  f32x4 pa[16] = {};
  if(z == 0){
    for(int r = 0; r < 64; ++r){
      float ka = Kl[r][a];
      #pragma unroll
      for(int q = 0; q < 16; ++q)
        pa[q] += ka * *(const f32x4*)&Wm[r][b0 + q*4];
    }
    #pragma unroll
    for(int q = 0; q < 16; ++q) pa[q] = -pa[q];
  } else {
    for(int r = 0; r < 64; ++r){
      float ua = Wm[r][a];
      #pragma unroll
      for(int q = 0; q < 16; ++q)
        pa[q] += ua * *(const f32x4*)&Kl[r][b0 + q*4];
    }
  }
  __syncthreads();
  float* Td = (float*)smem;
  #pragma unroll
  for(int q = 0; q < 16; ++q)
    *(f32x4*)tdq(Td, a, (b0 >> 2) + q) = pa[q];
  __syncthreads();
  size_t ob = (size_t)idx * 16384;
  if(z == 0){
    #pragma unroll
    for(int c2 = 0; c2 < 16; ++c2){
      int ii = c2*1024 + tid*4;
      int row = ii >> 7, col = ii & 127;
      f32x4 dv = *(const f32x4*)tdq(Td, row, col >> 2);
      *(f32x4*)(dF + ob + ii) = dv;
      u16 h0,l0,h1,l1,h2,l2,h3,l3;
      splitbf(dv[0], h0, l0); splitbf(dv[1], h1, l1);
      splitbf(dv[2], h2, l2); splitbf(dv[3], h3, l3);
      *(u32*)(dH + ob + ii)     = (u32)h0 | ((u32)h1 << 16);
      *(u32*)(dH + ob + ii + 2) = (u32)h2 | ((u32)h3 << 16);
      *(u32*)(dL + ob + ii)     = (u32)l0 | ((u32)l1 << 16);
      *(u32*)(dL + ob + ii + 2) = (u32)l2 | ((u32)l3 << 16);
    }
    #pragma unroll
    for(int c2 = 0; c2 < 8; ++c2){
      int o0 = c2*2048 + tid*8;
      int b = o0 >> 7, a0 = o0 & 127;
      u16 th[8], tl[8];
      #pragma unroll
      for(int e = 0; e < 8; ++e){
        float v = *((const float*)tdq(Td, a0 + e, b >> 2) + (b & 3));
        splitbf(v, th[e], tl[e]);
      }
      uint4 ph = make_uint4((u32)th[0] | ((u32)th[1] << 16), (u32)th[2] | ((u32)th[3] << 16),
                            (u32)th[4] | ((u32)th[5] << 16), (u32)th[6] | ((u32)th[7] << 16));
      uint4 plv = make_uint4((u32)tl[0] | ((u32)tl[1] << 16), (u32)tl[2] | ((u32)tl[3] << 16),
                             (u32)tl[4] | ((u32)tl[5] << 16), (u32)tl[6] | ((u32)tl[7] << 16));
      *(uint4*)(dTH + ob + o0) = ph;
      *(uint4*)(dTL + ob + o0) = plv;
    }
  } else {
    #pragma unroll
    for(int c2 = 0; c2 < 16; ++c2){
      int ii = c2*1024 + tid*4;
      int row = ii >> 7, col = ii & 127;
      f32x4 cv = *(const f32x4*)tdq(Td, row, col >> 2);
      *(f32x4*)(btF + ob + ii) = cv;
      u16 h0,l0,h1,l1,h2,l2,h3,l3;
      splitbf(cv[0], h0, l0); splitbf(cv[1], h1, l1);
      splitbf(cv[2], h2, l2); splitbf(cv[3], h3, l3);
      *(u32*)(btH + ob + ii)     = (u32)h0 | ((u32)h1 << 16);
      *(u32*)(btH + ob + ii + 2) = (u32)h2 | ((u32)h3 << 16);
      *(u32*)(btL + ob + ii)     = (u32)l0 | ((u32)l1 << 16);
      *(u32*)(btL + ob + ii + 2) = (u32)l2 | ((u32)l3 << 16);
    }
  }
}

// ---------------- Kogge-Stone compose round (split-precision) ----------------
__global__ __launch_bounds__(256) void k_ks(
    const float* __restrict__ sDF, const u16* __restrict__ sDH, const u16* __restrict__ sDL,
    const u16* __restrict__ sDTH, const u16* __restrict__ sDTL,
    const float* __restrict__ sBF, const u16* __restrict__ sBH, const u16* __restrict__ sBL,
    float* __restrict__ dDF, u16* __restrict__ dDH, u16* __restrict__ dDL,
    u16* __restrict__ dDTH, u16* __restrict__ dDTL,
    float* __restrict__ dBF, u16* __restrict__ dBH, u16* __restrict__ dBL, int off){
  __shared__ float T[128][132];
  int c = blockIdx.x, g = blockIdx.y, z = blockIdx.z;
  int idx = g*32 + c, tid = threadIdx.x;
  size_t base = (size_t)idx * 16384;
  if(c < off){
    if(z == 0){
      for(int i = tid; i < 4096; i += 256) ((uint4*)(dDF + base))[i] = ((const uint4*)(sDF + base))[i];
      for(int i = tid; i < 2048; i += 256){
        ((uint4*)(dDH + base))[i] = ((const uint4*)(sDH + base))[i];
        ((uint4*)(dDL + base))[i] = ((const uint4*)(sDL + base))[i];
        ((uint4*)(dDTH + base))[i] = ((const uint4*)(sDTH + base))[i];
        ((uint4*)(dDTL + base))[i] = ((const uint4*)(sDTL + base))[i];
      }
    } else {
      for(int i = tid; i < 4096; i += 256) ((uint4*)(dBF + base))[i] = ((const uint4*)(sBF + base))[i];
      for(int i = tid; i < 2048; i += 256){
        ((uint4*)(dBH + base))[i] = ((const uint4*)(sBH + base))[i];
        ((uint4*)(dBL + base))[i] = ((const uint4*)(sBL + base))[i];
      }
    }
    return;
  }
  size_t blo = (size_t)(idx - off) * 16384;
  int lane = tid & 63, w = tid >> 6;
  const u16 *Ah, *Al, *Bh, *Bl;
  if(z == 0){ Ah = sDH + base; Al = sDL + base; Bh = sDTH + blo; Bl = sDTL + blo; }
  else      { Ah = sBH + blo;  Al = sBL + blo;  Bh = sDH + base; Bl = sDL + base; }
  f32x4 acc[2][8] = {};
  #pragma unroll
  for(int ks = 0; ks < 4; ++ks){
    bf16x8 ah[2], al[2], bh[8], bl[8];
    #pragma unroll
    for(int mt = 0; mt < 2; ++mt){
      int ro = (w*32 + mt*16 + (lane & 15))*128 + ks*32 + ((lane >> 4) << 3);
      ah[mt] = *(const bf16x8*)(Ah + ro);
      al[mt] = *(const bf16x8*)(Al + ro);
    }
    #pragma unroll
    for(int nt = 0; nt < 8; ++nt){
      int ro = (nt*16 + (lane & 15))*128 + ks*32 + ((lane >> 4) << 3);
      bh[nt] = *(const bf16x8*)(Bh + ro);
      bl[nt] = *(const bf16x8*)(Bl + ro);
    }
    #pragma unroll
    for(int mt = 0; mt < 2; ++mt)
      #pragma unroll
      for(int nt = 0; nt < 8; ++nt)
        acc[mt][nt] = MFMA16(ah[mt], bh[nt],
                      MFMA16(ah[mt], bl[nt],
                      MFMA16(al[mt], bh[nt], acc[mt][nt])));
  }
  if(z == 0){
    #pragma unroll
    for(int mt = 0; mt < 2; ++mt)
      #pragma unroll
      for(int nt = 0; nt < 8; ++nt)
        #pragma unroll
        for(int r = 0; r < 4; ++r){
          int row = w*32 + mt*16 + ((lane >> 4) << 2) + r;
          int col = nt*16 + (lane & 15);
          float v = acc[mt][nt][r] + sDF[base + row*128 + col] + sDF[blo + row*128 + col];
          dDF[base + row*128 + col] = v;
          u16 hi, lo; splitbf(v, hi, lo);
          dDH[base + row*128 + col] = hi;
          dDL[base + row*128 + col] = lo;
          T[row][col] = v;
        }
    __syncthreads();
    int tcol = tid >> 1, half = tid & 1;
    for(int m = 0; m < 64; ++m){
      float v = T[half*64 + m][tcol];
      u16 hi, lo; splitbf(v, hi, lo);
      dDTH[base + (size_t)tcol*128 + half*64 + m] = hi;
      dDTL[base + (size_t)tcol*128 + half*64 + m] = lo;
    }
  } else {
    #pragma unroll
    for(int mt = 0; mt < 2; ++mt)
      #pragma unroll
      for(int nt = 0; nt < 8; ++nt)
        #pragma unroll
        for(int r = 0; r < 4; ++r){
          int row = w*32 + mt*16 + ((lane >> 4) << 2) + r;
          int col = nt*16 + (lane & 15);
          float v = acc[mt][nt][r] + sBF[base + row*128 + col] + sBF[blo + row*128 + col];
          dBF[base + row*128 + col] = v;
          u16 hi, lo; splitbf(v, hi, lo);
          dBH[base + row*128 + col] = hi;
          dBL[base + row*128 + col] = lo;
        }
  }
}

// ---------------- hi/lo MFMA helper for 128x128 compose ----------------
__device__ __forceinline__ void comp_mfma(const u16* Ah, const u16* Al, const u16* Bh, const u16* Bl,
                                          f32x4 (&acc)[2][8], int lane, int w){
  #pragma unroll
  for(int ks = 0; ks < 4; ++ks){
    bf16x8 ah[2], al[2], bh[8], bl[8];
    #pragma unroll
    for(int mt = 0; mt < 2; ++mt){
      int ro = (w*32 + mt*16 + (lane & 15))*128 + ks*32 + ((lane >> 4) << 3);
      ah[mt] = *(const bf16x8*)(Ah + ro);
      al[mt] = *(const bf16x8*)(Al + ro);
    }
    #pragma unroll
    for(int nt = 0; nt < 8; ++nt){
      int ro = (nt*16 + (lane & 15))*128 + ks*32 + ((lane >> 4) << 3);
      bh[nt] = *(const bf16x8*)(Bh + ro);
      bl[nt] = *(const bf16x8*)(Bl + ro);
    }
    #pragma unroll
    for(int mt = 0; mt < 2; ++mt)
      #pragma unroll
      for(int nt = 0; nt < 8; ++nt)
        acc[mt][nt] = MFMA16(ah[mt], bh[nt],
                      MFMA16(ah[mt], bl[nt],
                      MFMA16(al[mt], bh[nt], acc[mt][nt])));
  }
}

// ---------------- generic compose with LDS-staged F-sums ----------------
__global__ __launch_bounds__(256) void k_comp(
    const float* __restrict__ bDF, const u16* __restrict__ bDH, const u16* __restrict__ bDL,
    const u16* __restrict__ bDTH, const u16* __restrict__ bDTL,
    const float* __restrict__ bBTF, const u16* __restrict__ bBTH, const u16* __restrict__ bBTL,
    float* __restrict__ pDF, u16* __restrict__ pDH, u16* __restrict__ pDL,
    u16* __restrict__ pDTH, u16* __restrict__ pDTL,
    float* __restrict__ pBTF, u16* __restrict__ pBTH, u16* __restrict__ pBTL,
    CompJobs jobs){
  __shared__ float T[128][132];
  int job = blockIdx.x, z = blockIdx.y, tid = threadIdx.x;
  int a = jobs.a[job], b = jobs.b[job], d = jobs.d[job] - 128;
  size_t ob = (size_t)d * 16384;
  int lane = tid & 63, w = tid >> 6;
  const u16 *Ah, *Al, *Bh, *Bl;
  const float *F1, *F2;
  if(z == 0){
    Ah = selu(bDH, pDH, a);  Al = selu(bDL, pDL, a);
    Bh = selu(bDTH, pDTH, b); Bl = selu(bDTL, pDTL, b);
    F1 = self32(bDF, pDF, a); F2 = self32(bDF, pDF, b);
  } else {
    Ah = selu(bBTH, pBTH, b); Al = selu(bBTL, pBTL, b);
    Bh = selu(bDH, pDH, a);   Bl = selu(bDL, pDL, a);
    F1 = self32(bBTF, pBTF, a); F2 = self32(bBTF, pBTF, b);
  }
  for(int i = tid*4; i < 16384; i += 1024){
    f32x4 v1 = *(const f32x4*)(F1 + i);
    f32x4 v2 = *(const f32x4*)(F2 + i);
    f32x4 sv = v1 + v2;
    int row = i >> 7, col = i & 127;
    *(f32x4*)&T[row][col] = sv;
  }
  __syncthreads();
  f32x4 acc[2][8] = {};
  comp_mfma(Ah, Al, Bh, Bl, acc, lane, w);
  if(z == 0){
    #pragma unroll
    for(int mt = 0; mt < 2; ++mt)
      #pragma unroll
      for(int nt = 0; nt < 8; ++nt)
        #pragma unroll
        for(int r = 0; r < 4; ++r){
          int row = w*32 + mt*16 + ((lane >> 4) << 2) + r;
          int col = nt*16 + (lane & 15);
          float v = acc[mt][nt][r] + T[row][col];
          pDF[ob + row*128 + col] = v;
          u16 hi, lo; splitbf(v, hi, lo);
          pDH[ob + row*128 + col] = hi;
          pDL[ob + row*128 + col] = lo;
          T[row][col] = v;
        }
    __syncthreads();
    int tcol = tid >> 1, half = tid & 1;
    for(int m = 0; m < 64; ++m){
      float v = T[half*64 + m][tcol];
      u16 hi, lo; splitbf(v, hi, lo);
      pDTH[ob + (size_t)tcol*128 + half*64 + m] = hi;
      pDTL[ob + (size_t)tcol*128 + half*64 + m] = lo;
    }
  } else {
    #pragma unroll
    for(int mt = 0; mt < 2; ++mt)
      #pragma unroll
      for(int nt = 0; nt < 8; ++nt)
        #pragma unroll
        for(int r = 0; r < 4; ++r){
          int row = w*32 + mt*16 + ((lane >> 4) << 2) + r;
          int col = nt*16 + (lane & 15);
          float v = acc[mt][nt][r] + T[row][col];
          pBTF[ob + row*128 + col] = v;
          u16 hi, lo; splitbf(v, hi, lo);
          pBTH[ob + row*128 + col] = hi;
          pBTL[ob + row*128 + col] = lo;
        }
  }
}

// ---------------- head starts (parallel, LDS-staged F) ----------------
__global__ __launch_bounds__(256) void k_heads(
    const u16* __restrict__ bDH, const u16* __restrict__ bDL,
    const float* __restrict__ bBTF, const u16* __restrict__ bBTH, const u16* __restrict__ bBTL,
    const u16* __restrict__ pDH, const u16* __restrict__ pDL,
    const float* __restrict__ pBTF, const u16* __restrict__ pBTH, const u16* __restrict__ pBTL,
    float* __restrict__ ttF, u16* __restrict__ ttH, u16* __restrict__ ttL, u16* __restrict__ sj){
  __shared__ float T[128][132];
  int h = blockIdx.x, g = h >> 2, i0 = h & 3;
  int tid = threadIdx.x, lane = tid & 63, w = tid >> 6;
  int psi = (g == 0) ? -1 : (g == 1 ? 136 : (g == 2 ? 140 : 142));
  int phi = (i0 == 0) ? -1 : (i0 == 1 ? g*32 + 31 : (i0 == 2 ? 128 + g : 132 + g));
  const float* Pf = (psi >= 0) ? self32(bBTF, pBTF, psi) : nullptr;
  const float* Ff = (phi >= 0) ? self32(bBTF, pBTF, phi) : nullptr;
  for(int i = tid*4; i < 16384; i += 1024){
    f32x4 sv = {};
    if(Pf) sv += *(const f32x4*)(Pf + i);
    if(Ff) sv += *(const f32x4*)(Ff + i);
    int row = i >> 7, col = i & 127;
    *(f32x4*)&T[row][col] = sv;
  }
  __syncthreads();
  f32x4 acc[2][8] = {};
  if(psi >= 0 && phi >= 0)
    comp_mfma(selu(bBTH,pBTH,psi), selu(bBTL,pBTL,psi), selu(bDH,pDH,phi), selu(bDL,pDL,phi), acc, lane, w);
  #pragma unroll
  for(int mt = 0; mt < 2; ++mt)
    #pragma unroll
    for(int nt = 0; nt < 8; ++nt)
      #pragma unroll
      for(int r = 0; r < 4; ++r){
        int row = w*32 + mt*16 + ((lane >> 4) << 2) + r;
        int col = nt*16 + (lane & 15);
        float v = acc[mt][nt][r] + T[row][col];
        u16 hi, lo; splitbf(v, hi, lo);
        size_t o = (size_t)h*16384 + row*128 + col;
        ttF[o] = v; ttH[o] = hi; ttL[o] = lo;
        sj[(size_t)(h*32)*16384 + row*128 + col] = hi;
      }
}

// ---------------- expand ----------------
__global__ __launch_bounds__(256) void k_expand(const u16* __restrict__ bDH, const u16* __restrict__ bDL,
                                                const float* __restrict__ bBF, const float* __restrict__ ttF,
                                                const u16* __restrict__ ttH, const u16* __restrict__ ttL,
                                                u16* __restrict__ sj){
  int j = blockIdx.x;
  int c = j & 31;
  if(c == 0) return;
  int h = j >> 5, g = h >> 2;
  size_t obase = (size_t)j * 16384;
  size_t mb = (size_t)(g*32 + c - 1) * 16384;
  size_t tb = (size_t)h * 16384;
  int tid = threadIdx.x, lane = tid & 63, w = tid >> 6;
  f32x4 acc[2][8] = {};
  comp_mfma(ttH + tb, ttL + tb, bDH + mb, bDL + mb, acc, lane, w);
  #pragma unroll
  for(int mt = 0; mt < 2; ++mt)
    #pragma unroll
    for(int nt = 0; nt < 8; ++nt)
      #pragma unroll
      for(int r = 0; r < 4; ++r){
        int row = w*32 + mt*16 + ((lane >> 4) << 2) + r;
        int col = nt*16 + (lane & 15);
        float v = acc[mt][nt][r] + ttF[tb + row*128 + col] + bBF[mb + row*128 + col];
        sj[obase + row*128 + col] = f2bf(v);
      }
}

// ---------------- o_lin ----------------
__global__ __launch_bounds__(256) void k_olin(const u16* __restrict__ qlb, const u16* __restrict__ klb,
                                              const u16* __restrict__ wb, const float* __restrict__ u0f,
                                              const u16* __restrict__ sj, float* __restrict__ omix){
  __shared__ u16 ut[128*64];
  __shared__ u16 pl[4][16*64];
  int j = blockIdx.x;
  int h = j >> 5, c = j & 31, g = h >> 2, idx = g*32 + c;
  int tid = threadIdx.x, lane = tid & 63, w = tid >> 6;
  const u16* Sj = sj + (size_t)j * 16384;
  const u16* Q  = qlb + ((size_t)h*2048 + c*64) * 128;
  const u16* Kc = klb + ((size_t)g*2048 + c*64) * 128;
  const u16* W  = wb + (size_t)idx * 8192;
  const float* U0 = u0f + (size_t)idx * 8192;
  bf16x8 aq[4], aw[4];
  #pragma unroll
  for(int ks = 0; ks < 4; ++ks){
    aq[ks] = *(const bf16x8*)(Q + (w*16 + (lane & 15))*128 + ks*32 + ((lane >> 4) << 3));
    aw[ks] = *(const bf16x8*)(W + (w*16 + (lane & 15))*128 + ks*32 + ((lane >> 4) << 3));
  }
  f32x4 t1[8] = {}, ui[8] = {};
  #pragma unroll
  for(int ks = 0; ks < 4; ++ks)
    #pragma unroll
    for(int nt = 0; nt < 8; ++nt){
      bf16x8 b = *(const bf16x8*)(Sj + (nt*16 + (lane & 15))*128 + ks*32 + ((lane >> 4) << 3));
      t1[nt] = MFMA16(aq[ks], b, t1[nt]);
      ui[nt] = MFMA16(aw[ks], b, ui[nt]);
    }
  f32x4 sc[4] = {};
  #pragma unroll
  for(int ks = 0; ks < 4; ++ks)
    #pragma unroll
    for(int nt = 0; nt < 4; ++nt){
      bf16x8 b = *(const bf16x8*)(Kc + (nt*16 + (lane & 15))*128 + ks*32 + ((lane >> 4) << 3));
      sc[nt] = MFMA16(aq[ks], b, sc[nt]);
    }
  #pragma unroll
  for(int nt = 0; nt < 4; ++nt)
    #pragma unroll
    for(int r = 0; r < 4; ++r){
      int row = ((lane >> 4) << 2) + r;
      int col = nt*16 + (lane & 15);
      int grow = w*16 + row;
      float v = (col <= grow) ? sc[nt][r] : 0.f;
      int bo = (row*128 + col*2) ^ ((row & 7) << 4);
      *(u16*)((char*)&pl[w][0] + bo) = f2bf(v);
    }
  #pragma unroll
  for(int nt = 0; nt < 8; ++nt)
    #pragma unroll
    for(int r = 0; r < 4; ++r){
      int kv = w*16 + ((lane >> 4) << 2) + r;
      int d  = nt*16 + (lane & 15);
      float v = U0[kv*128 + d] - ui[nt][r];
      int bo = (d*128 + kv*2) ^ ((d & 7) << 4);
      *(u16*)((char*)ut + bo) = f2bf(v);
    }
  __syncthreads();
  f32x4 o2[8] = {};
  #pragma unroll
  for(int ks2 = 0; ks2 < 2; ++ks2){
    int row = lane & 15;
    int boA = (row*128 + ks2*64 + ((lane >> 4) << 4)) ^ ((row & 7) << 4);
    bf16x8 a = *(const bf16x8*)((const char*)&pl[w][0] + boA);
    #pragma unroll
    for(int nt = 0; nt < 8; ++nt){
      int d = nt*16 + (lane & 15);
      int boB = (d*128 + ks2*64 + ((lane >> 4) << 4)) ^ ((d & 7) << 4);
      bf16x8 b = *(const bf16x8*)((const char*)ut + boB);
      o2[nt] = MFMA16(a, b, o2[nt]);
    }
  }
  #pragma unroll
  for(int nt = 0; nt < 8; ++nt)
    #pragma unroll
    for(int r = 0; r < 4; ++r){
      int grow = c*64 + w*16 + ((lane >> 4) << 2) + r;
      int d = nt*16 + (lane & 15);
      omix[(size_t)grow*2048 + h*128 + d] = 0.5f * (t1[nt][r] + o2[nt][r]);
    }
}

// ---------------- base causal attention v4: shared LDS K/V staging (swizzled), m97 2-barrier loop ----------------
__global__ __launch_bounds__(256) void k_attn(const u16* __restrict__ qbf, const u16* __restrict__ kbf,
                                              const u16* __restrict__ vT, const float* __restrict__ omix,
                                              u16* __restrict__ obf,
                                              float* __restrict__ part1, float* __restrict__ part2){
  __shared__ u16 Kl[4096];
  __shared__ u16 Vl[4096];
  __shared__ u16 pl[4][1280];
  int rb = blockIdx.x;
  int bid = (rb & 7) * 80 + (rb >> 3);
  int h = bid / 40, j = bid % 40;
  int qB, kt0, kt1, slot = -1;
  if(j < 4){ qB = j; kt0 = 0; kt1 = 4*(qB+1); }
  else {
    int jj = j - 4; int seg;
    if(jj < 8){ qB = 4 + (jj >> 1); seg = jj & 1; }
    else if(jj < 20){ int q = jj - 8; qB = 8 + q/3; seg = q - (qB-8)*3; }
    else { int q = jj - 20; qB = 12 + (q >> 2); seg = q & 3; }
    slot = h*36 + jj;
    kt0 = seg*16;
    int full = 4*(qB+1);
    kt1 = (kt0 + 16 < full) ? kt0 + 16 : full;
  }
  int g = h >> 2;
  int tid = threadIdx.x, lane = tid & 63, w = tid >> 6;
  const u16* K = kbf + (size_t)g*2048*128;
  const u16* V = vT + (size_t)g*128*2048;
  bf16x8 aq[2][4];
  #pragma unroll
  for(int m = 0; m < 2; ++m){
    const u16* Q = qbf + ((size_t)h*2048 + qB*128 + w*32 + m*16) * 128;
    #pragma unroll
    for(int ks = 0; ks < 4; ++ks)
      aq[m][ks] = *(const bf16x8*)(Q + (lane & 15)*128 + ks*32 + ((lane >> 4) << 3));
  }
  f32x4 acc[2][8] = {};
  float lsum[2][4] = {};
  const float scale = 0.08838834764831845f;
  int qr0[2];
  #pragma unroll
  for(int m = 0; m < 2; ++m) qr0[m] = qB*128 + w*32 + m*16 + ((lane >> 4) << 2);
  u16* plw = &pl[w][0];
  for(int kt = kt0; kt < kt1; ++kt){
    __syncthreads();
    #pragma unroll
    for(int inst = 0; inst < 2; ++inst){
      int ob = w*2048 + inst*1024;
      int lo = ob + lane*16;
      {
        int r = lo >> 8;
        int gc = ((lo >> 4) & 15) ^ (r & 7);
        gload_lds16(K + (size_t)(kt*32 + r)*128 + gc*8, (u16*)((char*)Kl + ob));
      }
      {
        int d = lo >> 6;
        int gnb = ((lo >> 4) & 3) ^ ((d >> 1) & 3);
        gload_lds16(V + (size_t)d*2048 + kt*32 + gnb*8, (u16*)((char*)Vl + ob));
      }
    }
    __syncthreads();
    bf16x8 kb[8];
    #pragma unroll
    for(int ct = 0; ct < 2; ++ct)
      #pragma unroll
      for(int ks = 0; ks < 4; ++ks){
        int r = ct*16 + (lane & 15);
        int pc = (ks*4 + (lane >> 4)) ^ (r & 7);
        kb[ct*4+ks] = *(const bf16x8*)(Kl + r*128 + pc*8);
      }
    f32x4 s[2][2] = {};
    #pragma unroll
    for(int m = 0; m < 2; ++m)
      #pragma unroll
      for(int ct = 0; ct < 2; ++ct)
        #pragma unroll
        for(int ks = 0; ks < 4; ++ks)
          s[m][ct] = MFMA16(aq[m][ks], kb[ct*4+ks], s[m][ct]);
    bf16x8 bv[8];
    #pragma unroll
    for(int nt = 0; nt < 8; ++nt){
      int d = nt*16 + (lane & 15);
      int pnb = (lane >> 4) ^ ((d >> 1) & 3);
      bv[nt] = *(const bf16x8*)(Vl + d*32 + pnb*8);
    }
    #pragma unroll
    for(int m = 0; m < 2; ++m)
      #pragma unroll
      for(int ct = 0; ct < 2; ++ct)
        #pragma unroll
        for(int r = 0; r < 4; ++r){
          int col = kt*32 + ct*16 + (lane & 15);
          float p = (col <= qr0[m] + r) ? __expf(s[m][ct][r] * scale) : 0.f;
          lsum[m][r] += p;
          int row = m*16 + ((lane >> 4) << 2) + r;
          *(u16*)((char*)plw + row*80 + (ct*16 + (lane & 15))*2) = f2bf(p);
        }
    __builtin_amdgcn_s_setprio(1);
    #pragma unroll
    for(int m = 0; m < 2; ++m){
      bf16x8 ap = *(const bf16x8*)((const char*)plw + (m*16 + (lane & 15))*80 + ((lane >> 4) << 4));
      #pragma unroll
      for(int nt = 0; nt < 8; ++nt)
        acc[m][nt] = MFMA16(ap, bv[nt], acc[m][nt]);
    }
    __builtin_amdgcn_s_setprio(0);
  }
  #pragma unroll
  for(int m = 0; m < 2; ++m)
    #pragma unroll
    for(int r = 0; r < 4; ++r){
      float v = lsum[m][r];
      v += __shfl_xor(v, 1, 64); v += __shfl_xor(v, 2, 64);
      v += __shfl_xor(v, 4, 64); v += __shfl_xor(v, 8, 64);
      lsum[m][r] = v;
    }
  if(slot < 0){
    #pragma unroll
    for(int m = 0; m < 2; ++m)
      #pragma unroll
      for(int nt = 0; nt < 8; ++nt)
        #pragma unroll
        for(int r = 0; r < 4; ++r){
          int row = qB*128 + w*32 + m*16 + ((lane >> 4) << 2) + r;
          int d = nt*16 + (lane & 15);
          size_t o = (size_t)row*2048 + h*128 + d;
          float fin = omix[o] + 0.5f * acc[m][nt][r] / lsum[m][r];
          obf[o] = f2bf(fin);
        }
  } else {
    float* P = slotp(part1, part2, slot);
    #pragma unroll
    for(int m = 0; m < 2; ++m)
      #pragma unroll
      for(int nt = 0; nt < 8; ++nt)
        #pragma unroll
        for(int r = 0; r < 4; ++r){
          int row = w*32 + m*16 + ((lane >> 4) << 2) + r;
          int d = nt*16 + (lane & 15);
          P[(size_t)row*128 + d] = acc[m][nt][r];
        }
    if((lane & 15) == 0)
      #pragma unroll
      for(int m = 0; m < 2; ++m)
        #pragma unroll
        for(int r = 0; r < 4; ++r)
          P[16384 + w*32 + m*16 + ((lane >> 4) << 2) + r] = lsum[m][r];
  }
}

// ---------------- combine attention K-segments; writes final bf16 omix ----------------
__global__ __launch_bounds__(256) void k_acomb(const float* __restrict__ part1, const float* __restrict__ part2,
                                               const float* __restrict__ omix, u16* __restrict__ obf){
  int bid = blockIdx.x;
  int h = bid / 12, qx = bid % 12, qB = 4 + qx;
  int nseg = (qB >= 12) ? 4 : (qB >= 8) ? 3 : 2;
  int off = (qB < 8) ? (qB-4)*2 : (qB < 12) ? 8 + (qB-8)*3 : 20 + (qB-12)*4;
  int s0 = h*36 + off;
  int tid = threadIdx.x;
  #pragma unroll
  for(int it = 0; it < 16; ++it){
    int i = it*1024 + tid*4;
    int row = i >> 7;
    f32x4 a = {};
    float l = 0.f;
    for(int s = 0; s < nseg; ++s){
      const float* P = slotpc(part1, part2, s0 + s);
      a += *(const f32x4*)(P + i);
      l += P[16384 + row];
    }
    size_t idx = (size_t)(qB*128 + row)*2048 + h*128 + (i & 127);
    f32x4 cur = *(const f32x4*)(omix + idx);
    f32x4 fin = cur + a * (0.5f / l);
    u32 w0 = (u32)f2bf(fin[0]) | ((u32)f2bf(fin[1]) << 16);
    u32 w1 = (u32)f2bf(fin[2]) | ((u32)f2bf(fin[3]) << 16);
    *(u32*)(obf + idx) = w0;
    *(u32*)(obf + idx + 2) = w1;
  }
}

// ---------------- launch ----------------
extern "C" void kernel_launch(void* const* d_in, const int* in_sizes, int n_in,
                              void* d_out, int out_size, void* d_ws, size_t ws_size,
                              hipStream_t stream){
  (void)in_sizes; (void)n_in; (void)out_size; (void)ws_size;
  const float* hs = (const float*)d_in[0];
  const float* Wq = (const float*)d_in[1];
  const float* Wk = (const float*)d_in[2];
  const float* Wv = (const float*)d_in[3];
  const float* Wo = (const float*)d_in[4];
  float* out = (float*)d_out;
  char* ws = (char*)d_ws;

  u16*   hs_bf   = (u16*)(ws + OF_HSBF);
  u16*   wqkv_bf = (u16*)(ws + OF_WQKVBF);
  u16*   wo_bf   = (u16*)(ws + OF_WOBF);
  float* qkv     = (float*)(ws + OF_QKV);
  float* qkvB    = (float*)(ws + OF_QKVB);
  u16*   qbf     = (u16*)(ws + OF_QBF);
  u16*   kbf     = (u16*)(ws + OF_KBF);
  u16*   vT      = (u16*)(ws + OF_VT);
  u16*   qlb     = (u16*)(ws + OF_QLB);
  float* klf     = (float*)(ws + OF_KLF);
  u16*   klb     = (u16*)(ws + OF_KLB);
  float* glf     = (float*)(ws + OF_GLF);
  float* tinvb   = (float*)(ws + OF_TINV);
  float* wf      = (float*)(ws + OF_WF);
  u16*   wb      = (u16*)(ws + OF_WB);
  float* u0f     = (float*)(ws + OF_U0);
  u16*   sjb     = (u16*)(ws + OF_SJ);
  float* omix    = (float*)(ws + OF_OMIX);
  u16*   obf     = (u16*)(ws + OF_OBF);
  float* outh0   = (float*)(ws + OF_OUTH0);
  float* outh1   = (float*)(ws + OF_OUTH1);
  float* aDF  = (float*)(ws + OF_ADF);
  u16*   aDH  = (u16*)(ws + OF_ADH);
  u16*   aDL  = (u16*)(ws + OF_ADL);
  u16*   aDTH = (u16*)(ws + OF_ADTH);
  u16*   aDTL = (u16*)(ws + OF_ADTL);
  float* aBTF = (float*)(ws + OF_ABTF);
  u16*   aBTH = (u16*)(ws + OF_ABTH);
  u16*   aBTL = (u16*)(ws + OF_ABTL);
  float* bDF  = (float*)(ws + OF_BDF);
  u16*   bDH  = (u16*)(ws + OF_BDH);
  u16*   bDL  = (u16*)(ws + OF_BDL);
  u16*   bDTH = (u16*)(ws + OF_BDTH);
  u16*   bDTL = (u16*)(ws + OF_BDTL);
  float* bBTF = (float*)(ws + OF_BBTF);
  u16*   bBTH = (u16*)(ws + OF_BBTH);
  u16*   bBTL = (u16*)(ws + OF_BBTL);
  float* ttF  = (float*)(ws + OF_TTF);
  u16*   ttH  = (u16*)(ws + OF_TTH);
  u16*   ttL  = (u16*)(ws + OF_TTL);
  float* pDF  = (float*)(ws + OF_PDF);
  float* pBTF = (float*)(ws + OF_PBTF);
  u16*   pDH  = (u16*)(ws + OF_PDH);
  u16*   pDL  = (u16*)(ws + OF_PDL);
  u16*   pDTH = (u16*)(ws + OF_PDTH);
  u16*   pDTL = (u16*)(ws + OF_PDTL);
  u16*   pBTH = (u16*)(ws + OF_PBTH);
  u16*   pBTL = (u16*)(ws + OF_PBTL);
  float* apart1 = (float*)(ws + OF_APART1);
  float* apart2 = (float*)(ws + OF_APART2);

  k_f2ball<<<14336, 256, 0, stream>>>(hs, Wq, Wk, Wv, Wo, hs_bf, wqkv_bf, wo_bf);
  k_gemm<<<dim3(24, 16, 2), 256, 0, stream>>>(hs_bf, wqkv_bf, qkv, qkvB, 2048, 3072);
  k_linvt<<<10496, 256, 0, stream>>>(qkv, qkvB, qbf, qlb, kbf, klf, klb, glf, vT);

  k_prep1<<<128, 256, 0, stream>>>(klf, glf, tinvb);
  k_prep2a<<<256, 256, 0, stream>>>(klf, glf, qkv, tinvb, wf, wb, u0f);
  k_prep2b<<<256, 256, 0, stream>>>(klf, wf, u0f, aDF, aDH, aDL, aDTH, aDTL, aBTF, aBTH, aBTL);

  k_ks<<<dim3(32, 4, 2), 256, 0, stream>>>(aDF, aDH, aDL, aDTH, aDTL, aBTF, aBTH, aBTL,
                                           bDF, bDH, bDL, bDTH, bDTL, bBTF, bBTH, bBTL, 1);
  k_ks<<<dim3(32, 4, 2), 256, 0, stream>>>(bDF, bDH, bDL, bDTH, bDTL, bBTF, bBTH, bBTL,
                                           aDF, aDH, aDL, aDTH, aDTL, aBTF, aBTH, aBTL, 2);
  k_ks<<<dim3(32, 4, 2), 256, 0, stream>>>(aDF, aDH, aDL, aDTH, aDTL, aBTF, aBTH, aBTL,
                                           bDF, bDH, bDL, bDTH, bDTL, bBTF, bBTH, bBTL, 4);
  k_ks<<<dim3(32, 4, 2), 256, 0, stream>>>(bDF, bDH, bDL, bDTH, bDTL, bBTF, bBTH, bBTL,
                                           aDF, aDH, aDL, aDTH, aDTL, aBTF, aBTH, aBTL, 8);
  k_ks<<<dim3(32, 4, 2), 256, 0, stream>>>(aDF, aDH, aDL, aDTH, aDTL, aBTF, aBTH, aBTL,
                                           bDF, bDH, bDL, bDTH, bDTL, bBTF, bBTH, bBTL, 16);

  CompJobs j1{}; // Phi_g^2
  for(int g = 0; g < 4; ++g){ j1.a[g] = g*32+31; j1.b[g] = g*32+31; j1.d[g] = 128+g; }
  k_comp<<<dim3(4, 2), 256, 0, stream>>>(bDF, bDH, bDL, bDTH, bDTL, bBTF, bBTH, bBTL,
                                         pDF, pDH, pDL, pDTH, pDTL, pBTF, pBTH, pBTL, j1);
  CompJobs j2{}; // Phi^3, Phi^4
  for(int g = 0; g < 4; ++g){
    j2.a[g]   = 128+g; j2.b[g]   = g*32+31; j2.d[g]   = 132+g;
    j2.a[4+g] = 128+g; j2.b[4+g] = 128+g;   j2.d[4+g] = 136+g;
  }
  k_comp<<<dim3(8, 2), 256, 0, stream>>>(bDF, bDH, bDL, bDTH, bDTL, bBTF, bBTH, bBTL,
                                         pDF, pDH, pDL, pDTH, pDTL, pBTF, pBTH, pBTL, j2);
  CompJobs j3{}; // Psi2; T
  j3.a[0] = 137; j3.b[0] = 136; j3.d[0] = 140;
  j3.a[1] = 138; j3.b[1] = 137; j3.d[1] = 141;
  k_comp<<<dim3(2, 2), 256, 0, stream>>>(bDF, bDH, bDL, bDTH, bDTL, bBTF, bBTH, bBTL,
                                         pDF, pDH, pDL, pDTH, pDTL, pBTF, pBTH, pBTL, j3);
  CompJobs j4{}; // Psi3
  j4.a[0] = 141; j4.b[0] = 136; j4.d[0] = 142;
  k_comp<<<dim3(1, 2), 256, 0, stream>>>(bDF, bDH, bDL, bDTH, bDTL, bBTF, bBTH, bBTL,
                                         pDF, pDH, pDL, pDTH, pDTL, pBTF, pBTH, pBTL, j4);

  k_heads<<<16, 256, 0, stream>>>(bDH, bDL, bBTF, bBTH, bBTL,
                                  pDH, pDL, pBTF, pBTH, pBTL, ttF, ttH, ttL, sjb);
  k_expand<<<512, 256, 0, stream>>>(bDH, bDL, bBTF, ttF, ttH, ttL, sjb);

  k_olin<<<512, 256, 0, stream>>>(qlb, klb, wb, u0f, sjb, omix);
  k_attn<<<640, 256, 0, stream>>>(qbf, kbf, vT, omix, obf, apart1, apart2);
  k_acomb<<<192, 256, 0, stream>>>(apart1, apart2, omix, obf);

  k_gemm<<<dim3(16, 16, 2), 256, 0, stream>>>(obf, wo_bf, outh0, outh1, 2048, 2048);
  k_ocomb<<<4096, 256, 0, stream>>>(outh0, outh1, out);
}